// Round 13
// baseline (2067.401 us; speedup 1.0000x reference)
//
#include <hip/hip_runtime.h>
#include <hip/hip_bf16.h>
#include <math.h>

// Problem constants
#define D_    1024
#define H_    16
#define HD_   64
#define NL_   6
#define DFF_  4096
#define B_    4
#define L_    1024
#define LC_   512

typedef short bf16x8 __attribute__((ext_vector_type(8)));
typedef float f32x4  __attribute__((ext_vector_type(4)));
typedef unsigned int uint32;

// ---------------------------------------------------------------- utilities
__device__ __forceinline__ float waveReduceSum(float v) {
#pragma unroll
  for (int off = 32; off > 0; off >>= 1) v += __shfl_xor(v, off);
  return v;
}
__device__ __forceinline__ ushort f2bf(float f) {
  union { __hip_bfloat16 h; ushort u; } c;
  c.h = __float2bfloat16(f);
  return c.u;
}
__device__ __forceinline__ float bf2f(ushort u) {
  union { uint32 i; float f; } c;
  c.i = ((uint32)u) << 16;
  return c.f;
}
__device__ __forceinline__ uint32 pk2(float a, float b) {
  return (uint32)f2bf(a) | ((uint32)f2bf(b) << 16);
}
// async global->LDS, 16B per lane. lds base must be wave-uniform (m104).
__device__ __forceinline__ void gload16(const ushort* g, ushort* l) {
  __builtin_amdgcn_global_load_lds(
      (const __attribute__((address_space(1))) uint32*)g,
      (__attribute__((address_space(3))) uint32*)l, 16, 0, 0);
}

// banded XCD swizzle: XCD chunk covers 4 tile-rows x (chunk/4) tile-cols.
// Requires gridDim.y % 4 == 0 and nwg % 8 == 0. Returns row,col tile indices.
__device__ __forceinline__ void xcd_banded(int& trow, int& tcol) {
  const int nwg = gridDim.x * gridDim.y;
  const int wg = blockIdx.y * gridDim.x + blockIdx.x;
  const int q = nwg >> 3;
  const int swz = (wg & 7) * q + (wg >> 3);
  const int bandw = gridDim.x * 4;
  const int band = swz / bandw;
  const int rem = swz % bandw;
  trow = band * 4 + (rem & 3);
  tcol = rem >> 2;
}

// ---------------------------------------------------------------- fp32 -> bf16 bulk convert
__global__ __launch_bounds__(256) void cvt_bf16_kernel(
    const float* __restrict__ in, ushort* __restrict__ out, int n4) {
  int i = blockIdx.x * 256 + threadIdx.x;
  int stride = gridDim.x * 256;
  for (; i < n4; i += stride) {
    float4 v = ((const float4*)in)[i];
    ushort4 o = {f2bf(v.x), f2bf(v.y), f2bf(v.z), f2bf(v.w)};
    ((ushort4*)out)[i] = o;
  }
}

// packed [NL][2048][1024]: rows 0-1023 = ck layer, 1024-2047 = cv layer
__global__ __launch_bounds__(256) void cvt_pack_kv_kernel(
    const float* __restrict__ ck, const float* __restrict__ cv,
    ushort* __restrict__ out, int n4) {
  int i = blockIdx.x * 256 + threadIdx.x;
  int stride = gridDim.x * 256;
  for (; i < n4; i += stride) {
    int row = i >> 8;               // 256 float4 per 1024-wide row
    int cb = i & 255;
    int layer = row >> 11;
    int sel = (row >> 10) & 1;
    int r = row & 1023;
    const float* src = (sel ? cv : ck) +
                       (((size_t)layer << 10) + r) * 1024 + cb * 4;
    float4 v = *(const float4*)src;
    ushort4 o = {f2bf(v.x), f2bf(v.y), f2bf(v.z), f2bf(v.w)};
    ((ushort4*)out)[i] = o;
  }
}

// ---------------------------------------------------------------- RoPE table
__global__ void rope_table_kernel(float* __restrict__ tab) {
  int t = blockIdx.x * 256 + threadIdx.x;   // [0, L_*32)
  if (t >= L_ * 32) return;
  int l = t >> 5, j = t & 31;
  float inv = powf(10000.f, -(float)j * (1.f / 32.f));
  float ang = (float)l * inv;
  tab[l * 64 + j] = cosf(ang);
  tab[l * 64 + 32 + j] = sinf(ang);
}

// ---------------------------------------------------------------- AdaLN gb, all layers in one launch
__global__ __launch_bounds__(256) void adaln_gb_all_kernel(
    const float* __restrict__ emb,
    const float* __restrict__ n1w, const float* __restrict__ n2w,
    const float* __restrict__ n3w,
    const float* __restrict__ n1b, const float* __restrict__ n2b,
    const float* __restrict__ n3b,
    float* __restrict__ gb) {
  int wid = blockIdx.x * 4 + (threadIdx.x >> 6);   // [0, 18*2048)
  int lane = threadIdx.x & 63;
  int n = wid & 2047;
  int g = wid >> 11;                 // 0..17
  int layer = g / 3, j = g - layer * 3;
  const float* wbase = (j == 0 ? n1w : (j == 1 ? n2w : n3w));
  const float* bbase = (j == 0 ? n1b : (j == 1 ? n2b : n3b));
  const float* wr = wbase + ((size_t)layer * 2048 + n) * 1024;
  float s0 = 0.f, s1 = 0.f, s2 = 0.f, s3 = 0.f;
#pragma unroll
  for (int k4 = 0; k4 < 4; ++k4) {
    int idx = k4 * 64 + lane;
    float4 w4 = ((const float4*)wr)[idx];
    float4 e0 = ((const float4*)emb)[idx];
    float4 e1 = ((const float4*)(emb + 1024))[idx];
    float4 e2 = ((const float4*)(emb + 2048))[idx];
    float4 e3 = ((const float4*)(emb + 3072))[idx];
    s0 += w4.x * e0.x + w4.y * e0.y + w4.z * e0.z + w4.w * e0.w;
    s1 += w4.x * e1.x + w4.y * e1.y + w4.z * e1.z + w4.w * e1.w;
    s2 += w4.x * e2.x + w4.y * e2.y + w4.z * e2.z + w4.w * e2.w;
    s3 += w4.x * e3.x + w4.y * e3.y + w4.z * e3.z + w4.w * e3.w;
  }
  s0 = waveReduceSum(s0);
  s1 = waveReduceSum(s1);
  s2 = waveReduceSum(s2);
  s3 = waveReduceSum(s3);
  if (lane == 0) {
    float bb = bbase[(size_t)layer * 2048 + n];
    gb[((size_t)g * 4 + 0) * 2048 + n] = s0 + bb;
    gb[((size_t)g * 4 + 1) * 2048 + n] = s1 + bb;
    gb[((size_t)g * 4 + 2) * 2048 + n] = s2 + bb;
    gb[((size_t)g * 4 + 3) * 2048 + n] = s3 + bb;
  }
}

// ---------------------------------------------------------------- AdaLN apply (bf16 out)
__global__ __launch_bounds__(256) void adaln_apply_kernel(
    const float* __restrict__ x, const float* __restrict__ gb,
    ushort* __restrict__ xn) {
  int r = blockIdx.x;
  int b = r >> 10;
  const float* xr = x + (size_t)r * D_;
  int tid = threadIdx.x;
  float4 v = *(const float4*)(xr + tid * 4);
  float s = v.x + v.y + v.z + v.w;
  float q = v.x * v.x + v.y * v.y + v.z * v.z + v.w * v.w;
  s = waveReduceSum(s);
  q = waveReduceSum(q);
  __shared__ float ssum[4], ssq[4], stats[2];
  int w = tid >> 6, lane = tid & 63;
  if (lane == 0) { ssum[w] = s; ssq[w] = q; }
  __syncthreads();
  if (tid == 0) {
    float S = ssum[0] + ssum[1] + ssum[2] + ssum[3];
    float Q = ssq[0] + ssq[1] + ssq[2] + ssq[3];
    float mean = S * (1.f / D_);
    float var = Q * (1.f / D_) - mean * mean;
    stats[0] = mean;
    stats[1] = rsqrtf(var + 1e-5f);
  }
  __syncthreads();
  float mean = stats[0], rstd = stats[1];
  const float* gp = gb + (size_t)b * 2048;
  float4 g  = *(const float4*)(gp + tid * 4);
  float4 be = *(const float4*)(gp + D_ + tid * 4);
  ushort4 o;
  o.x = f2bf((v.x - mean) * rstd * (1.f + g.x) + be.x);
  o.y = f2bf((v.y - mean) * rstd * (1.f + g.y) + be.y);
  o.z = f2bf((v.z - mean) * rstd * (1.f + g.z) + be.z);
  o.w = f2bf((v.w - mean) * rstd * (1.f + g.w) + be.w);
  *(ushort4*)(xn + (size_t)r * D_ + tid * 4) = o;
}

// ---------------------------------------------------------------- bf16 MFMA GEMM (128x128)
// depth-2 pipelined (3 LDS buffers + counted vmcnt), banded XCD swizzle,
// source-chunk LDS swizzle, padded vector epilogue, optional fused RoPE.
template <int FLAGS, bool OUTBF, int ROPE>
__global__ __launch_bounds__(256) void gemm_mfma_kernel(
    const ushort* __restrict__ A, int lda,
    const ushort* __restrict__ W, int ldw,
    const float* __restrict__ bias,
    const float* __restrict__ res, int ldres,
    void* __restrict__ Cout, int ldc, int K,
    const float* __restrict__ tab, int rlim, int lmask) {
  __shared__ __align__(16) ushort lds[24576];   // 48KB: A bufs @0, W bufs @12288
  const int tid = threadIdx.x;
  const int lane = tid & 63, wv = tid >> 6;
  const int wrow = (wv >> 1) * 64, wcol = (wv & 1) * 64;
  const int fr = lane & 15;
  const int kbs = (((lane >> 4) ^ (fr & 3)) & 3) * 8;

  int trow, tcol;
  xcd_banded(trow, tcol);
  const int row0 = trow * 128;
  const int col0 = tcol * 128;

  const int c0 = wv * 2, c1 = wv * 2 + 1;
  const int sr = lane >> 2;
  const int sc = (((lane & 3) ^ (sr & 3)) & 3) * 8;
  const ushort* Ap0 = A + (size_t)(row0 + c0 * 16 + sr) * lda + sc;
  const ushort* Ap1 = A + (size_t)(row0 + c1 * 16 + sr) * lda + sc;
  const ushort* Wp0 = W + (size_t)(col0 + c0 * 16 + sr) * ldw + sc;
  const ushort* Wp1 = W + (size_t)(col0 + c1 * 16 + sr) * ldw + sc;

  f32x4 acc[4][4];
#pragma unroll
  for (int m = 0; m < 4; ++m)
#pragma unroll
    for (int n = 0; n < 4; ++n) acc[m][n] = (f32x4)0.f;

#define ASB(B) (lds + (B) * 4096)
#define WSB(B) (lds + 12288 + (B) * 4096)
#define STAGE(B, T)                                   \
  do {                                                \
    const int koff_ = (T) * 32;                       \
    gload16(Ap0 + koff_, ASB(B) + c0 * 512);          \
    gload16(Ap1 + koff_, ASB(B) + c1 * 512);          \
    gload16(Wp0 + koff_, WSB(B) + c0 * 512);          \
    gload16(Wp1 + koff_, WSB(B) + c1 * 512);          \
  } while (0)
#define WAITV8() asm volatile("s_waitcnt vmcnt(8)" ::: "memory")
#define WAITV4() asm volatile("s_waitcnt vmcnt(4)" ::: "memory")
#define WAITV0() asm volatile("s_waitcnt vmcnt(0)" ::: "memory")
#define BAR()    __builtin_amdgcn_s_barrier()
#define COMPUTE(B)                                                          \
  do {                                                                      \
    bf16x8 af[4], bfr[4];                                                   \
    _Pragma("unroll")                                                       \
    for (int m = 0; m < 4; ++m)                                             \
      af[m] = *(const bf16x8*)(ASB(B) + (wrow + m * 16 + fr) * 32 + kbs);   \
    _Pragma("unroll")                                                       \
    for (int n = 0; n < 4; ++n)                                             \
      bfr[n] = *(const bf16x8*)(WSB(B) + (wcol + n * 16 + fr) * 32 + kbs);  \
    _Pragma("unroll")                                                       \
    for (int m = 0; m < 4; ++m)                                             \
      _Pragma("unroll")                                                     \
      for (int n = 0; n < 4; ++n)                                           \
        acc[m][n] = __builtin_amdgcn_mfma_f32_16x16x32_bf16(af[m], bfr[n],  \
                                                            acc[m][n], 0, 0, 0); \
  } while (0)

  const int NT = K >> 5;
  STAGE(0, 0);
  STAGE(1, 1);
  for (int t = 0; t < NT; t += 3) {
    {
      const bool sA = (t + 2) < NT;
      if (sA) STAGE(2, t + 2);
      if ((t + 1) < NT) { if (sA) WAITV8(); else WAITV4(); } else WAITV0();
      BAR(); COMPUTE(0); BAR();
    }
    if ((t + 1) < NT) {
      const bool sB = (t + 3) < NT;
      if (sB) STAGE(0, t + 3);
      if ((t + 2) < NT) { if (sB) WAITV8(); else WAITV4(); } else WAITV0();
      BAR(); COMPUTE(1); BAR();
    }
    if ((t + 2) < NT) {
      const bool sC = (t + 4) < NT;
      if (sC) STAGE(1, t + 4);
      if ((t + 3) < NT) { if (sC) WAITV8(); else WAITV4(); } else WAITV0();
      BAR(); COMPUTE(2); BAR();
    }
  }
#undef STAGE
#undef WAITV8
#undef WAITV4
#undef WAITV0
#undef COMPUTE

  float bn[4];
  if (FLAGS & 1) {
#pragma unroll
    for (int n = 0; n < 4; ++n) bn[n] = bias[col0 + wcol + n * 16 + fr];
  }
#define EPI(v, n)                                                     \
  do {                                                                \
    if (FLAGS & 1) (v) += bn[n];                                      \
    if (FLAGS & 2) (v) = 0.5f * (v) * (1.f + erff((v) * 0.70710678118f)); \
  } while (0)

  if (OUTBF) {
    ushort* Ct = lds;                       // [128][136] bf16 (padded)
    ushort* Cg = (ushort*)Cout;
#pragma unroll
    for (int m = 0; m < 4; ++m) {
      int lr0 = wrow + m * 16 + (lane >> 4) * 4;
#pragma unroll
      for (int n = 0; n < 4; ++n) {
        int lc = wcol + n * 16 + fr;
#pragma unroll
        for (int r = 0; r < 4; ++r) {
          float v = acc[m][n][r];
          EPI(v, n);
          Ct[(lr0 + r) * 136 + lc] = f2bf(v);
        }
      }
    }
    __syncthreads();
#pragma unroll
    for (int it = 0; it < 8; ++it) {
      int lr = (tid >> 4) + it * 16;
      int lc = (tid & 15) * 8;
      union { int4 v; ushort us[8]; } vv;
      vv.v = *(const int4*)&Ct[lr * 136 + lc];
      if (ROPE && (col0 + lc) < rlim) {
        union { int4 v; ushort us[8]; } pv;
        pv.v = *(const int4*)&Ct[lr * 136 + (lc ^ 32)];
        int l = (row0 + lr) & lmask;
        int j = lc & 31;
        const float* cb = &tab[l * 64 + j];
        bool lowhalf = (lc & 63) < 32;
#pragma unroll
        for (int e = 0; e < 8; ++e) {
          float cc = cb[e], ss = cb[32 + e];
          float xv = bf2f(vv.us[e]), xp = bf2f(pv.us[e]);
          float o = lowhalf ? (xv * cc - xp * ss) : (xp * ss + xv * cc);
          vv.us[e] = f2bf(o);
        }
      }
      *(int4*)&Cg[(size_t)(row0 + lr) * ldc + col0 + lc] = vv.v;
    }
  } else {
    float* Cf = (float*)lds;                // [64][132] f32 (padded) per half
    float* Cg = (float*)Cout;
#pragma unroll
    for (int half = 0; half < 2; ++half) {
      if ((wv >> 1) == half) {
#pragma unroll
        for (int m = 0; m < 4; ++m) {
          int lr0 = m * 16 + (lane >> 4) * 4;
#pragma unroll
          for (int n = 0; n < 4; ++n) {
            int lc = wcol + n * 16 + fr;
#pragma unroll
            for (int r = 0; r < 4; ++r) {
              float v = acc[m][n][r];
              EPI(v, n);
              Cf[(lr0 + r) * 132 + lc] = v;
            }
          }
        }
      }
      __syncthreads();
#pragma unroll
      for (int it = 0; it < 8; ++it) {
        int lr = (tid >> 5) + it * 8;
        int lc = (tid & 31) * 4;
        int grow = row0 + half * 64 + lr;
        float4 v = *(const float4*)&Cf[lr * 132 + lc];
        if (FLAGS & 4) {
          float4 rv = *(const float4*)&res[(size_t)grow * ldres + col0 + lc];
          v.x += rv.x; v.y += rv.y; v.z += rv.z; v.w += rv.w;
        }
        *(float4*)&Cg[(size_t)grow * ldc + col0 + lc] = v;
      }
      __syncthreads();
    }
  }
#undef EPI
#undef ASB
#undef WSB
#undef BAR
}

// ---------------------------------------------------------------- 128x64 fp32-out GEMM
// For N=1024 projections (so/co/f2): grid 16x32 = 512 blocks = 2/CU so
// cross-block overlap hides stage latency. Same proven pipeline/swizzle,
// 3-load stages (vmcnt 6/3/0). 4 waves 2x2, wave tile 64x32, acc[4][2].
// FLAGS: 1=+bias, 2=gelu, 4=+res(fp32). Requires K%64==0.
template <int FLAGS>
__global__ __launch_bounds__(256) void gemm_n64_kernel(
    const ushort* __restrict__ A, int lda,
    const ushort* __restrict__ W, int ldw,
    const float* __restrict__ bias,
    const float* __restrict__ res, int ldres,
    float* __restrict__ Cout, int ldc, int K) {
  __shared__ __align__(16) ushort lds[18432];   // 36KB: A 3x8KB @0, W 3x4KB @12288
  const int tid = threadIdx.x;
  const int lane = tid & 63, wv = tid >> 6;
  const int wrow = (wv >> 1) * 64, wcol = (wv & 1) * 32;
  const int fr = lane & 15;
  const int kbs = (((lane >> 4) ^ (fr & 3)) & 3) * 8;

  int trow, tcol;
  xcd_banded(trow, tcol);
  const int row0 = trow * 128;
  const int col0 = tcol * 64;

  // staging: per stage 3 gload16/wave. A chunks wv*2, wv*2+1 (16 rows each);
  // W chunk wv (16 rows). lane: row sr = lane>>2, col-chunk inverse-swizzled.
  const int a0 = wv * 2, a1 = wv * 2 + 1;
  const int sr = lane >> 2;
  const int sc = (((lane & 3) ^ (sr & 3)) & 3) * 8;
  const ushort* Ap0 = A + (size_t)(row0 + a0 * 16 + sr) * lda + sc;
  const ushort* Ap1 = A + (size_t)(row0 + a1 * 16 + sr) * lda + sc;
  const ushort* Wp  = W + (size_t)(col0 + wv * 16 + sr) * ldw + sc;

  f32x4 acc[4][2];
#pragma unroll
  for (int m = 0; m < 4; ++m)
#pragma unroll
    for (int n = 0; n < 2; ++n) acc[m][n] = (f32x4)0.f;

#define ASB6(B) (lds + (B) * 4096)
#define WSB6(B) (lds + 12288 + (B) * 2048)
#define STAGE6(B, T)                                  \
  do {                                                \
    const int koff_ = (T) * 32;                       \
    gload16(Ap0 + koff_, ASB6(B) + a0 * 512);         \
    gload16(Ap1 + koff_, ASB6(B) + a1 * 512);         \
    gload16(Wp + koff_, WSB6(B) + wv * 512);          \
  } while (0)
#define WAITW6() asm volatile("s_waitcnt vmcnt(6)" ::: "memory")
#define WAITW3() asm volatile("s_waitcnt vmcnt(3)" ::: "memory")
#define WAITW0() asm volatile("s_waitcnt vmcnt(0)" ::: "memory")
#define BAR6()   __builtin_amdgcn_s_barrier()
#define COMPUTE6(B)                                                         \
  do {                                                                      \
    bf16x8 af[4], bfr[2];                                                   \
    _Pragma("unroll")                                                       \
    for (int m = 0; m < 4; ++m)                                             \
      af[m] = *(const bf16x8*)(ASB6(B) + (wrow + m * 16 + fr) * 32 + kbs);  \
    _Pragma("unroll")                                                       \
    for (int n = 0; n < 2; ++n)                                             \
      bfr[n] = *(const bf16x8*)(WSB6(B) + (wcol + n * 16 + fr) * 32 + kbs); \
    _Pragma("unroll")                                                       \
    for (int m = 0; m < 4; ++m)                                             \
      _Pragma("unroll")                                                     \
      for (int n = 0; n < 2; ++n)                                           \
        acc[m][n] = __builtin_amdgcn_mfma_f32_16x16x32_bf16(af[m], bfr[n],  \
                                                            acc[m][n], 0, 0, 0); \
  } while (0)

  const int NT = K >> 5;
  STAGE6(0, 0);
  STAGE6(1, 1);
  for (int t = 0; t < NT; t += 3) {
    {
      const bool sA = (t + 2) < NT;
      if (sA) STAGE6(2, t + 2);
      if ((t + 1) < NT) { if (sA) WAITW6(); else WAITW3(); } else WAITW0();
      BAR6(); COMPUTE6(0); BAR6();
    }
    if ((t + 1) < NT) {
      const bool sB = (t + 3) < NT;
      if (sB) STAGE6(0, t + 3);
      if ((t + 2) < NT) { if (sB) WAITW6(); else WAITW3(); } else WAITW0();
      BAR6(); COMPUTE6(1); BAR6();
    }
    if ((t + 2) < NT) {
      const bool sC = (t + 4) < NT;
      if (sC) STAGE6(1, t + 4);
      if ((t + 3) < NT) { if (sC) WAITW6(); else WAITW3(); } else WAITW0();
      BAR6(); COMPUTE6(2); BAR6();
    }
  }
#undef STAGE6
#undef WAITW6
#undef WAITW3
#undef WAITW0
#undef COMPUTE6
#undef ASB6
#undef WSB6
#undef BAR6

  // epilogue: acc -> LDS [128][68] f32 (34KB, fits 36KB) -> float4 stores
  float bn[2];
  if (FLAGS & 1) {
#pragma unroll
    for (int n = 0; n < 2; ++n) bn[n] = bias[col0 + wcol + n * 16 + fr];
  }
  float* Cf = (float*)lds;
#pragma unroll
  for (int m = 0; m < 4; ++m) {
    int lr0 = wrow + m * 16 + (lane >> 4) * 4;
#pragma unroll
    for (int n = 0; n < 2; ++n) {
      int lc = wcol + n * 16 + fr;
#pragma unroll
      for (int r = 0; r < 4; ++r) {
        float v = acc[m][n][r];
        if (FLAGS & 1) v += bn[n];
        if (FLAGS & 2) v = 0.5f * v * (1.f + erff(v * 0.70710678118f));
        Cf[(lr0 + r) * 68 + lc] = v;
      }
    }
  }
  __syncthreads();
#pragma unroll
  for (int it = 0; it < 8; ++it) {
    int idx = tid + it * 256;          // 2048 = 128 rows x 16 float4
    int lr = idx >> 4;
    int lc = (idx & 15) * 4;
    int grow = row0 + lr;
    float4 v = *(const float4*)&Cf[lr * 68 + lc];
    if (FLAGS & 4) {
      float4 rv = *(const float4*)&res[(size_t)grow * ldres + col0 + lc];
      v.x += rv.x; v.y += rv.y; v.z += rv.z; v.w += rv.w;
    }
    *(float4*)&Cout[(size_t)grow * ldc + col0 + lc] = v;
  }
}

// ---------------------------------------------------------------- 256x256 8-wave GEMM
// BK=64, double-buffered 128KB LDS, one barrier + one (late, cheap) vmcnt(0)
// per K-tile; banded XCD swizzle; chunk-XOR LDS swizzle; setprio around MFMA.
// Epilogue: linear [256][256] LDS tile (exactly 128KB) -> vector stores.
// FLAGS: 1=+bias, 2=gelu. Requires K%64==0, M,N%256==0, gridDim.y%4==0.
template <int FLAGS, int ROPE>
__global__ __launch_bounds__(512, 2) void gemm256_kernel(
    const ushort* __restrict__ A, int lda,
    const ushort* __restrict__ W, int ldw,
    const float* __restrict__ bias,
    ushort* __restrict__ Cout, int ldc, int K,
    const float* __restrict__ tab, int rlim, int lmask) {
  __shared__ __align__(16) ushort lds[65536];   // 128 KB
  const int tid = threadIdx.x;
  const int lane = tid & 63, wid = tid >> 6;
  const int wm = wid >> 2, wn = wid & 3;        // 2 x 4 wave grid
  const int fr = lane & 15, hi = lane >> 4;

  int trow, tcol;
  xcd_banded(trow, tcol);
  const int row0 = trow * 256;
  const int col0 = tcol * 256;

  // staging: chunk ch = wid*4+j covers tile rows ch*8..+7 (1KB linear in LDS).
  // lane l -> row offset l>>3, global col-chunk (l&7)^(l>>3) (inverse swizzle).
  const int srow = lane >> 3;
  const int scol = ((lane & 7) ^ srow) * 8;
  const ushort* Asrc[4];
  const ushort* Wsrc[4];
#pragma unroll
  for (int j = 0; j < 4; ++j) {
    int r = wid * 32 + j * 8 + srow;
    Asrc[j] = A + (size_t)(row0 + r) * lda + scol;
    Wsrc[j] = W + (size_t)(col0 + r) * ldw + scol;
  }
#define AB256(b) (lds + (b) * 16384)
#define WB256(b) (lds + 32768 + (b) * 16384)
#define STG256(b, T)                                      \
  do {                                                    \
    const int kk_ = (T) * 64;                             \
    _Pragma("unroll")                                     \
    for (int j = 0; j < 4; ++j) {                         \
      int ch_ = wid * 4 + j;                              \
      gload16(Asrc[j] + kk_, AB256(b) + ch_ * 512);       \
      gload16(Wsrc[j] + kk_, WB256(b) + ch_ * 512);       \
    }                                                     \
  } while (0)

  f32x4 acc[8][4];
#pragma unroll
  for (int m = 0; m < 8; ++m)
#pragma unroll
    for (int n = 0; n < 4; ++n) acc[m][n] = (f32x4)0.f;

  const int NT = K >> 6;
  STG256(0, 0);
  asm volatile("s_waitcnt vmcnt(0)" ::: "memory");
  __builtin_amdgcn_s_barrier();
  for (int t = 0; t < NT; ++t) {
    const int cur = t & 1;
    if (t + 1 < NT) STG256(cur ^ 1, t + 1);   // issue BEFORE compute
    const ushort* ab = AB256(cur);
    const ushort* wb = WB256(cur);
    __builtin_amdgcn_s_setprio(1);
#pragma unroll
    for (int s = 0; s < 2; ++s) {
      bf16x8 wf[4];
#pragma unroll
      for (int n = 0; n < 4; ++n) {
        int row = wn * 64 + n * 16 + fr;
        wf[n] = *(const bf16x8*)(wb + row * 64 + (((s * 4 + hi) ^ (fr & 7)) * 8));
      }
#pragma unroll
      for (int m = 0; m < 8; ++m) {
        int row = wm * 128 + m * 16 + fr;
        bf16x8 af = *(const bf16x8*)(ab + row * 64 + (((s * 4 + hi) ^ (fr & 7)) * 8));
#pragma unroll
        for (int n = 0; n < 4; ++n)
          acc[m][n] = __builtin_amdgcn_mfma_f32_16x16x32_bf16(af, wf[n],
                                                              acc[m][n], 0, 0, 0);
      }
    }
    __builtin_amdgcn_s_setprio(0);
    asm volatile("s_waitcnt vmcnt(0)" ::: "memory");   // loads had whole compute to land
    __builtin_amdgcn_s_barrier();
  }
#undef STG256

  // epilogue: acc -> LDS [256][256] linear (exactly fits) -> vector stores
  float bn[4];
  if (FLAGS & 1) {
#pragma unroll
    for (int n = 0; n < 4; ++n) bn[n] = bias[col0 + wn * 64 + n * 16 + fr];
  }
  ushort* Ct = lds;
#pragma unroll
  for (int m = 0; m < 8; ++m) {
    int lr0 = wm * 128 + m * 16 + hi * 4;
#pragma unroll
    for (int n = 0; n < 4; ++n) {
      int lc = wn * 64 + n * 16 + fr;
#pragma unroll
      for (int r = 0; r < 4; ++r) {
        float v = acc[m][n][r];
        if (FLAGS & 1) v += bn[n];
        if (FLAGS & 2) v = 0.5f * v * (1.f + erff(v * 0.70710678118f));
        Ct[(lr0 + r) * 256 + lc] = f2bf(v);
      }
    }
  }
  __syncthreads();
#pragma unroll
  for (int it = 0; it < 16; ++it) {
    int idx = tid + it * 512;
    int lr = idx >> 5;                 // 0..255
    int lc = (idx & 31) * 8;           // 0..248
    union { int4 v; ushort us[8]; } vv;
    vv.v = *(const int4*)&Ct[lr * 256 + lc];
    if (ROPE && (col0 + lc) < rlim) {
      union { int4 v; ushort us[8]; } pv;
      pv.v = *(const int4*)&Ct[lr * 256 + (lc ^ 32)];
      int l = (row0 + lr) & lmask;
      int j = lc & 31;
      const float* cb = &tab[l * 64 + j];
      bool lowhalf = (lc & 63) < 32;
#pragma unroll
      for (int e = 0; e < 8; ++e) {
        float cc = cb[e], ss = cb[32 + e];
        float xv = bf2f(vv.us[e]), xp = bf2f(pv.us[e]);
        float o = lowhalf ? (xv * cc - xp * ss) : (xp * ss + xv * cc);
        vv.us[e] = f2bf(o);
      }
    }
    *(int4*)&Cout[(size_t)(row0 + lr) * ldc + col0 + lc] = vv.v;
  }
#undef AB256
#undef WB256
}

// ---------------------------------------------------------------- MFMA flash attention
// 128 q-rows/block, 8 waves: waves 0-3 stage K (quarter w), waves 4-7 stage V
// (transposed quarter w-4). Swapped QK^T, register-exchange P, K/V dbuf.
#define SWZ(row, col) (((row) << 6) + ((col) ^ (((row) & 7) << 3)))
__global__ __launch_bounds__(512) void attn_mfma_kernel(
    const ushort* __restrict__ Q, int ldq,
    const ushort* __restrict__ K, int ldk,
    const ushort* __restrict__ V, int ldv,
    ushort* __restrict__ O, int ldo,
    int Lq, int Lk, float scale) {
  __shared__ __align__(16) ushort Ks[2][64 * 64];
  __shared__ __align__(16) ushort Vt[2][64 * 64];
  __shared__ __align__(16) ushort Os[128 * 64];
  const int tid = threadIdx.x;
  const int lane = tid & 63, w = tid >> 6;       // w in 0..7
  const int fr = lane & 15, hi = lane >> 4, kb = hi * 8;
  const int b = blockIdx.z, h = blockIdx.y, q0 = blockIdx.x * 128;
  const int kw = w & 3;
  const bool isK = (w < 4);

  // Q fragments from global, scale folded in (exact for scale = 0.125)
  bf16x8 aq[2];
  {
    const ushort* qp = Q + (size_t)(b * Lq + q0 + w * 16 + fr) * ldq + h * 64 + kb;
    union { bf16x8 v; ushort us[8]; } t0, t1;
    t0.v = *(const bf16x8*)qp;
    t1.v = *(const bf16x8*)(qp + 32);
#pragma unroll
    for (int e = 0; e < 8; ++e) {
      t0.us[e] = f2bf(bf2f(t0.us[e]) * scale);
      t1.us[e] = f2bf(bf2f(t1.us[e]) * scale);
    }
    aq[0] = t0.v;
    aq[1] = t1.v;
  }

  const int ldkv = isK ? ldk : ldv;
  const ushort* kvbase = (isK ? K : V) + (size_t)(b * Lk + lane) * ldkv
                         + h * 64 + kw * 16;
  const size_t kvstep = (size_t)64 * ldkv;
  int4 r0, r1;
#define LOADKV(T)                                      \
  do {                                                 \
    const ushort* p_ = kvbase + (size_t)(T) * kvstep;  \
    r0 = ((const int4*)p_)[0];                         \
    r1 = ((const int4*)p_)[1];                         \
  } while (0)
#define WRITEKV(P)                                                        \
  do {                                                                    \
    if (isK) {                                                            \
      *(int4*)&Ks[P][SWZ(lane, kw * 16)]     = r0;                        \
      *(int4*)&Ks[P][SWZ(lane, kw * 16 + 8)] = r1;                        \
    } else {                                                              \
      union { int4 v; ushort us[8]; } u0_, u1_;                           \
      u0_.v = r0; u1_.v = r1;                                             \
      _Pragma("unroll")                                                   \
      for (int e = 0; e < 8; ++e) Vt[P][SWZ(kw * 16 + e, lane)] = u0_.us[e]; \
      _Pragma("unroll")                                                   \
      for (int e = 0; e < 8; ++e) Vt[P][SWZ(kw * 16 + 8 + e, lane)] = u1_.us[e]; \
    }                                                                     \
  } while (0)

  f32x4 oacc[4];
#pragma unroll
  for (int n = 0; n < 4; ++n) oacc[n] = (f32x4)0.f;
  float mq = -1e30f, lq = 0.f;
  const int ntiles = Lk >> 6;
  const bool lowhalf = (lane < 32);
  const bool sendSelf = (hi == 1 || hi == 2);

  LOADKV(0);
  WRITEKV(0);
  int p = 0;
  for (int t = 0; t < ntiles; ++t) {
    if (t + 1 < ntiles) LOADKV(t + 1);
    __syncthreads();

    f32x4 sacc[4];
#pragma unroll
    for (int n = 0; n < 4; ++n) sacc[n] = (f32x4)0.f;
    __builtin_amdgcn_s_setprio(1);
#pragma unroll
    for (int s = 0; s < 2; ++s) {
#pragma unroll
      for (int n = 0; n < 4; ++n) {
        bf16x8 ak = *(const bf16x8*)&Ks[p][SWZ(n * 16 + fr, s * 32 + kb)];
        sacc[n] = __builtin_amdgcn_mfma_f32_16x16x32_bf16(ak, aq[s], sacc[n], 0, 0, 0);
      }
    }
    __builtin_amdgcn_s_setprio(0);

    float sm = sacc[0][0];
#pragma unroll
    for (int n = 0; n < 4; ++n)
#pragma unroll
      for (int r = 0; r < 4; ++r) sm = fmaxf(sm, sacc[n][r]);
    sm = fmaxf(sm, __shfl_xor(sm, 16));
    sm = fmaxf(sm, __shfl_xor(sm, 32));
    float mnew = fmaxf(mq, sm);
    float corrq = __expf(mq - mnew);
    mq = mnew;
    float pe[4][4];
    float psum = 0.f;
#pragma unroll
    for (int n = 0; n < 4; ++n)
#pragma unroll
      for (int r = 0; r < 4; ++r) {
        pe[n][r] = __expf(sacc[n][r] - mnew);
        psum += pe[n][r];
      }
    psum += __shfl_xor(psum, 16);
    psum += __shfl_xor(psum, 32);
    lq = lq * corrq + psum;
    float c0 = __shfl(corrq, hi * 4 + 0);
    float c1 = __shfl(corrq, hi * 4 + 1);
    float c2 = __shfl(corrq, hi * 4 + 2);
    float c3 = __shfl(corrq, hi * 4 + 3);
#pragma unroll
    for (int n = 0; n < 4; ++n) {
      oacc[n][0] *= c0; oacc[n][1] *= c1; oacc[n][2] *= c2; oacc[n][3] *= c3;
    }

    uint32 u00 = pk2(pe[0][0], pe[0][1]), u01 = pk2(pe[0][2], pe[0][3]);
    uint32 u10 = pk2(pe[1][0], pe[1][1]), u11 = pk2(pe[1][2], pe[1][3]);
    uint32 u20 = pk2(pe[2][0], pe[2][1]), u21 = pk2(pe[2][2], pe[2][3]);
    uint32 u30 = pk2(pe[3][0], pe[3][1]), u31 = pk2(pe[3][2], pe[3][3]);
    uint32 selfw0 = lowhalf ? u00 : u10;
    uint32 selfw1 = lowhalf ? u01 : u11;
    uint32 selfw2 = lowhalf ? u20 : u30;
    uint32 selfw3 = lowhalf ? u21 : u31;
    uint32 send10 = lowhalf ? u10 : u00;
    uint32 send11 = lowhalf ? u11 : u01;
    uint32 send12 = lowhalf ? u30 : u20;
    uint32 send13 = lowhalf ? u31 : u21;
    uint32 farw0 = __shfl_xor((int)send10, 32);
    uint32 farw1 = __shfl_xor((int)send11, 32);
    uint32 farw2 = __shfl_xor((int)send12, 32);
    uint32 farw3 = __shfl_xor((int)send13, 32);
    uint32 s20 = sendSelf ? selfw0 : farw0;
    uint32 s21 = sendSelf ? selfw1 : farw1;
    uint32 s22 = sendSelf ? selfw2 : farw2;
    uint32 s23 = sendSelf ? selfw3 : farw3;
    uint32 rcv0 = __shfl_xor((int)s20, 16);
    uint32 rcv1 = __shfl_xor((int)s21, 16);
    uint32 rcv2 = __shfl_xor((int)s22, 16);
    uint32 rcv3 = __shfl_xor((int)s23, 16);
    union { uint32 wd[4]; bf16x8 v; } pa0, pa1;
    if (hi == 0) {
      pa0.wd[0] = selfw0; pa0.wd[1] = selfw1; pa0.wd[2] = rcv0; pa0.wd[3] = rcv1;
      pa1.wd[0] = selfw2; pa1.wd[1] = selfw3; pa1.wd[2] = rcv2; pa1.wd[3] = rcv3;
    } else if (hi == 1) {
      pa0.wd[0] = rcv0; pa0.wd[1] = rcv1; pa0.wd[2] = farw0; pa0.wd[3] = farw1;
      pa1.wd[0] = rcv2; pa1.wd[1] = rcv3; pa1.wd[2] = farw2; pa1.wd[3] = farw3;
    } else if (hi == 2) {
      pa0.wd[0] = farw0; pa0.wd[1] = farw1; pa0.wd[2] = rcv0; pa0.wd[3] = rcv1;
      pa1.wd[0] = farw2; pa1.wd[1] = farw3; pa1.wd[2] = rcv2; pa1.wd[3] = rcv3;
    } else {
      pa0.wd[0] = rcv0; pa0.wd[1] = rcv1; pa0.wd[2] = selfw0; pa0.wd[3] = selfw1;
      pa1.wd[0] = rcv2; pa1.wd[1] = rcv3; pa1.wd[2] = selfw2; pa1.wd[3] = selfw3;
    }

    __builtin_amdgcn_s_setprio(1);
#pragma unroll
    for (int n = 0; n < 4; ++n) {
      bf16x8 bv0 = *(const bf16x8*)&Vt[p][SWZ(n * 16 + fr, 0 * 32 + kb)];
      oacc[n] = __builtin_amdgcn_mfma_f32_16x16x32_bf16(pa0.v, bv0, oacc[n], 0, 0, 0);
      bf16x8 bv1 = *(const bf16x8*)&Vt[p][SWZ(n * 16 + fr, 1 * 32 + kb)];
      oacc[n] = __builtin_amdgcn_mfma_f32_16x16x32_bf16(pa1.v, bv1, oacc[n], 0, 0, 0);
    }
    __builtin_amdgcn_s_setprio(0);

    __syncthreads();
    if (t + 1 < ntiles) WRITEKV(p ^ 1);
    p ^= 1;
  }
#undef LOADKV
#undef WRITEKV

  float linv[4];
#pragma unroll
  for (int r = 0; r < 4; ++r) linv[r] = 1.f / __shfl(lq, hi * 4 + r);
#pragma unroll
  for (int r = 0; r < 4; ++r) {
    int rl = w * 16 + hi * 4 + r;
#pragma unroll
    for (int n = 0; n < 4; ++n)
      Os[SWZ(rl, n * 16 + fr)] = f2bf(oacc[n][r] * linv[r]);
  }
  __syncthreads();
  {
    int row = tid >> 2, cbk = (tid & 3) * 16;
    ushort* op = O + (size_t)(b * Lq + q0 + row) * ldo + h * 64 + cbk;
    int4 o0 = *(const int4*)&Os[SWZ(row, cbk)];
    int4 o1 = *(const int4*)&Os[SWZ(row, cbk + 8)];
    ((int4*)op)[0] = o0;
    ((int4*)op)[1] = o1;
  }
}

// ---------------------------------------------------------------- launch
extern "C" void kernel_launch(void* const* d_in, const int* in_sizes, int n_in,
                              void* d_out, int out_size, void* d_ws, size_t ws_size,
                              hipStream_t stream) {
  const float* x_in = (const float*)d_in[0];
  const float* emb  = (const float*)d_in[1];
  const float* ctx  = (const float*)d_in[2];
  const float* n1w = (const float*)d_in[5];
  const float* n1b = (const float*)d_in[6];
  const float* n2w = (const float*)d_in[7];
  const float* n2b = (const float*)d_in[8];
  const float* n3w = (const float*)d_in[9];
  const float* n3b = (const float*)d_in[10];
  const float* qkvw = (const float*)d_in[11];
  const float* sow  = (const float*)d_in[12];
  const float* cqw  = (const float*)d_in[13];
  const float* ckw  = (const float*)d_in[14];
  const float* cvw  = (const float*)d_in[15];
  const float* cow  = (const float*)d_in[16];
  const float* f1w  = (const float*)d_in[17];
  const float* f1b  = (const float*)d_in[18];
  const float* f2w  = (const float*)d_in[19];
  const float* f2b  = (const float*)d_in[20];

  float* xcur = (float*)d_out;

  // workspace layout
  ushort* xnb  = (ushort*)d_ws;                        // 4096x1024 bf16
  ushort* big  = xnb + (size_t)4096 * 1024;            // 4096x4096 bf16 (qkv/q/h)
  ushort* obb  = big + (size_t)4096 * 4096;            // 4096x1024 bf16 (attn out)
  ushort* kvb  = obb + (size_t)4096 * 1024;            // 2048x2048 bf16 (K|V packed)
  ushort* ctxb = kvb + (size_t)2048 * 2048;            // 2048x1024 bf16 (persistent)
  float*  gball= (float*)(ctxb + (size_t)2048 * 1024); // 18*4*2048 f32
  float*  tab  = gball + 18 * 4 * 2048;                // 65536 f32
  ushort* scrW = (ushort*)(tab + 65536);               // 4096x1024 bf16 scratch
  const size_t SZ_QKV = (size_t)NL_ * 3072 * 1024;
  const size_t SZ_SQ  = (size_t)NL_ * 1024 * 1024;
  const size_t SZ_F   = (size_t)NL_ * 4096 * 1024;
  ushort* wqkv = scrW + (size_t)4096 * 1024;
  ushort* wso  = wqkv + SZ_QKV;
  ushort* wcq  = wso + SZ_SQ;
  ushort* wkv  = wcq + SZ_SQ;          // [NL][2048][1024] packed ck|cv
  ushort* wco  = wkv + 2 * SZ_SQ;
  ushort* wf1  = wco + SZ_SQ;
  ushort* wf2  = wf1 + SZ_F;
  const size_t need_full = (size_t)((char*)(wf2 + SZ_F) - (char*)d_ws);
  const bool wbfull = (ws_size >= need_full);

  hipMemcpyAsync(xcur, x_in, (size_t)B_ * L_ * D_ * sizeof(float),
                 hipMemcpyDeviceToDevice, stream);
  rope_table_kernel<<<128, 256, 0, stream>>>(tab);
  adaln_gb_all_kernel<<<9216, 256, 0, stream>>>(emb, n1w, n2w, n3w,
                                                n1b, n2b, n3b, gball);
  cvt_bf16_kernel<<<1024, 256, 0, stream>>>(ctx, ctxb,
                                            (int)((size_t)2048 * 1024 / 4));

  if (wbfull) {
    cvt_bf16_kernel<<<2048, 256, 0, stream>>>(qkvw, wqkv, (int)(SZ_QKV / 4));
    cvt_bf16_kernel<<<2048, 256, 0, stream>>>(sow,  wso,  (int)(SZ_SQ / 4));
    cvt_bf16_kernel<<<2048, 256, 0, stream>>>(cqw,  wcq,  (int)(SZ_SQ / 4));
    cvt_pack_kv_kernel<<<2048, 256, 0, stream>>>(ckw, cvw, wkv,
                                                 (int)(2 * SZ_SQ / 4));
    cvt_bf16_kernel<<<2048, 256, 0, stream>>>(cow,  wco,  (int)(SZ_SQ / 4));
    cvt_bf16_kernel<<<2048, 256, 0, stream>>>(f1w,  wf1,  (int)(SZ_F / 4));
    cvt_bf16_kernel<<<2048, 256, 0, stream>>>(f2w,  wf2,  (int)(SZ_F / 4));
  }

  auto prepW = [&](const float* src, ushort* full, size_t layerOff,
                   size_t nelem) -> const ushort* {
    if (wbfull) return full + layerOff;
    cvt_bf16_kernel<<<1024, 256, 0, stream>>>(src + layerOff, scrW,
                                              (int)(nelem / 4));
    return scrW;
  };

  const int ROWS = B_ * L_;
  const dim3 blk(256);
  const dim3 blk512(512);

  for (int i = 0; i < NL_; ++i) {
    const float* f1bi = f1b + (size_t)i * DFF_;
    const float* f2bi = f2b + (size_t)i * D_;

    // ---- self-attention block ----
    adaln_apply_kernel<<<ROWS, blk, 0, stream>>>(
        xcur, gball + (size_t)(i * 3 + 0) * 4 * 2048, xnb);
    gemm256_kernel<0, 1><<<dim3(12, 16), blk512, 0, stream>>>(       // rope q,k
        xnb, D_, prepW(qkvw, wqkv, (size_t)i * 3072 * 1024, (size_t)3072 * 1024),
        D_, nullptr, big, 3072, D_, tab, 2048, 1023);
    attn_mfma_kernel<<<dim3(L_ / 128, H_, B_), blk512, 0, stream>>>(
        big, 3072, big + 1024, 3072, big + 2048, 3072, obb, D_, L_, L_, 0.125f);
    gemm_n64_kernel<4><<<dim3(16, 32), blk, 0, stream>>>(
        obb, D_, prepW(sow, wso, (size_t)i * 1024 * 1024, (size_t)1024 * 1024),
        D_, nullptr, xcur, D_, xcur, D_, D_);

    // ---- cross-attention block ----
    adaln_apply_kernel<<<ROWS, blk, 0, stream>>>(
        xcur, gball + (size_t)(i * 3 + 1) * 4 * 2048, xnb);
    gemm_mfma_kernel<0, true, 1><<<dim3(8, 32), blk, 0, stream>>>(   // rope q
        xnb, D_, prepW(cqw, wcq, (size_t)i * 1024 * 1024, (size_t)1024 * 1024),
        D_, nullptr, nullptr, 0, big, 1024, D_, tab, 1024, 1023);
    // K|V packed GEMM: N=2048, rope on K half (cols < 1024)
    {
      const ushort* wkvi;
      if (wbfull) {
        wkvi = wkv + (size_t)i * 2048 * 1024;
      } else {
        cvt_bf16_kernel<<<512, 256, 0, stream>>>(
            ckw + (size_t)i * 1024 * 1024, scrW, (int)((size_t)1024 * 1024 / 4));
        cvt_bf16_kernel<<<512, 256, 0, stream>>>(
            cvw + (size_t)i * 1024 * 1024, scrW + (size_t)1024 * 1024,
            (int)((size_t)1024 * 1024 / 4));
        wkvi = scrW;
      }
      gemm_mfma_kernel<0, true, 1><<<dim3(16, 16), blk, 0, stream>>>(
          ctxb, D_, wkvi, D_, nullptr, nullptr, 0, kvb, 2048, D_, tab, 1024, 511);
    }
    attn_mfma_kernel<<<dim3(L_ / 128, H_, B_), blk512, 0, stream>>>(
        big, 1024, kvb, 2048, kvb + 1024, 2048, obb, D_, L_, LC_, 0.125f);
    gemm_n64_kernel<4><<<dim3(16, 32), blk, 0, stream>>>(
        obb, D_, prepW(cow, wco, (size_t)i * 1024 * 1024, (size_t)1024 * 1024),
        D_, nullptr, xcur, D_, xcur, D_, D_);

    // ---- FFN block ----
    adaln_apply_kernel<<<ROWS, blk, 0, stream>>>(
        xcur, gball + (size_t)(i * 3 + 2) * 4 * 2048, xnb);
    gemm256_kernel<3, 0><<<dim3(16, 16), blk512, 0, stream>>>(       // bias+gelu
        xnb, D_, prepW(f1w, wf1, (size_t)i * 4096 * 1024, (size_t)4096 * 1024),
        D_, f1bi, big, DFF_, D_, tab, 0, 0);
    gemm_n64_kernel<5><<<dim3(16, 32), blk, 0, stream>>>(
        big, DFF_, prepW(f2w, wf2, (size_t)i * 4096 * 1024, (size_t)4096 * 1024),
        DFF_, f2bi, xcur, D_, xcur, D_, DFF_);
  }
}

// Round 14
// 1990.328 us; speedup vs baseline: 1.0387x; 1.0387x over previous
//
#include <hip/hip_runtime.h>
#include <hip/hip_bf16.h>
#include <math.h>

// Problem constants
#define D_    1024
#define H_    16
#define HD_   64
#define NL_   6
#define DFF_  4096
#define B_    4
#define L_    1024
#define LC_   512

typedef short bf16x8 __attribute__((ext_vector_type(8)));
typedef float f32x4  __attribute__((ext_vector_type(4)));
typedef unsigned int uint32;

// ---------------------------------------------------------------- utilities
__device__ __forceinline__ float waveReduceSum(float v) {
#pragma unroll
  for (int off = 32; off > 0; off >>= 1) v += __shfl_xor(v, off);
  return v;
}
__device__ __forceinline__ ushort f2bf(float f) {
  union { __hip_bfloat16 h; ushort u; } c;
  c.h = __float2bfloat16(f);
  return c.u;
}
__device__ __forceinline__ float bf2f(ushort u) {
  union { uint32 i; float f; } c;
  c.i = ((uint32)u) << 16;
  return c.f;
}
__device__ __forceinline__ uint32 pk2(float a, float b) {
  return (uint32)f2bf(a) | ((uint32)f2bf(b) << 16);
}
// async global->LDS, 16B per lane. lds base must be wave-uniform (m104).
__device__ __forceinline__ void gload16(const ushort* g, ushort* l) {
  __builtin_amdgcn_global_load_lds(
      (const __attribute__((address_space(1))) uint32*)g,
      (__attribute__((address_space(3))) uint32*)l, 16, 0, 0);
}

// banded XCD swizzle: XCD chunk covers 4 tile-rows x (chunk/4) tile-cols.
// Requires gridDim.y % 4 == 0 and nwg % 8 == 0. Returns row,col tile indices.
__device__ __forceinline__ void xcd_banded(int& trow, int& tcol) {
  const int nwg = gridDim.x * gridDim.y;
  const int wg = blockIdx.y * gridDim.x + blockIdx.x;
  const int q = nwg >> 3;
  const int swz = (wg & 7) * q + (wg >> 3);
  const int bandw = gridDim.x * 4;
  const int band = swz / bandw;
  const int rem = swz % bandw;
  trow = band * 4 + (rem & 3);
  tcol = rem >> 2;
}

// ---------------------------------------------------------------- fp32 -> bf16 bulk convert
__global__ __launch_bounds__(256) void cvt_bf16_kernel(
    const float* __restrict__ in, ushort* __restrict__ out, int n4) {
  int i = blockIdx.x * 256 + threadIdx.x;
  int stride = gridDim.x * 256;
  for (; i < n4; i += stride) {
    float4 v = ((const float4*)in)[i];
    ushort4 o = {f2bf(v.x), f2bf(v.y), f2bf(v.z), f2bf(v.w)};
    ((ushort4*)out)[i] = o;
  }
}

// packed [NL][2048][1024]: rows 0-1023 = ck layer, 1024-2047 = cv layer
__global__ __launch_bounds__(256) void cvt_pack_kv_kernel(
    const float* __restrict__ ck, const float* __restrict__ cv,
    ushort* __restrict__ out, int n4) {
  int i = blockIdx.x * 256 + threadIdx.x;
  int stride = gridDim.x * 256;
  for (; i < n4; i += stride) {
    int row = i >> 8;               // 256 float4 per 1024-wide row
    int cb = i & 255;
    int layer = row >> 11;
    int sel = (row >> 10) & 1;
    int r = row & 1023;
    const float* src = (sel ? cv : ck) +
                       (((size_t)layer << 10) + r) * 1024 + cb * 4;
    float4 v = *(const float4*)src;
    ushort4 o = {f2bf(v.x), f2bf(v.y), f2bf(v.z), f2bf(v.w)};
    ((ushort4*)out)[i] = o;
  }
}

// ---------------------------------------------------------------- RoPE table
__global__ void rope_table_kernel(float* __restrict__ tab) {
  int t = blockIdx.x * 256 + threadIdx.x;   // [0, L_*32)
  if (t >= L_ * 32) return;
  int l = t >> 5, j = t & 31;
  float inv = powf(10000.f, -(float)j * (1.f / 32.f));
  float ang = (float)l * inv;
  tab[l * 64 + j] = cosf(ang);
  tab[l * 64 + 32 + j] = sinf(ang);
}

// ---------------------------------------------------------------- AdaLN gb, all layers in one launch
__global__ __launch_bounds__(256) void adaln_gb_all_kernel(
    const float* __restrict__ emb,
    const float* __restrict__ n1w, const float* __restrict__ n2w,
    const float* __restrict__ n3w,
    const float* __restrict__ n1b, const float* __restrict__ n2b,
    const float* __restrict__ n3b,
    float* __restrict__ gb) {
  int wid = blockIdx.x * 4 + (threadIdx.x >> 6);   // [0, 18*2048)
  int lane = threadIdx.x & 63;
  int n = wid & 2047;
  int g = wid >> 11;                 // 0..17
  int layer = g / 3, j = g - layer * 3;
  const float* wbase = (j == 0 ? n1w : (j == 1 ? n2w : n3w));
  const float* bbase = (j == 0 ? n1b : (j == 1 ? n2b : n3b));
  const float* wr = wbase + ((size_t)layer * 2048 + n) * 1024;
  float s0 = 0.f, s1 = 0.f, s2 = 0.f, s3 = 0.f;
#pragma unroll
  for (int k4 = 0; k4 < 4; ++k4) {
    int idx = k4 * 64 + lane;
    float4 w4 = ((const float4*)wr)[idx];
    float4 e0 = ((const float4*)emb)[idx];
    float4 e1 = ((const float4*)(emb + 1024))[idx];
    float4 e2 = ((const float4*)(emb + 2048))[idx];
    float4 e3 = ((const float4*)(emb + 3072))[idx];
    s0 += w4.x * e0.x + w4.y * e0.y + w4.z * e0.z + w4.w * e0.w;
    s1 += w4.x * e1.x + w4.y * e1.y + w4.z * e1.z + w4.w * e1.w;
    s2 += w4.x * e2.x + w4.y * e2.y + w4.z * e2.z + w4.w * e2.w;
    s3 += w4.x * e3.x + w4.y * e3.y + w4.z * e3.z + w4.w * e3.w;
  }
  s0 = waveReduceSum(s0);
  s1 = waveReduceSum(s1);
  s2 = waveReduceSum(s2);
  s3 = waveReduceSum(s3);
  if (lane == 0) {
    float bb = bbase[(size_t)layer * 2048 + n];
    gb[((size_t)g * 4 + 0) * 2048 + n] = s0 + bb;
    gb[((size_t)g * 4 + 1) * 2048 + n] = s1 + bb;
    gb[((size_t)g * 4 + 2) * 2048 + n] = s2 + bb;
    gb[((size_t)g * 4 + 3) * 2048 + n] = s3 + bb;
  }
}

// ---------------------------------------------------------------- AdaLN apply (bf16 out)
__global__ __launch_bounds__(256) void adaln_apply_kernel(
    const float* __restrict__ x, const float* __restrict__ gb,
    ushort* __restrict__ xn) {
  int r = blockIdx.x;
  int b = r >> 10;
  const float* xr = x + (size_t)r * D_;
  int tid = threadIdx.x;
  float4 v = *(const float4*)(xr + tid * 4);
  float s = v.x + v.y + v.z + v.w;
  float q = v.x * v.x + v.y * v.y + v.z * v.z + v.w * v.w;
  s = waveReduceSum(s);
  q = waveReduceSum(q);
  __shared__ float ssum[4], ssq[4], stats[2];
  int w = tid >> 6, lane = tid & 63;
  if (lane == 0) { ssum[w] = s; ssq[w] = q; }
  __syncthreads();
  if (tid == 0) {
    float S = ssum[0] + ssum[1] + ssum[2] + ssum[3];
    float Q = ssq[0] + ssq[1] + ssq[2] + ssq[3];
    float mean = S * (1.f / D_);
    float var = Q * (1.f / D_) - mean * mean;
    stats[0] = mean;
    stats[1] = rsqrtf(var + 1e-5f);
  }
  __syncthreads();
  float mean = stats[0], rstd = stats[1];
  const float* gp = gb + (size_t)b * 2048;
  float4 g  = *(const float4*)(gp + tid * 4);
  float4 be = *(const float4*)(gp + D_ + tid * 4);
  ushort4 o;
  o.x = f2bf((v.x - mean) * rstd * (1.f + g.x) + be.x);
  o.y = f2bf((v.y - mean) * rstd * (1.f + g.y) + be.y);
  o.z = f2bf((v.z - mean) * rstd * (1.f + g.z) + be.z);
  o.w = f2bf((v.w - mean) * rstd * (1.f + g.w) + be.w);
  *(ushort4*)(xn + (size_t)r * D_ + tid * 4) = o;
}

// ---------------------------------------------------------------- bf16 MFMA GEMM (128x128)
// depth-2 pipelined (3 LDS buffers + counted vmcnt), banded XCD swizzle,
// source-chunk LDS swizzle, padded vector epilogue, optional fused RoPE.
template <int FLAGS, bool OUTBF, int ROPE>
__global__ __launch_bounds__(256) void gemm_mfma_kernel(
    const ushort* __restrict__ A, int lda,
    const ushort* __restrict__ W, int ldw,
    const float* __restrict__ bias,
    const float* __restrict__ res, int ldres,
    void* __restrict__ Cout, int ldc, int K,
    const float* __restrict__ tab, int rlim, int lmask) {
  __shared__ __align__(16) ushort lds[24576];   // 48KB: A bufs @0, W bufs @12288
  const int tid = threadIdx.x;
  const int lane = tid & 63, wv = tid >> 6;
  const int wrow = (wv >> 1) * 64, wcol = (wv & 1) * 64;
  const int fr = lane & 15;
  const int kbs = (((lane >> 4) ^ (fr & 3)) & 3) * 8;

  int trow, tcol;
  xcd_banded(trow, tcol);
  const int row0 = trow * 128;
  const int col0 = tcol * 128;

  const int c0 = wv * 2, c1 = wv * 2 + 1;
  const int sr = lane >> 2;
  const int sc = (((lane & 3) ^ (sr & 3)) & 3) * 8;
  const ushort* Ap0 = A + (size_t)(row0 + c0 * 16 + sr) * lda + sc;
  const ushort* Ap1 = A + (size_t)(row0 + c1 * 16 + sr) * lda + sc;
  const ushort* Wp0 = W + (size_t)(col0 + c0 * 16 + sr) * ldw + sc;
  const ushort* Wp1 = W + (size_t)(col0 + c1 * 16 + sr) * ldw + sc;

  f32x4 acc[4][4];
#pragma unroll
  for (int m = 0; m < 4; ++m)
#pragma unroll
    for (int n = 0; n < 4; ++n) acc[m][n] = (f32x4)0.f;

#define ASB(B) (lds + (B) * 4096)
#define WSB(B) (lds + 12288 + (B) * 4096)
#define STAGE(B, T)                                   \
  do {                                                \
    const int koff_ = (T) * 32;                       \
    gload16(Ap0 + koff_, ASB(B) + c0 * 512);          \
    gload16(Ap1 + koff_, ASB(B) + c1 * 512);          \
    gload16(Wp0 + koff_, WSB(B) + c0 * 512);          \
    gload16(Wp1 + koff_, WSB(B) + c1 * 512);          \
  } while (0)
#define WAITV8() asm volatile("s_waitcnt vmcnt(8)" ::: "memory")
#define WAITV4() asm volatile("s_waitcnt vmcnt(4)" ::: "memory")
#define WAITV0() asm volatile("s_waitcnt vmcnt(0)" ::: "memory")
#define BAR()    __builtin_amdgcn_s_barrier()
#define COMPUTE(B)                                                          \
  do {                                                                      \
    bf16x8 af[4], bfr[4];                                                   \
    _Pragma("unroll")                                                       \
    for (int m = 0; m < 4; ++m)                                             \
      af[m] = *(const bf16x8*)(ASB(B) + (wrow + m * 16 + fr) * 32 + kbs);   \
    _Pragma("unroll")                                                       \
    for (int n = 0; n < 4; ++n)                                             \
      bfr[n] = *(const bf16x8*)(WSB(B) + (wcol + n * 16 + fr) * 32 + kbs);  \
    _Pragma("unroll")                                                       \
    for (int m = 0; m < 4; ++m)                                             \
      _Pragma("unroll")                                                     \
      for (int n = 0; n < 4; ++n)                                           \
        acc[m][n] = __builtin_amdgcn_mfma_f32_16x16x32_bf16(af[m], bfr[n],  \
                                                            acc[m][n], 0, 0, 0); \
  } while (0)

  const int NT = K >> 5;
  STAGE(0, 0);
  STAGE(1, 1);
  for (int t = 0; t < NT; t += 3) {
    {
      const bool sA = (t + 2) < NT;
      if (sA) STAGE(2, t + 2);
      if ((t + 1) < NT) { if (sA) WAITV8(); else WAITV4(); } else WAITV0();
      BAR(); COMPUTE(0); BAR();
    }
    if ((t + 1) < NT) {
      const bool sB = (t + 3) < NT;
      if (sB) STAGE(0, t + 3);
      if ((t + 2) < NT) { if (sB) WAITV8(); else WAITV4(); } else WAITV0();
      BAR(); COMPUTE(1); BAR();
    }
    if ((t + 2) < NT) {
      const bool sC = (t + 4) < NT;
      if (sC) STAGE(1, t + 4);
      if ((t + 3) < NT) { if (sC) WAITV8(); else WAITV4(); } else WAITV0();
      BAR(); COMPUTE(2); BAR();
    }
  }
#undef STAGE
#undef WAITV8
#undef WAITV4
#undef WAITV0
#undef COMPUTE

  float bn[4];
  if (FLAGS & 1) {
#pragma unroll
    for (int n = 0; n < 4; ++n) bn[n] = bias[col0 + wcol + n * 16 + fr];
  }
#define EPI(v, n)                                                     \
  do {                                                                \
    if (FLAGS & 1) (v) += bn[n];                                      \
    if (FLAGS & 2) (v) = 0.5f * (v) * (1.f + erff((v) * 0.70710678118f)); \
  } while (0)

  if (OUTBF) {
    ushort* Ct = lds;                       // [128][136] bf16 (padded)
    ushort* Cg = (ushort*)Cout;
#pragma unroll
    for (int m = 0; m < 4; ++m) {
      int lr0 = wrow + m * 16 + (lane >> 4) * 4;
#pragma unroll
      for (int n = 0; n < 4; ++n) {
        int lc = wcol + n * 16 + fr;
#pragma unroll
        for (int r = 0; r < 4; ++r) {
          float v = acc[m][n][r];
          EPI(v, n);
          Ct[(lr0 + r) * 136 + lc] = f2bf(v);
        }
      }
    }
    __syncthreads();
#pragma unroll
    for (int it = 0; it < 8; ++it) {
      int lr = (tid >> 4) + it * 16;
      int lc = (tid & 15) * 8;
      union { int4 v; ushort us[8]; } vv;
      vv.v = *(const int4*)&Ct[lr * 136 + lc];
      if (ROPE && (col0 + lc) < rlim) {
        union { int4 v; ushort us[8]; } pv;
        pv.v = *(const int4*)&Ct[lr * 136 + (lc ^ 32)];
        int l = (row0 + lr) & lmask;
        int j = lc & 31;
        const float* cb = &tab[l * 64 + j];
        bool lowhalf = (lc & 63) < 32;
#pragma unroll
        for (int e = 0; e < 8; ++e) {
          float cc = cb[e], ss = cb[32 + e];
          float xv = bf2f(vv.us[e]), xp = bf2f(pv.us[e]);
          float o = lowhalf ? (xv * cc - xp * ss) : (xp * ss + xv * cc);
          vv.us[e] = f2bf(o);
        }
      }
      *(int4*)&Cg[(size_t)(row0 + lr) * ldc + col0 + lc] = vv.v;
    }
  } else {
    float* Cf = (float*)lds;                // [64][132] f32 (padded) per half
    float* Cg = (float*)Cout;
#pragma unroll
    for (int half = 0; half < 2; ++half) {
      if ((wv >> 1) == half) {
#pragma unroll
        for (int m = 0; m < 4; ++m) {
          int lr0 = m * 16 + (lane >> 4) * 4;
#pragma unroll
          for (int n = 0; n < 4; ++n) {
            int lc = wcol + n * 16 + fr;
#pragma unroll
            for (int r = 0; r < 4; ++r) {
              float v = acc[m][n][r];
              EPI(v, n);
              Cf[(lr0 + r) * 132 + lc] = v;
            }
          }
        }
      }
      __syncthreads();
#pragma unroll
      for (int it = 0; it < 8; ++it) {
        int lr = (tid >> 5) + it * 8;
        int lc = (tid & 31) * 4;
        int grow = row0 + half * 64 + lr;
        float4 v = *(const float4*)&Cf[lr * 132 + lc];
        if (FLAGS & 4) {
          float4 rv = *(const float4*)&res[(size_t)grow * ldres + col0 + lc];
          v.x += rv.x; v.y += rv.y; v.z += rv.z; v.w += rv.w;
        }
        *(float4*)&Cg[(size_t)grow * ldc + col0 + lc] = v;
      }
      __syncthreads();
    }
  }
#undef EPI
#undef ASB
#undef WSB
#undef BAR
}

// ---------------------------------------------------------------- merged cq + (ck|cv) GEMM
// z=0: big = xnb @ cqW^T (M=4096, ldc=1024, lmask=1023, virtual grid 8x32)
// z=1: kvb = ctxb @ kvW^T (M=2048, ldc=2048, lmask=511, virtual grid 16x16)
// Both: K=1024, lda=1024, bf16-out, RoPE cols<1024. Same proven pipeline.
__global__ __launch_bounds__(256) void gemm_cqkv_kernel(
    const ushort* __restrict__ Aq, const ushort* __restrict__ Ac,
    const ushort* __restrict__ Wq, const ushort* __restrict__ Wkv,
    ushort* __restrict__ Cq, ushort* __restrict__ Ckv,
    const float* __restrict__ tab) {
  __shared__ __align__(16) ushort lds[24576];
  const int tid = threadIdx.x;
  const int lane = tid & 63, wv = tid >> 6;
  const int wrow = (wv >> 1) * 64, wcol = (wv & 1) * 64;
  const int fr = lane & 15;
  const int kbs = (((lane >> 4) ^ (fr & 3)) & 3) * 8;
  const int K = 1024, lda = 1024;

  const int z = blockIdx.z;
  const ushort* A = z ? Ac : Aq;
  const ushort* W = z ? Wkv : Wq;
  ushort* Cg = z ? Ckv : Cq;
  const int ldc = z ? 2048 : 1024;
  const int lmask = z ? 511 : 1023;
  const int vgx = z ? 16 : 8;

  // banded swizzle on the virtual grid (256 blocks per z-slice)
  const int flat = blockIdx.y * gridDim.x + blockIdx.x;   // 0..255
  const int swz = (flat & 7) * 32 + (flat >> 3);
  const int bandw = vgx * 4;
  const int band = swz / bandw;
  const int rem = swz % bandw;
  const int row0 = (band * 4 + (rem & 3)) * 128;
  const int col0 = (rem >> 2) * 128;

  const int c0 = wv * 2, c1 = wv * 2 + 1;
  const int sr = lane >> 2;
  const int sc = (((lane & 3) ^ (sr & 3)) & 3) * 8;
  const ushort* Ap0 = A + (size_t)(row0 + c0 * 16 + sr) * lda + sc;
  const ushort* Ap1 = A + (size_t)(row0 + c1 * 16 + sr) * lda + sc;
  const ushort* Wp0 = W + (size_t)(col0 + c0 * 16 + sr) * lda + sc;
  const ushort* Wp1 = W + (size_t)(col0 + c1 * 16 + sr) * lda + sc;

  f32x4 acc[4][4];
#pragma unroll
  for (int m = 0; m < 4; ++m)
#pragma unroll
    for (int n = 0; n < 4; ++n) acc[m][n] = (f32x4)0.f;

#define ASB(B) (lds + (B) * 4096)
#define WSB(B) (lds + 12288 + (B) * 4096)
#define STAGE(B, T)                                   \
  do {                                                \
    const int koff_ = (T) * 32;                       \
    gload16(Ap0 + koff_, ASB(B) + c0 * 512);          \
    gload16(Ap1 + koff_, ASB(B) + c1 * 512);          \
    gload16(Wp0 + koff_, WSB(B) + c0 * 512);          \
    gload16(Wp1 + koff_, WSB(B) + c1 * 512);          \
  } while (0)
#define WAITV8() asm volatile("s_waitcnt vmcnt(8)" ::: "memory")
#define WAITV4() asm volatile("s_waitcnt vmcnt(4)" ::: "memory")
#define WAITV0() asm volatile("s_waitcnt vmcnt(0)" ::: "memory")
#define BAR()    __builtin_amdgcn_s_barrier()
#define COMPUTE(B)                                                          \
  do {                                                                      \
    bf16x8 af[4], bfr[4];                                                   \
    _Pragma("unroll")                                                       \
    for (int m = 0; m < 4; ++m)                                             \
      af[m] = *(const bf16x8*)(ASB(B) + (wrow + m * 16 + fr) * 32 + kbs);   \
    _Pragma("unroll")                                                       \
    for (int n = 0; n < 4; ++n)                                             \
      bfr[n] = *(const bf16x8*)(WSB(B) + (wcol + n * 16 + fr) * 32 + kbs);  \
    _Pragma("unroll")                                                       \
    for (int m = 0; m < 4; ++m)                                             \
      _Pragma("unroll")                                                     \
      for (int n = 0; n < 4; ++n)                                           \
        acc[m][n] = __builtin_amdgcn_mfma_f32_16x16x32_bf16(af[m], bfr[n],  \
                                                            acc[m][n], 0, 0, 0); \
  } while (0)

  const int NT = K >> 5;   // 32
  STAGE(0, 0);
  STAGE(1, 1);
  for (int t = 0; t < NT; t += 3) {
    {
      const bool sA = (t + 2) < NT;
      if (sA) STAGE(2, t + 2);
      if ((t + 1) < NT) { if (sA) WAITV8(); else WAITV4(); } else WAITV0();
      BAR(); COMPUTE(0); BAR();
    }
    if ((t + 1) < NT) {
      const bool sB = (t + 3) < NT;
      if (sB) STAGE(0, t + 3);
      if ((t + 2) < NT) { if (sB) WAITV8(); else WAITV4(); } else WAITV0();
      BAR(); COMPUTE(1); BAR();
    }
    if ((t + 2) < NT) {
      const bool sC = (t + 4) < NT;
      if (sC) STAGE(1, t + 4);
      if ((t + 3) < NT) { if (sC) WAITV8(); else WAITV4(); } else WAITV0();
      BAR(); COMPUTE(2); BAR();
    }
  }
#undef STAGE
#undef WAITV8
#undef WAITV4
#undef WAITV0
#undef COMPUTE

  // bf16 epilogue with fused RoPE (cols < 1024)
  ushort* Ct = lds;                       // [128][136]
#pragma unroll
  for (int m = 0; m < 4; ++m) {
    int lr0 = wrow + m * 16 + (lane >> 4) * 4;
#pragma unroll
    for (int n = 0; n < 4; ++n) {
      int lc = wcol + n * 16 + fr;
#pragma unroll
      for (int r = 0; r < 4; ++r)
        Ct[(lr0 + r) * 136 + lc] = f2bf(acc[m][n][r]);
    }
  }
  __syncthreads();
#pragma unroll
  for (int it = 0; it < 8; ++it) {
    int lr = (tid >> 4) + it * 16;
    int lc = (tid & 15) * 8;
    union { int4 v; ushort us[8]; } vv;
    vv.v = *(const int4*)&Ct[lr * 136 + lc];
    if ((col0 + lc) < 1024) {
      union { int4 v; ushort us[8]; } pv;
      pv.v = *(const int4*)&Ct[lr * 136 + (lc ^ 32)];
      int l = (row0 + lr) & lmask;
      int j = lc & 31;
      const float* cb = &tab[l * 64 + j];
      bool lowhalf = (lc & 63) < 32;
#pragma unroll
      for (int e = 0; e < 8; ++e) {
        float cc = cb[e], ss = cb[32 + e];
        float xv = bf2f(vv.us[e]), xp = bf2f(pv.us[e]);
        float o = lowhalf ? (xv * cc - xp * ss) : (xp * ss + xv * cc);
        vv.us[e] = f2bf(o);
      }
    }
    *(int4*)&Cg[(size_t)(row0 + lr) * ldc + col0 + lc] = vv.v;
  }
#undef ASB
#undef WSB
#undef BAR
}

// ---------------------------------------------------------------- 256x256 8-wave GEMM
// BK=64, double-buffered 128KB LDS, one barrier + one late vmcnt(0) per K-tile;
// banded XCD swizzle; chunk-XOR LDS swizzle; setprio around MFMA. bf16 out.
// Epilogue: linear [256][256] LDS tile -> vector stores.
// FLAGS: 1=+bias, 2=gelu. Requires K%64==0, M,N%256==0, gridDim.y%4==0.
template <int FLAGS, int ROPE>
__global__ __launch_bounds__(512, 2) void gemm256_kernel(
    const ushort* __restrict__ A, int lda,
    const ushort* __restrict__ W, int ldw,
    const float* __restrict__ bias,
    ushort* __restrict__ Cout, int ldc, int K,
    const float* __restrict__ tab, int rlim, int lmask) {
  __shared__ __align__(16) ushort lds[65536];   // 128 KB
  const int tid = threadIdx.x;
  const int lane = tid & 63, wid = tid >> 6;
  const int wm = wid >> 2, wn = wid & 3;        // 2 x 4 wave grid
  const int fr = lane & 15, hi = lane >> 4;

  int trow, tcol;
  xcd_banded(trow, tcol);
  const int row0 = trow * 256;
  const int col0 = tcol * 256;

  const int srow = lane >> 3;
  const int scol = ((lane & 7) ^ srow) * 8;
  const ushort* Asrc[4];
  const ushort* Wsrc[4];
#pragma unroll
  for (int j = 0; j < 4; ++j) {
    int r = wid * 32 + j * 8 + srow;
    Asrc[j] = A + (size_t)(row0 + r) * lda + scol;
    Wsrc[j] = W + (size_t)(col0 + r) * ldw + scol;
  }
#define AB256(b) (lds + (b) * 16384)
#define WB256(b) (lds + 32768 + (b) * 16384)
#define STG256(b, T)                                      \
  do {                                                    \
    const int kk_ = (T) * 64;                             \
    _Pragma("unroll")                                     \
    for (int j = 0; j < 4; ++j) {                         \
      int ch_ = wid * 4 + j;                              \
      gload16(Asrc[j] + kk_, AB256(b) + ch_ * 512);       \
      gload16(Wsrc[j] + kk_, WB256(b) + ch_ * 512);       \
    }                                                     \
  } while (0)

  f32x4 acc[8][4];
#pragma unroll
  for (int m = 0; m < 8; ++m)
#pragma unroll
    for (int n = 0; n < 4; ++n) acc[m][n] = (f32x4)0.f;

  const int NT = K >> 6;
  STG256(0, 0);
  asm volatile("s_waitcnt vmcnt(0)" ::: "memory");
  __builtin_amdgcn_s_barrier();
  for (int t = 0; t < NT; ++t) {
    const int cur = t & 1;
    if (t + 1 < NT) STG256(cur ^ 1, t + 1);   // issue BEFORE compute
    const ushort* ab = AB256(cur);
    const ushort* wb = WB256(cur);
    __builtin_amdgcn_s_setprio(1);
#pragma unroll
    for (int s = 0; s < 2; ++s) {
      bf16x8 wf[4];
#pragma unroll
      for (int n = 0; n < 4; ++n) {
        int row = wn * 64 + n * 16 + fr;
        wf[n] = *(const bf16x8*)(wb + row * 64 + (((s * 4 + hi) ^ (fr & 7)) * 8));
      }
#pragma unroll
      for (int m = 0; m < 8; ++m) {
        int row = wm * 128 + m * 16 + fr;
        bf16x8 af = *(const bf16x8*)(ab + row * 64 + (((s * 4 + hi) ^ (fr & 7)) * 8));
#pragma unroll
        for (int n = 0; n < 4; ++n)
          acc[m][n] = __builtin_amdgcn_mfma_f32_16x16x32_bf16(af, wf[n],
                                                              acc[m][n], 0, 0, 0);
      }
    }
    __builtin_amdgcn_s_setprio(0);
    asm volatile("s_waitcnt vmcnt(0)" ::: "memory");
    __builtin_amdgcn_s_barrier();
  }
#undef STG256

  float bn[4];
  if (FLAGS & 1) {
#pragma unroll
    for (int n = 0; n < 4; ++n) bn[n] = bias[col0 + wn * 64 + n * 16 + fr];
  }
  ushort* Ct = lds;
#pragma unroll
  for (int m = 0; m < 8; ++m) {
    int lr0 = wm * 128 + m * 16 + hi * 4;
#pragma unroll
    for (int n = 0; n < 4; ++n) {
      int lc = wn * 64 + n * 16 + fr;
#pragma unroll
      for (int r = 0; r < 4; ++r) {
        float v = acc[m][n][r];
        if (FLAGS & 1) v += bn[n];
        if (FLAGS & 2) v = 0.5f * v * (1.f + erff(v * 0.70710678118f));
        Ct[(lr0 + r) * 256 + lc] = f2bf(v);
      }
    }
  }
  __syncthreads();
#pragma unroll
  for (int it = 0; it < 16; ++it) {
    int idx = tid + it * 512;
    int lr = idx >> 5;
    int lc = (idx & 31) * 8;
    union { int4 v; ushort us[8]; } vv;
    vv.v = *(const int4*)&Ct[lr * 256 + lc];
    if (ROPE && (col0 + lc) < rlim) {
      union { int4 v; ushort us[8]; } pv;
      pv.v = *(const int4*)&Ct[lr * 256 + (lc ^ 32)];
      int l = (row0 + lr) & lmask;
      int j = lc & 31;
      const float* cb = &tab[l * 64 + j];
      bool lowhalf = (lc & 63) < 32;
#pragma unroll
      for (int e = 0; e < 8; ++e) {
        float cc = cb[e], ss = cb[32 + e];
        float xv = bf2f(vv.us[e]), xp = bf2f(pv.us[e]);
        float o = lowhalf ? (xv * cc - xp * ss) : (xp * ss + xv * cc);
        vv.us[e] = f2bf(o);
      }
    }
    *(int4*)&Cout[(size_t)(row0 + lr) * ldc + col0 + lc] = vv.v;
  }
#undef AB256
#undef WB256
}

// ---------------------------------------------------------------- MFMA flash attention
// 128 q-rows/block, 8 waves: waves 0-3 stage K, waves 4-7 stage V (transposed).
// Swapped QK^T, register-exchange P, K/V dbuf + async-stage.
#define SWZ(row, col) (((row) << 6) + ((col) ^ (((row) & 7) << 3)))
__global__ __launch_bounds__(512) void attn_mfma_kernel(
    const ushort* __restrict__ Q, int ldq,
    const ushort* __restrict__ K, int ldk,
    const ushort* __restrict__ V, int ldv,
    ushort* __restrict__ O, int ldo,
    int Lq, int Lk, float scale) {
  __shared__ __align__(16) ushort Ks[2][64 * 64];
  __shared__ __align__(16) ushort Vt[2][64 * 64];
  __shared__ __align__(16) ushort Os[128 * 64];
  const int tid = threadIdx.x;
  const int lane = tid & 63, w = tid >> 6;       // w in 0..7
  const int fr = lane & 15, hi = lane >> 4, kb = hi * 8;
  const int b = blockIdx.z, h = blockIdx.y, q0 = blockIdx.x * 128;
  const int kw = w & 3;
  const bool isK = (w < 4);

  bf16x8 aq[2];
  {
    const ushort* qp = Q + (size_t)(b * Lq + q0 + w * 16 + fr) * ldq + h * 64 + kb;
    union { bf16x8 v; ushort us[8]; } t0, t1;
    t0.v = *(const bf16x8*)qp;
    t1.v = *(const bf16x8*)(qp + 32);
#pragma unroll
    for (int e = 0; e < 8; ++e) {
      t0.us[e] = f2bf(bf2f(t0.us[e]) * scale);
      t1.us[e] = f2bf(bf2f(t1.us[e]) * scale);
    }
    aq[0] = t0.v;
    aq[1] = t1.v;
  }

  const int ldkv = isK ? ldk : ldv;
  const ushort* kvbase = (isK ? K : V) + (size_t)(b * Lk + lane) * ldkv
                         + h * 64 + kw * 16;
  const size_t kvstep = (size_t)64 * ldkv;
  int4 r0, r1;
#define LOADKV(T)                                      \
  do {                                                 \
    const ushort* p_ = kvbase + (size_t)(T) * kvstep;  \
    r0 = ((const int4*)p_)[0];                         \
    r1 = ((const int4*)p_)[1];                         \
  } while (0)
#define WRITEKV(P)                                                        \
  do {                                                                    \
    if (isK) {                                                            \
      *(int4*)&Ks[P][SWZ(lane, kw * 16)]     = r0;                        \
      *(int4*)&Ks[P][SWZ(lane, kw * 16 + 8)] = r1;                        \
    } else {                                                              \
      union { int4 v; ushort us[8]; } u0_, u1_;                           \
      u0_.v = r0; u1_.v = r1;                                             \
      _Pragma("unroll")                                                   \
      for (int e = 0; e < 8; ++e) Vt[P][SWZ(kw * 16 + e, lane)] = u0_.us[e]; \
      _Pragma("unroll")                                                   \
      for (int e = 0; e < 8; ++e) Vt[P][SWZ(kw * 16 + 8 + e, lane)] = u1_.us[e]; \
    }                                                                     \
  } while (0)

  f32x4 oacc[4];
#pragma unroll
  for (int n = 0; n < 4; ++n) oacc[n] = (f32x4)0.f;
  float mq = -1e30f, lq = 0.f;
  const int ntiles = Lk >> 6;
  const bool lowhalf = (lane < 32);
  const bool sendSelf = (hi == 1 || hi == 2);

  LOADKV(0);
  WRITEKV(0);
  int p = 0;
  for (int t = 0; t < ntiles; ++t) {
    if (t + 1 < ntiles) LOADKV(t + 1);
    __syncthreads();

    f32x4 sacc[4];
#pragma unroll
    for (int n = 0; n < 4; ++n) sacc[n] = (f32x4)0.f;
    __builtin_amdgcn_s_setprio(1);
#pragma unroll
    for (int s = 0; s < 2; ++s) {
#pragma unroll
      for (int n = 0; n < 4; ++n) {
        bf16x8 ak = *(const bf16x8*)&Ks[p][SWZ(n * 16 + fr, s * 32 + kb)];
        sacc[n] = __builtin_amdgcn_mfma_f32_16x16x32_bf16(ak, aq[s], sacc[n], 0, 0, 0);
      }
    }
    __builtin_amdgcn_s_setprio(0);

    float sm = sacc[0][0];
#pragma unroll
    for (int n = 0; n < 4; ++n)
#pragma unroll
      for (int r = 0; r < 4; ++r) sm = fmaxf(sm, sacc[n][r]);
    sm = fmaxf(sm, __shfl_xor(sm, 16));
    sm = fmaxf(sm, __shfl_xor(sm, 32));
    float mnew = fmaxf(mq, sm);
    float corrq = __expf(mq - mnew);
    mq = mnew;
    float pe[4][4];
    float psum = 0.f;
#pragma unroll
    for (int n = 0; n < 4; ++n)
#pragma unroll
      for (int r = 0; r < 4; ++r) {
        pe[n][r] = __expf(sacc[n][r] - mnew);
        psum += pe[n][r];
      }
    psum += __shfl_xor(psum, 16);
    psum += __shfl_xor(psum, 32);
    lq = lq * corrq + psum;
    float c0 = __shfl(corrq, hi * 4 + 0);
    float c1 = __shfl(corrq, hi * 4 + 1);
    float c2 = __shfl(corrq, hi * 4 + 2);
    float c3 = __shfl(corrq, hi * 4 + 3);
#pragma unroll
    for (int n = 0; n < 4; ++n) {
      oacc[n][0] *= c0; oacc[n][1] *= c1; oacc[n][2] *= c2; oacc[n][3] *= c3;
    }

    uint32 u00 = pk2(pe[0][0], pe[0][1]), u01 = pk2(pe[0][2], pe[0][3]);
    uint32 u10 = pk2(pe[1][0], pe[1][1]), u11 = pk2(pe[1][2], pe[1][3]);
    uint32 u20 = pk2(pe[2][0], pe[2][1]), u21 = pk2(pe[2][2], pe[2][3]);
    uint32 u30 = pk2(pe[3][0], pe[3][1]), u31 = pk2(pe[3][2], pe[3][3]);
    uint32 selfw0 = lowhalf ? u00 : u10;
    uint32 selfw1 = lowhalf ? u01 : u11;
    uint32 selfw2 = lowhalf ? u20 : u30;
    uint32 selfw3 = lowhalf ? u21 : u31;
    uint32 send10 = lowhalf ? u10 : u00;
    uint32 send11 = lowhalf ? u11 : u01;
    uint32 send12 = lowhalf ? u30 : u20;
    uint32 send13 = lowhalf ? u31 : u21;
    uint32 farw0 = __shfl_xor((int)send10, 32);
    uint32 farw1 = __shfl_xor((int)send11, 32);
    uint32 farw2 = __shfl_xor((int)send12, 32);
    uint32 farw3 = __shfl_xor((int)send13, 32);
    uint32 s20 = sendSelf ? selfw0 : farw0;
    uint32 s21 = sendSelf ? selfw1 : farw1;
    uint32 s22 = sendSelf ? selfw2 : farw2;
    uint32 s23 = sendSelf ? selfw3 : farw3;
    uint32 rcv0 = __shfl_xor((int)s20, 16);
    uint32 rcv1 = __shfl_xor((int)s21, 16);
    uint32 rcv2 = __shfl_xor((int)s22, 16);
    uint32 rcv3 = __shfl_xor((int)s23, 16);
    union { uint32 wd[4]; bf16x8 v; } pa0, pa1;
    if (hi == 0) {
      pa0.wd[0] = selfw0; pa0.wd[1] = selfw1; pa0.wd[2] = rcv0; pa0.wd[3] = rcv1;
      pa1.wd[0] = selfw2; pa1.wd[1] = selfw3; pa1.wd[2] = rcv2; pa1.wd[3] = rcv3;
    } else if (hi == 1) {
      pa0.wd[0] = rcv0; pa0.wd[1] = rcv1; pa0.wd[2] = farw0; pa0.wd[3] = farw1;
      pa1.wd[0] = rcv2; pa1.wd[1] = rcv3; pa1.wd[2] = farw2; pa1.wd[3] = farw3;
    } else if (hi == 2) {
      pa0.wd[0] = farw0; pa0.wd[1] = farw1; pa0.wd[2] = rcv0; pa0.wd[3] = rcv1;
      pa1.wd[0] = farw2; pa1.wd[1] = farw3; pa1.wd[2] = rcv2; pa1.wd[3] = rcv3;
    } else {
      pa0.wd[0] = rcv0; pa0.wd[1] = rcv1; pa0.wd[2] = selfw0; pa0.wd[3] = selfw1;
      pa1.wd[0] = rcv2; pa1.wd[1] = rcv3; pa1.wd[2] = selfw2; pa1.wd[3] = selfw3;
    }

    __builtin_amdgcn_s_setprio(1);
#pragma unroll
    for (int n = 0; n < 4; ++n) {
      bf16x8 bv0 = *(const bf16x8*)&Vt[p][SWZ(n * 16 + fr, 0 * 32 + kb)];
      oacc[n] = __builtin_amdgcn_mfma_f32_16x16x32_bf16(pa0.v, bv0, oacc[n], 0, 0, 0);
      bf16x8 bv1 = *(const bf16x8*)&Vt[p][SWZ(n * 16 + fr, 1 * 32 + kb)];
      oacc[n] = __builtin_amdgcn_mfma_f32_16x16x32_bf16(pa1.v, bv1, oacc[n], 0, 0, 0);
    }
    __builtin_amdgcn_s_setprio(0);

    __syncthreads();
    if (t + 1 < ntiles) WRITEKV(p ^ 1);
    p ^= 1;
  }
#undef LOADKV
#undef WRITEKV

  float linv[4];
#pragma unroll
  for (int r = 0; r < 4; ++r) linv[r] = 1.f / __shfl(lq, hi * 4 + r);
#pragma unroll
  for (int r = 0; r < 4; ++r) {
    int rl = w * 16 + hi * 4 + r;
#pragma unroll
    for (int n = 0; n < 4; ++n)
      Os[SWZ(rl, n * 16 + fr)] = f2bf(oacc[n][r] * linv[r]);
  }
  __syncthreads();
  {
    int row = tid >> 2, cbk = (tid & 3) * 16;
    ushort* op = O + (size_t)(b * Lq + q0 + row) * ldo + h * 64 + cbk;
    int4 o0 = *(const int4*)&Os[SWZ(row, cbk)];
    int4 o1 = *(const int4*)&Os[SWZ(row, cbk + 8)];
    ((int4*)op)[0] = o0;
    ((int4*)op)[1] = o1;
  }
}

// ---------------------------------------------------------------- launch
extern "C" void kernel_launch(void* const* d_in, const int* in_sizes, int n_in,
                              void* d_out, int out_size, void* d_ws, size_t ws_size,
                              hipStream_t stream) {
  const float* x_in = (const float*)d_in[0];
  const float* emb  = (const float*)d_in[1];
  const float* ctx  = (const float*)d_in[2];
  const float* n1w = (const float*)d_in[5];
  const float* n1b = (const float*)d_in[6];
  const float* n2w = (const float*)d_in[7];
  const float* n2b = (const float*)d_in[8];
  const float* n3w = (const float*)d_in[9];
  const float* n3b = (const float*)d_in[10];
  const float* qkvw = (const float*)d_in[11];
  const float* sow  = (const float*)d_in[12];
  const float* cqw  = (const float*)d_in[13];
  const float* ckw  = (const float*)d_in[14];
  const float* cvw  = (const float*)d_in[15];
  const float* cow  = (const float*)d_in[16];
  const float* f1w  = (const float*)d_in[17];
  const float* f1b  = (const float*)d_in[18];
  const float* f2w  = (const float*)d_in[19];
  const float* f2b  = (const float*)d_in[20];

  float* xcur = (float*)d_out;

  // workspace layout
  ushort* xnb  = (ushort*)d_ws;                        // 4096x1024 bf16
  ushort* big  = xnb + (size_t)4096 * 1024;            // 4096x4096 bf16 (qkv/q/h)
  ushort* obb  = big + (size_t)4096 * 4096;            // 4096x1024 bf16 (attn out)
  ushort* kvb  = obb + (size_t)4096 * 1024;            // 2048x2048 bf16 (K|V packed)
  ushort* ctxb = kvb + (size_t)2048 * 2048;            // 2048x1024 bf16 (persistent)
  float*  gball= (float*)(ctxb + (size_t)2048 * 1024); // 18*4*2048 f32
  float*  tab  = gball + 18 * 4 * 2048;                // 65536 f32
  ushort* scrW = (ushort*)(tab + 65536);               // 4096x1024 bf16 scratch
  const size_t SZ_QKV = (size_t)NL_ * 3072 * 1024;
  const size_t SZ_SQ  = (size_t)NL_ * 1024 * 1024;
  const size_t SZ_F   = (size_t)NL_ * 4096 * 1024;
  const size_t M1 = (size_t)1024 * 1024;
  ushort* wqkv = scrW + (size_t)4096 * 1024;
  ushort* wso  = wqkv + SZ_QKV;
  ushort* wcq  = wso + SZ_SQ;
  ushort* wkv  = wcq + SZ_SQ;          // [NL][2048][1024] packed ck|cv
  ushort* wco  = wkv + 2 * SZ_SQ;
  ushort* wf1  = wco + SZ_SQ;
  ushort* wf2  = wf1 + SZ_F;
  const size_t need_full = (size_t)((char*)(wf2 + SZ_F) - (char*)d_ws);
  const bool wbfull = (ws_size >= need_full);

  hipMemcpyAsync(xcur, x_in, (size_t)B_ * L_ * D_ * sizeof(float),
                 hipMemcpyDeviceToDevice, stream);
  rope_table_kernel<<<128, 256, 0, stream>>>(tab);
  adaln_gb_all_kernel<<<9216, 256, 0, stream>>>(emb, n1w, n2w, n3w,
                                                n1b, n2b, n3b, gball);
  cvt_bf16_kernel<<<1024, 256, 0, stream>>>(ctx, ctxb,
                                            (int)((size_t)2048 * 1024 / 4));

  if (wbfull) {
    cvt_bf16_kernel<<<2048, 256, 0, stream>>>(qkvw, wqkv, (int)(SZ_QKV / 4));
    cvt_bf16_kernel<<<2048, 256, 0, stream>>>(sow,  wso,  (int)(SZ_SQ / 4));
    cvt_bf16_kernel<<<2048, 256, 0, stream>>>(cqw,  wcq,  (int)(SZ_SQ / 4));
    cvt_pack_kv_kernel<<<2048, 256, 0, stream>>>(ckw, cvw, wkv,
                                                 (int)(2 * SZ_SQ / 4));
    cvt_bf16_kernel<<<2048, 256, 0, stream>>>(cow,  wco,  (int)(SZ_SQ / 4));
    cvt_bf16_kernel<<<2048, 256, 0, stream>>>(f1w,  wf1,  (int)(SZ_F / 4));
    cvt_bf16_kernel<<<2048, 256, 0, stream>>>(f2w,  wf2,  (int)(SZ_F / 4));
  }

  auto prepW = [&](const float* src, ushort* full, size_t layerOff,
                   size_t nelem) -> const ushort* {
    if (wbfull) return full + layerOff;
    cvt_bf16_kernel<<<1024, 256, 0, stream>>>(src + layerOff, scrW,
                                              (int)(nelem / 4));
    return scrW;
  };

  const int ROWS = B_ * L_;
  const dim3 blk(256);
  const dim3 blk512(512);

  for (int i = 0; i < NL_; ++i) {
    const float* f1bi = f1b + (size_t)i * DFF_;
    const float* f2bi = f2b + (size_t)i * D_;

    // ---- self-attention block ----
    adaln_apply_kernel<<<ROWS, blk, 0, stream>>>(
        xcur, gball + (size_t)(i * 3 + 0) * 4 * 2048, xnb);
    gemm256_kernel<0, 1><<<dim3(12, 16), blk512, 0, stream>>>(       // rope q,k
        xnb, D_, prepW(qkvw, wqkv, (size_t)i * 3072 * 1024, (size_t)3072 * 1024),
        D_, nullptr, big, 3072, D_, tab, 2048, 1023);
    attn_mfma_kernel<<<dim3(L_ / 128, H_, B_), blk512, 0, stream>>>(
        big, 3072, big + 1024, 3072, big + 2048, 3072, obb, D_, L_, L_, 0.125f);
    gemm_mfma_kernel<4, false, 0><<<dim3(8, 32), blk, 0, stream>>>(
        obb, D_, prepW(sow, wso, (size_t)i * M1, M1),
        D_, nullptr, xcur, D_, xcur, D_, D_, tab, 0, 0);

    // ---- cross-attention block ----
    adaln_apply_kernel<<<ROWS, blk, 0, stream>>>(
        xcur, gball + (size_t)(i * 3 + 1) * 4 * 2048, xnb);
    // merged cq + (ck|cv) projections (rope on q and k halves)
    {
      const ushort *wcqi, *wkvi;
      if (wbfull) {
        wcqi = wcq + (size_t)i * M1;
        wkvi = wkv + (size_t)i * 2 * M1;
      } else {
        cvt_bf16_kernel<<<512, 256, 0, stream>>>(cqw + (size_t)i * M1, scrW,
                                                 (int)(M1 / 4));
        cvt_bf16_kernel<<<512, 256, 0, stream>>>(ckw + (size_t)i * M1,
                                                 scrW + M1, (int)(M1 / 4));
        cvt_bf16_kernel<<<512, 256, 0, stream>>>(cvw + (size_t)i * M1,
                                                 scrW + 2 * M1, (int)(M1 / 4));
        wcqi = scrW;
        wkvi = scrW + M1;
      }
      gemm_cqkv_kernel<<<dim3(16, 16, 2), blk, 0, stream>>>(
          xnb, ctxb, wcqi, wkvi, big, kvb, tab);
    }
    attn_mfma_kernel<<<dim3(L_ / 128, H_, B_), blk512, 0, stream>>>(
        big, 1024, kvb, 2048, kvb + 1024, 2048, obb, D_, L_, LC_, 0.125f);
    gemm_mfma_kernel<4, false, 0><<<dim3(8, 32), blk, 0, stream>>>(
        obb, D_, prepW(cow, wco, (size_t)i * M1, M1),
        D_, nullptr, xcur, D_, xcur, D_, D_, tab, 0, 0);

    // ---- FFN block ----
    adaln_apply_kernel<<<ROWS, blk, 0, stream>>>(
        xcur, gball + (size_t)(i * 3 + 2) * 4 * 2048, xnb);
    gemm256_kernel<3, 0><<<dim3(16, 16), blk512, 0, stream>>>(       // bias+gelu
        xnb, D_, prepW(f1w, wf1, (size_t)i * 4096 * 1024, (size_t)4096 * 1024),
        D_, f1bi, big, DFF_, D_, tab, 0, 0);
    gemm_mfma_kernel<5, false, 0><<<dim3(8, 32), blk, 0, stream>>>(
        big, DFF_, prepW(f2w, wf2, (size_t)i * 4096 * 1024, (size_t)4096 * 1024),
        DFF_, f2bi, xcur, D_, xcur, D_, DFF_, tab, 0, 0);
  }
}

// Round 15
// 1977.056 us; speedup vs baseline: 1.0457x; 1.0067x over previous
//
#include <hip/hip_runtime.h>
#include <hip/hip_bf16.h>
#include <math.h>

// Problem constants
#define D_    1024
#define H_    16
#define HD_   64
#define NL_   6
#define DFF_  4096
#define B_    4
#define L_    1024
#define LC_   512

typedef short bf16x8 __attribute__((ext_vector_type(8)));
typedef float f32x4  __attribute__((ext_vector_type(4)));
typedef unsigned int uint32;

// ---------------------------------------------------------------- utilities
__device__ __forceinline__ float waveReduceSum(float v) {
#pragma unroll
  for (int off = 32; off > 0; off >>= 1) v += __shfl_xor(v, off);
  return v;
}
__device__ __forceinline__ ushort f2bf(float f) {
  union { __hip_bfloat16 h; ushort u; } c;
  c.h = __float2bfloat16(f);
  return c.u;
}
__device__ __forceinline__ float bf2f(ushort u) {
  union { uint32 i; float f; } c;
  c.i = ((uint32)u) << 16;
  return c.f;
}
__device__ __forceinline__ uint32 pk2(float a, float b) {
  return (uint32)f2bf(a) | ((uint32)f2bf(b) << 16);
}
// async global->LDS, 16B per lane. lds base must be wave-uniform (m104).
__device__ __forceinline__ void gload16(const ushort* g, ushort* l) {
  __builtin_amdgcn_global_load_lds(
      (const __attribute__((address_space(1))) uint32*)g,
      (__attribute__((address_space(3))) uint32*)l, 16, 0, 0);
}

// banded XCD swizzle: XCD chunk covers 4 tile-rows x (chunk/4) tile-cols.
// Requires gridDim.y % 4 == 0 and nwg % 8 == 0. Returns row,col tile indices.
__device__ __forceinline__ void xcd_banded(int& trow, int& tcol) {
  const int nwg = gridDim.x * gridDim.y;
  const int wg = blockIdx.y * gridDim.x + blockIdx.x;
  const int q = nwg >> 3;
  const int swz = (wg & 7) * q + (wg >> 3);
  const int bandw = gridDim.x * 4;
  const int band = swz / bandw;
  const int rem = swz % bandw;
  trow = band * 4 + (rem & 3);
  tcol = rem >> 2;
}

// ---------------------------------------------------------------- fp32 -> bf16 bulk convert
__global__ __launch_bounds__(256) void cvt_bf16_kernel(
    const float* __restrict__ in, ushort* __restrict__ out, int n4) {
  int i = blockIdx.x * 256 + threadIdx.x;
  int stride = gridDim.x * 256;
  for (; i < n4; i += stride) {
    float4 v = ((const float4*)in)[i];
    ushort4 o = {f2bf(v.x), f2bf(v.y), f2bf(v.z), f2bf(v.w)};
    ((ushort4*)out)[i] = o;
  }
}

// packed [NL][2048][1024]: rows 0-1023 = ck layer, 1024-2047 = cv layer
__global__ __launch_bounds__(256) void cvt_pack_kv_kernel(
    const float* __restrict__ ck, const float* __restrict__ cv,
    ushort* __restrict__ out, int n4) {
  int i = blockIdx.x * 256 + threadIdx.x;
  int stride = gridDim.x * 256;
  for (; i < n4; i += stride) {
    int row = i >> 8;               // 256 float4 per 1024-wide row
    int cb = i & 255;
    int layer = row >> 11;
    int sel = (row >> 10) & 1;
    int r = row & 1023;
    const float* src = (sel ? cv : ck) +
                       (((size_t)layer << 10) + r) * 1024 + cb * 4;
    float4 v = *(const float4*)src;
    ushort4 o = {f2bf(v.x), f2bf(v.y), f2bf(v.z), f2bf(v.w)};
    ((ushort4*)out)[i] = o;
  }
}

// ---------------------------------------------------------------- RoPE table
__global__ void rope_table_kernel(float* __restrict__ tab) {
  int t = blockIdx.x * 256 + threadIdx.x;   // [0, L_*32)
  if (t >= L_ * 32) return;
  int l = t >> 5, j = t & 31;
  float inv = powf(10000.f, -(float)j * (1.f / 32.f));
  float ang = (float)l * inv;
  tab[l * 64 + j] = cosf(ang);
  tab[l * 64 + 32 + j] = sinf(ang);
}

// ---------------------------------------------------------------- AdaLN gb, all layers in one launch
__global__ __launch_bounds__(256) void adaln_gb_all_kernel(
    const float* __restrict__ emb,
    const float* __restrict__ n1w, const float* __restrict__ n2w,
    const float* __restrict__ n3w,
    const float* __restrict__ n1b, const float* __restrict__ n2b,
    const float* __restrict__ n3b,
    float* __restrict__ gb) {
  int wid = blockIdx.x * 4 + (threadIdx.x >> 6);   // [0, 18*2048)
  int lane = threadIdx.x & 63;
  int n = wid & 2047;
  int g = wid >> 11;                 // 0..17
  int layer = g / 3, j = g - layer * 3;
  const float* wbase = (j == 0 ? n1w : (j == 1 ? n2w : n3w));
  const float* bbase = (j == 0 ? n1b : (j == 1 ? n2b : n3b));
  const float* wr = wbase + ((size_t)layer * 2048 + n) * 1024;
  float s0 = 0.f, s1 = 0.f, s2 = 0.f, s3 = 0.f;
#pragma unroll
  for (int k4 = 0; k4 < 4; ++k4) {
    int idx = k4 * 64 + lane;
    float4 w4 = ((const float4*)wr)[idx];
    float4 e0 = ((const float4*)emb)[idx];
    float4 e1 = ((const float4*)(emb + 1024))[idx];
    float4 e2 = ((const float4*)(emb + 2048))[idx];
    float4 e3 = ((const float4*)(emb + 3072))[idx];
    s0 += w4.x * e0.x + w4.y * e0.y + w4.z * e0.z + w4.w * e0.w;
    s1 += w4.x * e1.x + w4.y * e1.y + w4.z * e1.z + w4.w * e1.w;
    s2 += w4.x * e2.x + w4.y * e2.y + w4.z * e2.z + w4.w * e2.w;
    s3 += w4.x * e3.x + w4.y * e3.y + w4.z * e3.z + w4.w * e3.w;
  }
  s0 = waveReduceSum(s0);
  s1 = waveReduceSum(s1);
  s2 = waveReduceSum(s2);
  s3 = waveReduceSum(s3);
  if (lane == 0) {
    float bb = bbase[(size_t)layer * 2048 + n];
    gb[((size_t)g * 4 + 0) * 2048 + n] = s0 + bb;
    gb[((size_t)g * 4 + 1) * 2048 + n] = s1 + bb;
    gb[((size_t)g * 4 + 2) * 2048 + n] = s2 + bb;
    gb[((size_t)g * 4 + 3) * 2048 + n] = s3 + bb;
  }
}

// ---------------------------------------------------------------- AdaLN apply (bf16 out)
__global__ __launch_bounds__(256) void adaln_apply_kernel(
    const float* __restrict__ x, const float* __restrict__ gb,
    ushort* __restrict__ xn) {
  int r = blockIdx.x;
  int b = r >> 10;
  const float* xr = x + (size_t)r * D_;
  int tid = threadIdx.x;
  float4 v = *(const float4*)(xr + tid * 4);
  float s = v.x + v.y + v.z + v.w;
  float q = v.x * v.x + v.y * v.y + v.z * v.z + v.w * v.w;
  s = waveReduceSum(s);
  q = waveReduceSum(q);
  __shared__ float ssum[4], ssq[4], stats[2];
  int w = tid >> 6, lane = tid & 63;
  if (lane == 0) { ssum[w] = s; ssq[w] = q; }
  __syncthreads();
  if (tid == 0) {
    float S = ssum[0] + ssum[1] + ssum[2] + ssum[3];
    float Q = ssq[0] + ssq[1] + ssq[2] + ssq[3];
    float mean = S * (1.f / D_);
    float var = Q * (1.f / D_) - mean * mean;
    stats[0] = mean;
    stats[1] = rsqrtf(var + 1e-5f);
  }
  __syncthreads();
  float mean = stats[0], rstd = stats[1];
  const float* gp = gb + (size_t)b * 2048;
  float4 g  = *(const float4*)(gp + tid * 4);
  float4 be = *(const float4*)(gp + D_ + tid * 4);
  ushort4 o;
  o.x = f2bf((v.x - mean) * rstd * (1.f + g.x) + be.x);
  o.y = f2bf((v.y - mean) * rstd * (1.f + g.y) + be.y);
  o.z = f2bf((v.z - mean) * rstd * (1.f + g.z) + be.z);
  o.w = f2bf((v.w - mean) * rstd * (1.f + g.w) + be.w);
  *(ushort4*)(xn + (size_t)r * D_ + tid * 4) = o;
}

// ---------------------------------------------------------------- bf16 MFMA GEMM (128x128)
// depth-2 pipelined (3 LDS buffers + counted vmcnt), banded XCD swizzle,
// source-chunk LDS swizzle, padded vector epilogue, optional fused RoPE.
template <int FLAGS, bool OUTBF, int ROPE>
__global__ __launch_bounds__(256) void gemm_mfma_kernel(
    const ushort* __restrict__ A, int lda,
    const ushort* __restrict__ W, int ldw,
    const float* __restrict__ bias,
    const float* __restrict__ res, int ldres,
    void* __restrict__ Cout, int ldc, int K,
    const float* __restrict__ tab, int rlim, int lmask) {
  __shared__ __align__(16) ushort lds[24576];   // 48KB: A bufs @0, W bufs @12288
  const int tid = threadIdx.x;
  const int lane = tid & 63, wv = tid >> 6;
  const int wrow = (wv >> 1) * 64, wcol = (wv & 1) * 64;
  const int fr = lane & 15;
  const int kbs = (((lane >> 4) ^ (fr & 3)) & 3) * 8;

  int trow, tcol;
  xcd_banded(trow, tcol);
  const int row0 = trow * 128;
  const int col0 = tcol * 128;

  const int c0 = wv * 2, c1 = wv * 2 + 1;
  const int sr = lane >> 2;
  const int sc = (((lane & 3) ^ (sr & 3)) & 3) * 8;
  const ushort* Ap0 = A + (size_t)(row0 + c0 * 16 + sr) * lda + sc;
  const ushort* Ap1 = A + (size_t)(row0 + c1 * 16 + sr) * lda + sc;
  const ushort* Wp0 = W + (size_t)(col0 + c0 * 16 + sr) * ldw + sc;
  const ushort* Wp1 = W + (size_t)(col0 + c1 * 16 + sr) * ldw + sc;

  f32x4 acc[4][4];
#pragma unroll
  for (int m = 0; m < 4; ++m)
#pragma unroll
    for (int n = 0; n < 4; ++n) acc[m][n] = (f32x4)0.f;

#define ASB(B) (lds + (B) * 4096)
#define WSB(B) (lds + 12288 + (B) * 4096)
#define STAGE(B, T)                                   \
  do {                                                \
    const int koff_ = (T) * 32;                       \
    gload16(Ap0 + koff_, ASB(B) + c0 * 512);          \
    gload16(Ap1 + koff_, ASB(B) + c1 * 512);          \
    gload16(Wp0 + koff_, WSB(B) + c0 * 512);          \
    gload16(Wp1 + koff_, WSB(B) + c1 * 512);          \
  } while (0)
#define WAITV8() asm volatile("s_waitcnt vmcnt(8)" ::: "memory")
#define WAITV4() asm volatile("s_waitcnt vmcnt(4)" ::: "memory")
#define WAITV0() asm volatile("s_waitcnt vmcnt(0)" ::: "memory")
#define BAR()    __builtin_amdgcn_s_barrier()
#define COMPUTE(B)                                                          \
  do {                                                                      \
    bf16x8 af[4], bfr[4];                                                   \
    _Pragma("unroll")                                                       \
    for (int m = 0; m < 4; ++m)                                             \
      af[m] = *(const bf16x8*)(ASB(B) + (wrow + m * 16 + fr) * 32 + kbs);   \
    _Pragma("unroll")                                                       \
    for (int n = 0; n < 4; ++n)                                             \
      bfr[n] = *(const bf16x8*)(WSB(B) + (wcol + n * 16 + fr) * 32 + kbs);  \
    _Pragma("unroll")                                                       \
    for (int m = 0; m < 4; ++m)                                             \
      _Pragma("unroll")                                                     \
      for (int n = 0; n < 4; ++n)                                           \
        acc[m][n] = __builtin_amdgcn_mfma_f32_16x16x32_bf16(af[m], bfr[n],  \
                                                            acc[m][n], 0, 0, 0); \
  } while (0)

  const int NT = K >> 5;
  STAGE(0, 0);
  STAGE(1, 1);
  for (int t = 0; t < NT; t += 3) {
    {
      const bool sA = (t + 2) < NT;
      if (sA) STAGE(2, t + 2);
      if ((t + 1) < NT) { if (sA) WAITV8(); else WAITV4(); } else WAITV0();
      BAR(); COMPUTE(0); BAR();
    }
    if ((t + 1) < NT) {
      const bool sB = (t + 3) < NT;
      if (sB) STAGE(0, t + 3);
      if ((t + 2) < NT) { if (sB) WAITV8(); else WAITV4(); } else WAITV0();
      BAR(); COMPUTE(1); BAR();
    }
    if ((t + 2) < NT) {
      const bool sC = (t + 4) < NT;
      if (sC) STAGE(1, t + 4);
      if ((t + 3) < NT) { if (sC) WAITV8(); else WAITV4(); } else WAITV0();
      BAR(); COMPUTE(2); BAR();
    }
  }
#undef STAGE
#undef WAITV8
#undef WAITV4
#undef WAITV0
#undef COMPUTE

  float bn[4];
  if (FLAGS & 1) {
#pragma unroll
    for (int n = 0; n < 4; ++n) bn[n] = bias[col0 + wcol + n * 16 + fr];
  }
#define EPI(v, n)                                                     \
  do {                                                                \
    if (FLAGS & 1) (v) += bn[n];                                      \
    if (FLAGS & 2) (v) = 0.5f * (v) * (1.f + erff((v) * 0.70710678118f)); \
  } while (0)

  if (OUTBF) {
    ushort* Ct = lds;                       // [128][136] bf16 (padded)
    ushort* Cg = (ushort*)Cout;
#pragma unroll
    for (int m = 0; m < 4; ++m) {
      int lr0 = wrow + m * 16 + (lane >> 4) * 4;
#pragma unroll
      for (int n = 0; n < 4; ++n) {
        int lc = wcol + n * 16 + fr;
#pragma unroll
        for (int r = 0; r < 4; ++r) {
          float v = acc[m][n][r];
          EPI(v, n);
          Ct[(lr0 + r) * 136 + lc] = f2bf(v);
        }
      }
    }
    __syncthreads();
#pragma unroll
    for (int it = 0; it < 8; ++it) {
      int lr = (tid >> 4) + it * 16;
      int lc = (tid & 15) * 8;
      union { int4 v; ushort us[8]; } vv;
      vv.v = *(const int4*)&Ct[lr * 136 + lc];
      if (ROPE && (col0 + lc) < rlim) {
        union { int4 v; ushort us[8]; } pv;
        pv.v = *(const int4*)&Ct[lr * 136 + (lc ^ 32)];
        int l = (row0 + lr) & lmask;
        int j = lc & 31;
        const float* cb = &tab[l * 64 + j];
        bool lowhalf = (lc & 63) < 32;
#pragma unroll
        for (int e = 0; e < 8; ++e) {
          float cc = cb[e], ss = cb[32 + e];
          float xv = bf2f(vv.us[e]), xp = bf2f(pv.us[e]);
          float o = lowhalf ? (xv * cc - xp * ss) : (xp * ss + xv * cc);
          vv.us[e] = f2bf(o);
        }
      }
      *(int4*)&Cg[(size_t)(row0 + lr) * ldc + col0 + lc] = vv.v;
    }
  } else {
    float* Cf = (float*)lds;                // [64][132] f32 (padded) per half
    float* Cg = (float*)Cout;
#pragma unroll
    for (int half = 0; half < 2; ++half) {
      if ((wv >> 1) == half) {
#pragma unroll
        for (int m = 0; m < 4; ++m) {
          int lr0 = m * 16 + (lane >> 4) * 4;
#pragma unroll
          for (int n = 0; n < 4; ++n) {
            int lc = wcol + n * 16 + fr;
#pragma unroll
            for (int r = 0; r < 4; ++r) {
              float v = acc[m][n][r];
              EPI(v, n);
              Cf[(lr0 + r) * 132 + lc] = v;
            }
          }
        }
      }
      __syncthreads();
#pragma unroll
      for (int it = 0; it < 8; ++it) {
        int lr = (tid >> 5) + it * 8;
        int lc = (tid & 31) * 4;
        int grow = row0 + half * 64 + lr;
        float4 v = *(const float4*)&Cf[lr * 132 + lc];
        if (FLAGS & 4) {
          float4 rv = *(const float4*)&res[(size_t)grow * ldres + col0 + lc];
          v.x += rv.x; v.y += rv.y; v.z += rv.z; v.w += rv.w;
        }
        *(float4*)&Cg[(size_t)grow * ldc + col0 + lc] = v;
      }
      __syncthreads();
    }
  }
#undef EPI
#undef ASB
#undef WSB
#undef BAR
}

// ---------------------------------------------------------------- merged cq + (ck|cv) GEMM
// z=0: big = xnb @ cqW^T (M=4096, ldc=1024, lmask=1023, virtual grid 8x32)
// z=1: kvb = ctxb @ kvW^T (M=2048, ldc=2048, lmask=511, virtual grid 16x16)
// Both: K=1024, lda=1024, bf16-out, RoPE cols<1024. Same proven pipeline.
__global__ __launch_bounds__(256) void gemm_cqkv_kernel(
    const ushort* __restrict__ Aq, const ushort* __restrict__ Ac,
    const ushort* __restrict__ Wq, const ushort* __restrict__ Wkv,
    ushort* __restrict__ Cq, ushort* __restrict__ Ckv,
    const float* __restrict__ tab) {
  __shared__ __align__(16) ushort lds[24576];
  const int tid = threadIdx.x;
  const int lane = tid & 63, wv = tid >> 6;
  const int wrow = (wv >> 1) * 64, wcol = (wv & 1) * 64;
  const int fr = lane & 15;
  const int kbs = (((lane >> 4) ^ (fr & 3)) & 3) * 8;
  const int K = 1024, lda = 1024;

  const int z = blockIdx.z;
  const ushort* A = z ? Ac : Aq;
  const ushort* W = z ? Wkv : Wq;
  ushort* Cg = z ? Ckv : Cq;
  const int ldc = z ? 2048 : 1024;
  const int lmask = z ? 511 : 1023;
  const int vgx = z ? 16 : 8;

  // banded swizzle on the virtual grid (256 blocks per z-slice)
  const int flat = blockIdx.y * gridDim.x + blockIdx.x;   // 0..255
  const int swz = (flat & 7) * 32 + (flat >> 3);
  const int bandw = vgx * 4;
  const int band = swz / bandw;
  const int rem = swz % bandw;
  const int row0 = (band * 4 + (rem & 3)) * 128;
  const int col0 = (rem >> 2) * 128;

  const int c0 = wv * 2, c1 = wv * 2 + 1;
  const int sr = lane >> 2;
  const int sc = (((lane & 3) ^ (sr & 3)) & 3) * 8;
  const ushort* Ap0 = A + (size_t)(row0 + c0 * 16 + sr) * lda + sc;
  const ushort* Ap1 = A + (size_t)(row0 + c1 * 16 + sr) * lda + sc;
  const ushort* Wp0 = W + (size_t)(col0 + c0 * 16 + sr) * lda + sc;
  const ushort* Wp1 = W + (size_t)(col0 + c1 * 16 + sr) * lda + sc;

  f32x4 acc[4][4];
#pragma unroll
  for (int m = 0; m < 4; ++m)
#pragma unroll
    for (int n = 0; n < 4; ++n) acc[m][n] = (f32x4)0.f;

#define ASB(B) (lds + (B) * 4096)
#define WSB(B) (lds + 12288 + (B) * 4096)
#define STAGE(B, T)                                   \
  do {                                                \
    const int koff_ = (T) * 32;                       \
    gload16(Ap0 + koff_, ASB(B) + c0 * 512);          \
    gload16(Ap1 + koff_, ASB(B) + c1 * 512);          \
    gload16(Wp0 + koff_, WSB(B) + c0 * 512);          \
    gload16(Wp1 + koff_, WSB(B) + c1 * 512);          \
  } while (0)
#define WAITV8() asm volatile("s_waitcnt vmcnt(8)" ::: "memory")
#define WAITV4() asm volatile("s_waitcnt vmcnt(4)" ::: "memory")
#define WAITV0() asm volatile("s_waitcnt vmcnt(0)" ::: "memory")
#define BAR()    __builtin_amdgcn_s_barrier()
#define COMPUTE(B)                                                          \
  do {                                                                      \
    bf16x8 af[4], bfr[4];                                                   \
    _Pragma("unroll")                                                       \
    for (int m = 0; m < 4; ++m)                                             \
      af[m] = *(const bf16x8*)(ASB(B) + (wrow + m * 16 + fr) * 32 + kbs);   \
    _Pragma("unroll")                                                       \
    for (int n = 0; n < 4; ++n)                                             \
      bfr[n] = *(const bf16x8*)(WSB(B) + (wcol + n * 16 + fr) * 32 + kbs);  \
    _Pragma("unroll")                                                       \
    for (int m = 0; m < 4; ++m)                                             \
      _Pragma("unroll")                                                     \
      for (int n = 0; n < 4; ++n)                                           \
        acc[m][n] = __builtin_amdgcn_mfma_f32_16x16x32_bf16(af[m], bfr[n],  \
                                                            acc[m][n], 0, 0, 0); \
  } while (0)

  const int NT = K >> 5;   // 32
  STAGE(0, 0);
  STAGE(1, 1);
  for (int t = 0; t < NT; t += 3) {
    {
      const bool sA = (t + 2) < NT;
      if (sA) STAGE(2, t + 2);
      if ((t + 1) < NT) { if (sA) WAITV8(); else WAITV4(); } else WAITV0();
      BAR(); COMPUTE(0); BAR();
    }
    if ((t + 1) < NT) {
      const bool sB = (t + 3) < NT;
      if (sB) STAGE(0, t + 3);
      if ((t + 2) < NT) { if (sB) WAITV8(); else WAITV4(); } else WAITV0();
      BAR(); COMPUTE(1); BAR();
    }
    if ((t + 2) < NT) {
      const bool sC = (t + 4) < NT;
      if (sC) STAGE(1, t + 4);
      if ((t + 3) < NT) { if (sC) WAITV8(); else WAITV4(); } else WAITV0();
      BAR(); COMPUTE(2); BAR();
    }
  }
#undef STAGE
#undef WAITV8
#undef WAITV4
#undef WAITV0
#undef COMPUTE

  // bf16 epilogue with fused RoPE (cols < 1024)
  ushort* Ct = lds;                       // [128][136]
#pragma unroll
  for (int m = 0; m < 4; ++m) {
    int lr0 = wrow + m * 16 + (lane >> 4) * 4;
#pragma unroll
    for (int n = 0; n < 4; ++n) {
      int lc = wcol + n * 16 + fr;
#pragma unroll
      for (int r = 0; r < 4; ++r)
        Ct[(lr0 + r) * 136 + lc] = f2bf(acc[m][n][r]);
    }
  }
  __syncthreads();
#pragma unroll
  for (int it = 0; it < 8; ++it) {
    int lr = (tid >> 4) + it * 16;
    int lc = (tid & 15) * 8;
    union { int4 v; ushort us[8]; } vv;
    vv.v = *(const int4*)&Ct[lr * 136 + lc];
    if ((col0 + lc) < 1024) {
      union { int4 v; ushort us[8]; } pv;
      pv.v = *(const int4*)&Ct[lr * 136 + (lc ^ 32)];
      int l = (row0 + lr) & lmask;
      int j = lc & 31;
      const float* cb = &tab[l * 64 + j];
      bool lowhalf = (lc & 63) < 32;
#pragma unroll
      for (int e = 0; e < 8; ++e) {
        float cc = cb[e], ss = cb[32 + e];
        float xv = bf2f(vv.us[e]), xp = bf2f(pv.us[e]);
        float o = lowhalf ? (xv * cc - xp * ss) : (xp * ss + xv * cc);
        vv.us[e] = f2bf(o);
      }
    }
    *(int4*)&Cg[(size_t)(row0 + lr) * ldc + col0 + lc] = vv.v;
  }
#undef ASB
#undef WSB
#undef BAR
}

// ---------------------------------------------------------------- 256x256 8-wave GEMM
// BK=64, double-buffered 128KB LDS, one barrier + one late vmcnt(0) per K-tile;
// banded XCD swizzle; chunk-XOR LDS swizzle; setprio around MFMA. bf16 out.
// Epilogue: linear [256][256] LDS tile -> vector stores.
// FLAGS: 1=+bias, 2=gelu. Requires K%64==0, M,N%256==0, gridDim.y%4==0.
template <int FLAGS, int ROPE>
__global__ __launch_bounds__(512, 2) void gemm256_kernel(
    const ushort* __restrict__ A, int lda,
    const ushort* __restrict__ W, int ldw,
    const float* __restrict__ bias,
    ushort* __restrict__ Cout, int ldc, int K,
    const float* __restrict__ tab, int rlim, int lmask) {
  __shared__ __align__(16) ushort lds[65536];   // 128 KB
  const int tid = threadIdx.x;
  const int lane = tid & 63, wid = tid >> 6;
  const int wm = wid >> 2, wn = wid & 3;        // 2 x 4 wave grid
  const int fr = lane & 15, hi = lane >> 4;

  int trow, tcol;
  xcd_banded(trow, tcol);
  const int row0 = trow * 256;
  const int col0 = tcol * 256;

  const int srow = lane >> 3;
  const int scol = ((lane & 7) ^ srow) * 8;
  const ushort* Asrc[4];
  const ushort* Wsrc[4];
#pragma unroll
  for (int j = 0; j < 4; ++j) {
    int r = wid * 32 + j * 8 + srow;
    Asrc[j] = A + (size_t)(row0 + r) * lda + scol;
    Wsrc[j] = W + (size_t)(col0 + r) * ldw + scol;
  }
#define AB256(b) (lds + (b) * 16384)
#define WB256(b) (lds + 32768 + (b) * 16384)
#define STG256(b, T)                                      \
  do {                                                    \
    const int kk_ = (T) * 64;                             \
    _Pragma("unroll")                                     \
    for (int j = 0; j < 4; ++j) {                         \
      int ch_ = wid * 4 + j;                              \
      gload16(Asrc[j] + kk_, AB256(b) + ch_ * 512);       \
      gload16(Wsrc[j] + kk_, WB256(b) + ch_ * 512);       \
    }                                                     \
  } while (0)

  f32x4 acc[8][4];
#pragma unroll
  for (int m = 0; m < 8; ++m)
#pragma unroll
    for (int n = 0; n < 4; ++n) acc[m][n] = (f32x4)0.f;

  const int NT = K >> 6;
  STG256(0, 0);
  asm volatile("s_waitcnt vmcnt(0)" ::: "memory");
  __builtin_amdgcn_s_barrier();
  for (int t = 0; t < NT; ++t) {
    const int cur = t & 1;
    if (t + 1 < NT) STG256(cur ^ 1, t + 1);   // issue BEFORE compute
    const ushort* ab = AB256(cur);
    const ushort* wb = WB256(cur);
    __builtin_amdgcn_s_setprio(1);
#pragma unroll
    for (int s = 0; s < 2; ++s) {
      bf16x8 wf[4];
#pragma unroll
      for (int n = 0; n < 4; ++n) {
        int row = wn * 64 + n * 16 + fr;
        wf[n] = *(const bf16x8*)(wb + row * 64 + (((s * 4 + hi) ^ (fr & 7)) * 8));
      }
#pragma unroll
      for (int m = 0; m < 8; ++m) {
        int row = wm * 128 + m * 16 + fr;
        bf16x8 af = *(const bf16x8*)(ab + row * 64 + (((s * 4 + hi) ^ (fr & 7)) * 8));
#pragma unroll
        for (int n = 0; n < 4; ++n)
          acc[m][n] = __builtin_amdgcn_mfma_f32_16x16x32_bf16(af, wf[n],
                                                              acc[m][n], 0, 0, 0);
      }
    }
    __builtin_amdgcn_s_setprio(0);
    asm volatile("s_waitcnt vmcnt(0)" ::: "memory");
    __builtin_amdgcn_s_barrier();
  }
#undef STG256

  float bn[4];
  if (FLAGS & 1) {
#pragma unroll
    for (int n = 0; n < 4; ++n) bn[n] = bias[col0 + wn * 64 + n * 16 + fr];
  }
  ushort* Ct = lds;
#pragma unroll
  for (int m = 0; m < 8; ++m) {
    int lr0 = wm * 128 + m * 16 + hi * 4;
#pragma unroll
    for (int n = 0; n < 4; ++n) {
      int lc = wn * 64 + n * 16 + fr;
#pragma unroll
      for (int r = 0; r < 4; ++r) {
        float v = acc[m][n][r];
        if (FLAGS & 1) v += bn[n];
        if (FLAGS & 2) v = 0.5f * v * (1.f + erff(v * 0.70710678118f));
        Ct[(lr0 + r) * 256 + lc] = f2bf(v);
      }
    }
  }
  __syncthreads();
#pragma unroll
  for (int it = 0; it < 16; ++it) {
    int idx = tid + it * 512;
    int lr = idx >> 5;
    int lc = (idx & 31) * 8;
    union { int4 v; ushort us[8]; } vv;
    vv.v = *(const int4*)&Ct[lr * 256 + lc];
    if (ROPE && (col0 + lc) < rlim) {
      union { int4 v; ushort us[8]; } pv;
      pv.v = *(const int4*)&Ct[lr * 256 + (lc ^ 32)];
      int l = (row0 + lr) & lmask;
      int j = lc & 31;
      const float* cb = &tab[l * 64 + j];
      bool lowhalf = (lc & 63) < 32;
#pragma unroll
      for (int e = 0; e < 8; ++e) {
        float cc = cb[e], ss = cb[32 + e];
        float xv = bf2f(vv.us[e]), xp = bf2f(pv.us[e]);
        float o = lowhalf ? (xv * cc - xp * ss) : (xp * ss + xv * cc);
        vv.us[e] = f2bf(o);
      }
    }
    *(int4*)&Cout[(size_t)(row0 + lr) * ldc + col0 + lc] = vv.v;
  }
#undef AB256
#undef WB256
}

// ---------------------------------------------------------------- MFMA flash attention
// 128 q-rows/block, 8 waves: waves 0-3 stage K, waves 4-7 stage V (transposed).
// Swapped QK^T, register-exchange P, K/V dbuf + async-stage, T13 defer-max
// (skip rescale when all rows' max growth <= 8; wave-uniform branch).
#define SWZ(row, col) (((row) << 6) + ((col) ^ (((row) & 7) << 3)))
__global__ __launch_bounds__(512) void attn_mfma_kernel(
    const ushort* __restrict__ Q, int ldq,
    const ushort* __restrict__ K, int ldk,
    const ushort* __restrict__ V, int ldv,
    ushort* __restrict__ O, int ldo,
    int Lq, int Lk, float scale) {
  __shared__ __align__(16) ushort Ks[2][64 * 64];
  __shared__ __align__(16) ushort Vt[2][64 * 64];
  __shared__ __align__(16) ushort Os[128 * 64];
  const int tid = threadIdx.x;
  const int lane = tid & 63, w = tid >> 6;       // w in 0..7
  const int fr = lane & 15, hi = lane >> 4, kb = hi * 8;
  const int b = blockIdx.z, h = blockIdx.y, q0 = blockIdx.x * 128;
  const int kw = w & 3;
  const bool isK = (w < 4);

  bf16x8 aq[2];
  {
    const ushort* qp = Q + (size_t)(b * Lq + q0 + w * 16 + fr) * ldq + h * 64 + kb;
    union { bf16x8 v; ushort us[8]; } t0, t1;
    t0.v = *(const bf16x8*)qp;
    t1.v = *(const bf16x8*)(qp + 32);
#pragma unroll
    for (int e = 0; e < 8; ++e) {
      t0.us[e] = f2bf(bf2f(t0.us[e]) * scale);
      t1.us[e] = f2bf(bf2f(t1.us[e]) * scale);
    }
    aq[0] = t0.v;
    aq[1] = t1.v;
  }

  const int ldkv = isK ? ldk : ldv;
  const ushort* kvbase = (isK ? K : V) + (size_t)(b * Lk + lane) * ldkv
                         + h * 64 + kw * 16;
  const size_t kvstep = (size_t)64 * ldkv;
  int4 r0, r1;
#define LOADKV(T)                                      \
  do {                                                 \
    const ushort* p_ = kvbase + (size_t)(T) * kvstep;  \
    r0 = ((const int4*)p_)[0];                         \
    r1 = ((const int4*)p_)[1];                         \
  } while (0)
#define WRITEKV(P)                                                        \
  do {                                                                    \
    if (isK) {                                                            \
      *(int4*)&Ks[P][SWZ(lane, kw * 16)]     = r0;                        \
      *(int4*)&Ks[P][SWZ(lane, kw * 16 + 8)] = r1;                        \
    } else {                                                              \
      union { int4 v; ushort us[8]; } u0_, u1_;                           \
      u0_.v = r0; u1_.v = r1;                                             \
      _Pragma("unroll")                                                   \
      for (int e = 0; e < 8; ++e) Vt[P][SWZ(kw * 16 + e, lane)] = u0_.us[e]; \
      _Pragma("unroll")                                                   \
      for (int e = 0; e < 8; ++e) Vt[P][SWZ(kw * 16 + 8 + e, lane)] = u1_.us[e]; \
    }                                                                     \
  } while (0)

  f32x4 oacc[4];
#pragma unroll
  for (int n = 0; n < 4; ++n) oacc[n] = (f32x4)0.f;
  float mq = -1e30f, lq = 0.f;
  const int ntiles = Lk >> 6;
  const bool lowhalf = (lane < 32);
  const bool sendSelf = (hi == 1 || hi == 2);

  LOADKV(0);
  WRITEKV(0);
  int p = 0;
  for (int t = 0; t < ntiles; ++t) {
    if (t + 1 < ntiles) LOADKV(t + 1);
    __syncthreads();

    f32x4 sacc[4];
#pragma unroll
    for (int n = 0; n < 4; ++n) sacc[n] = (f32x4)0.f;
    __builtin_amdgcn_s_setprio(1);
#pragma unroll
    for (int s = 0; s < 2; ++s) {
#pragma unroll
      for (int n = 0; n < 4; ++n) {
        bf16x8 ak = *(const bf16x8*)&Ks[p][SWZ(n * 16 + fr, s * 32 + kb)];
        sacc[n] = __builtin_amdgcn_mfma_f32_16x16x32_bf16(ak, aq[s], sacc[n], 0, 0, 0);
      }
    }
    __builtin_amdgcn_s_setprio(0);

    float sm = sacc[0][0];
#pragma unroll
    for (int n = 0; n < 4; ++n)
#pragma unroll
      for (int r = 0; r < 4; ++r) sm = fmaxf(sm, sacc[n][r]);
    sm = fmaxf(sm, __shfl_xor(sm, 16));
    sm = fmaxf(sm, __shfl_xor(sm, 32));
    // T13 defer-max: if every row's max growth <= 8, keep old running max
    // (corr == 1 exactly): skip exp, rescale and corr-distribution shfls.
    const bool defer = __all(sm - mq <= 8.f);
    if (!defer) {
      float mnew = fmaxf(mq, sm);
      float corrq = __expf(mq - mnew);
      mq = mnew;
      lq *= corrq;
      float c0 = __shfl(corrq, hi * 4 + 0);
      float c1 = __shfl(corrq, hi * 4 + 1);
      float c2 = __shfl(corrq, hi * 4 + 2);
      float c3 = __shfl(corrq, hi * 4 + 3);
#pragma unroll
      for (int n = 0; n < 4; ++n) {
        oacc[n][0] *= c0; oacc[n][1] *= c1; oacc[n][2] *= c2; oacc[n][3] *= c3;
      }
    }
    float pe[4][4];
    float psum = 0.f;
#pragma unroll
    for (int n = 0; n < 4; ++n)
#pragma unroll
      for (int r = 0; r < 4; ++r) {
        pe[n][r] = __expf(sacc[n][r] - mq);
        psum += pe[n][r];
      }
    psum += __shfl_xor(psum, 16);
    psum += __shfl_xor(psum, 32);
    lq += psum;

    uint32 u00 = pk2(pe[0][0], pe[0][1]), u01 = pk2(pe[0][2], pe[0][3]);
    uint32 u10 = pk2(pe[1][0], pe[1][1]), u11 = pk2(pe[1][2], pe[1][3]);
    uint32 u20 = pk2(pe[2][0], pe[2][1]), u21 = pk2(pe[2][2], pe[2][3]);
    uint32 u30 = pk2(pe[3][0], pe[3][1]), u31 = pk2(pe[3][2], pe[3][3]);
    uint32 selfw0 = lowhalf ? u00 : u10;
    uint32 selfw1 = lowhalf ? u01 : u11;
    uint32 selfw2 = lowhalf ? u20 : u30;
    uint32 selfw3 = lowhalf ? u21 : u31;
    uint32 send10 = lowhalf ? u10 : u00;
    uint32 send11 = lowhalf ? u11 : u01;
    uint32 send12 = lowhalf ? u30 : u20;
    uint32 send13 = lowhalf ? u31 : u21;
    uint32 farw0 = __shfl_xor((int)send10, 32);
    uint32 farw1 = __shfl_xor((int)send11, 32);
    uint32 farw2 = __shfl_xor((int)send12, 32);
    uint32 farw3 = __shfl_xor((int)send13, 32);
    uint32 s20 = sendSelf ? selfw0 : farw0;
    uint32 s21 = sendSelf ? selfw1 : farw1;
    uint32 s22 = sendSelf ? selfw2 : farw2;
    uint32 s23 = sendSelf ? selfw3 : farw3;
    uint32 rcv0 = __shfl_xor((int)s20, 16);
    uint32 rcv1 = __shfl_xor((int)s21, 16);
    uint32 rcv2 = __shfl_xor((int)s22, 16);
    uint32 rcv3 = __shfl_xor((int)s23, 16);
    union { uint32 wd[4]; bf16x8 v; } pa0, pa1;
    if (hi == 0) {
      pa0.wd[0] = selfw0; pa0.wd[1] = selfw1; pa0.wd[2] = rcv0; pa0.wd[3] = rcv1;
      pa1.wd[0] = selfw2; pa1.wd[1] = selfw3; pa1.wd[2] = rcv2; pa1.wd[3] = rcv3;
    } else if (hi == 1) {
      pa0.wd[0] = rcv0; pa0.wd[1] = rcv1; pa0.wd[2] = farw0; pa0.wd[3] = farw1;
      pa1.wd[0] = rcv2; pa1.wd[1] = rcv3; pa1.wd[2] = farw2; pa1.wd[3] = farw3;
    } else if (hi == 2) {
      pa0.wd[0] = farw0; pa0.wd[1] = farw1; pa0.wd[2] = rcv0; pa0.wd[3] = rcv1;
      pa1.wd[0] = farw2; pa1.wd[1] = farw3; pa1.wd[2] = rcv2; pa1.wd[3] = rcv3;
    } else {
      pa0.wd[0] = rcv0; pa0.wd[1] = rcv1; pa0.wd[2] = selfw0; pa0.wd[3] = selfw1;
      pa1.wd[0] = rcv2; pa1.wd[1] = rcv3; pa1.wd[2] = selfw2; pa1.wd[3] = selfw3;
    }

    __builtin_amdgcn_s_setprio(1);
#pragma unroll
    for (int n = 0; n < 4; ++n) {
      bf16x8 bv0 = *(const bf16x8*)&Vt[p][SWZ(n * 16 + fr, 0 * 32 + kb)];
      oacc[n] = __builtin_amdgcn_mfma_f32_16x16x32_bf16(pa0.v, bv0, oacc[n], 0, 0, 0);
      bf16x8 bv1 = *(const bf16x8*)&Vt[p][SWZ(n * 16 + fr, 1 * 32 + kb)];
      oacc[n] = __builtin_amdgcn_mfma_f32_16x16x32_bf16(pa1.v, bv1, oacc[n], 0, 0, 0);
    }
    __builtin_amdgcn_s_setprio(0);

    __syncthreads();
    if (t + 1 < ntiles) WRITEKV(p ^ 1);
    p ^= 1;
  }
#undef LOADKV
#undef WRITEKV

  float linv[4];
#pragma unroll
  for (int r = 0; r < 4; ++r) linv[r] = 1.f / __shfl(lq, hi * 4 + r);
#pragma unroll
  for (int r = 0; r < 4; ++r) {
    int rl = w * 16 + hi * 4 + r;
#pragma unroll
    for (int n = 0; n < 4; ++n)
      Os[SWZ(rl, n * 16 + fr)] = f2bf(oacc[n][r] * linv[r]);
  }
  __syncthreads();
  {
    int row = tid >> 2, cbk = (tid & 3) * 16;
    ushort* op = O + (size_t)(b * Lq + q0 + row) * ldo + h * 64 + cbk;
    int4 o0 = *(const int4*)&Os[SWZ(row, cbk)];
    int4 o1 = *(const int4*)&Os[SWZ(row, cbk + 8)];
    ((int4*)op)[0] = o0;
    ((int4*)op)[1] = o1;
  }
}

// ---------------------------------------------------------------- launch
extern "C" void kernel_launch(void* const* d_in, const int* in_sizes, int n_in,
                              void* d_out, int out_size, void* d_ws, size_t ws_size,
                              hipStream_t stream) {
  const float* x_in = (const float*)d_in[0];
  const float* emb  = (const float*)d_in[1];
  const float* ctx  = (const float*)d_in[2];
  const float* n1w = (const float*)d_in[5];
  const float* n1b = (const float*)d_in[6];
  const float* n2w = (const float*)d_in[7];
  const float* n2b = (const float*)d_in[8];
  const float* n3w = (const float*)d_in[9];
  const float* n3b = (const float*)d_in[10];
  const float* qkvw = (const float*)d_in[11];
  const float* sow  = (const float*)d_in[12];
  const float* cqw  = (const float*)d_in[13];
  const float* ckw  = (const float*)d_in[14];
  const float* cvw  = (const float*)d_in[15];
  const float* cow  = (const float*)d_in[16];
  const float* f1w  = (const float*)d_in[17];
  const float* f1b  = (const float*)d_in[18];
  const float* f2w  = (const float*)d_in[19];
  const float* f2b  = (const float*)d_in[20];

  float* xcur = (float*)d_out;

  // workspace layout
  ushort* xnb  = (ushort*)d_ws;                        // 4096x1024 bf16
  ushort* big  = xnb + (size_t)4096 * 1024;            // 4096x4096 bf16 (qkv/q/h)
  ushort* obb  = big + (size_t)4096 * 4096;            // 4096x1024 bf16 (attn out)
  ushort* kvb  = obb + (size_t)4096 * 1024;            // 2048x2048 bf16 (K|V packed)
  ushort* ctxb = kvb + (size_t)2048 * 2048;            // 2048x1024 bf16 (persistent)
  float*  gball= (float*)(ctxb + (size_t)2048 * 1024); // 18*4*2048 f32
  float*  tab  = gball + 18 * 4 * 2048;                // 65536 f32
  ushort* scrW = (ushort*)(tab + 65536);               // 4096x1024 bf16 scratch
  const size_t SZ_QKV = (size_t)NL_ * 3072 * 1024;
  const size_t SZ_SQ  = (size_t)NL_ * 1024 * 1024;
  const size_t SZ_F   = (size_t)NL_ * 4096 * 1024;
  const size_t M1 = (size_t)1024 * 1024;
  ushort* wqkv = scrW + (size_t)4096 * 1024;
  ushort* wso  = wqkv + SZ_QKV;
  ushort* wcq  = wso + SZ_SQ;
  ushort* wkv  = wcq + SZ_SQ;          // [NL][2048][1024] packed ck|cv
  ushort* wco  = wkv + 2 * SZ_SQ;
  ushort* wf1  = wco + SZ_SQ;
  ushort* wf2  = wf1 + SZ_F;
  const size_t need_full = (size_t)((char*)(wf2 + SZ_F) - (char*)d_ws);
  const bool wbfull = (ws_size >= need_full);

  hipMemcpyAsync(xcur, x_in, (size_t)B_ * L_ * D_ * sizeof(float),
                 hipMemcpyDeviceToDevice, stream);
  rope_table_kernel<<<128, 256, 0, stream>>>(tab);
  adaln_gb_all_kernel<<<9216, 256, 0, stream>>>(emb, n1w, n2w, n3w,
                                                n1b, n2b, n3b, gball);
  cvt_bf16_kernel<<<1024, 256, 0, stream>>>(ctx, ctxb,
                                            (int)((size_t)2048 * 1024 / 4));

  if (wbfull) {
    cvt_bf16_kernel<<<2048, 256, 0, stream>>>(qkvw, wqkv, (int)(SZ_QKV / 4));
    cvt_bf16_kernel<<<2048, 256, 0, stream>>>(sow,  wso,  (int)(SZ_SQ / 4));
    cvt_bf16_kernel<<<2048, 256, 0, stream>>>(cqw,  wcq,  (int)(SZ_SQ / 4));
    cvt_pack_kv_kernel<<<2048, 256, 0, stream>>>(ckw, cvw, wkv,
                                                 (int)(2 * SZ_SQ / 4));
    cvt_bf16_kernel<<<2048, 256, 0, stream>>>(cow,  wco,  (int)(SZ_SQ / 4));
    cvt_bf16_kernel<<<2048, 256, 0, stream>>>(f1w,  wf1,  (int)(SZ_F / 4));
    cvt_bf16_kernel<<<2048, 256, 0, stream>>>(f2w,  wf2,  (int)(SZ_F / 4));
  }

  auto prepW = [&](const float* src, ushort* full, size_t layerOff,
                   size_t nelem) -> const ushort* {
    if (wbfull) return full + layerOff;
    cvt_bf16_kernel<<<1024, 256, 0, stream>>>(src + layerOff, scrW,
                                              (int)(nelem / 4));
    return scrW;
  };

  const int ROWS = B_ * L_;
  const dim3 blk(256);
  const dim3 blk512(512);

  for (int i = 0; i < NL_; ++i) {
    const float* f1bi = f1b + (size_t)i * DFF_;
    const float* f2bi = f2b + (size_t)i * D_;

    // ---- self-attention block ----
    adaln_apply_kernel<<<ROWS, blk, 0, stream>>>(
        xcur, gball + (size_t)(i * 3 + 0) * 4 * 2048, xnb);
    gemm256_kernel<0, 1><<<dim3(12, 16), blk512, 0, stream>>>(       // rope q,k
        xnb, D_, prepW(qkvw, wqkv, (size_t)i * 3072 * 1024, (size_t)3072 * 1024),
        D_, nullptr, big, 3072, D_, tab, 2048, 1023);
    attn_mfma_kernel<<<dim3(L_ / 128, H_, B_), blk512, 0, stream>>>(
        big, 3072, big + 1024, 3072, big + 2048, 3072, obb, D_, L_, L_, 0.125f);
    gemm_mfma_kernel<4, false, 0><<<dim3(8, 32), blk, 0, stream>>>(
        obb, D_, prepW(sow, wso, (size_t)i * M1, M1),
        D_, nullptr, xcur, D_, xcur, D_, D_, tab, 0, 0);

    // ---- cross-attention block ----
    adaln_apply_kernel<<<ROWS, blk, 0, stream>>>(
        xcur, gball + (size_t)(i * 3 + 1) * 4 * 2048, xnb);
    // merged cq + (ck|cv) projections (rope on q and k halves)
    {
      const ushort *wcqi, *wkvi;
      if (wbfull) {
        wcqi = wcq + (size_t)i * M1;
        wkvi = wkv + (size_t)i * 2 * M1;
      } else {
        cvt_bf16_kernel<<<512, 256, 0, stream>>>(cqw + (size_t)i * M1, scrW,
                                                 (int)(M1 / 4));
        cvt_bf16_kernel<<<512, 256, 0, stream>>>(ckw + (size_t)i * M1,
                                                 scrW + M1, (int)(M1 / 4));
        cvt_bf16_kernel<<<512, 256, 0, stream>>>(cvw + (size_t)i * M1,
                                                 scrW + 2 * M1, (int)(M1 / 4));
        wcqi = scrW;
        wkvi = scrW + M1;
      }
      gemm_cqkv_kernel<<<dim3(16, 16, 2), blk, 0, stream>>>(
          xnb, ctxb, wcqi, wkvi, big, kvb, tab);
    }
    attn_mfma_kernel<<<dim3(L_ / 128, H_, B_), blk512, 0, stream>>>(
        big, 1024, kvb, 2048, kvb + 1024, 2048, obb, D_, L_, LC_, 0.125f);
    gemm_mfma_kernel<4, false, 0><<<dim3(8, 32), blk, 0, stream>>>(
        obb, D_, prepW(cow, wco, (size_t)i * M1, M1),
        D_, nullptr, xcur, D_, xcur, D_, D_, tab, 0, 0);

    // ---- FFN block ----
    adaln_apply_kernel<<<ROWS, blk, 0, stream>>>(
        xcur, gball + (size_t)(i * 3 + 2) * 4 * 2048, xnb);
    gemm256_kernel<3, 0><<<dim3(16, 16), blk512, 0, stream>>>(       // bias+gelu
        xnb, D_, prepW(f1w, wf1, (size_t)i * 4096 * 1024, (size_t)4096 * 1024),
        D_, f1bi, big, DFF_, D_, tab, 0, 0);
    gemm_mfma_kernel<5, false, 0><<<dim3(8, 32), blk, 0, stream>>>(
        big, DFF_, prepW(f2w, wf2, (size_t)i * 4096 * 1024, (size_t)4096 * 1024),
        DFF_, f2bi, xcur, D_, xcur, D_, DFF_, tab, 0, 0);
  }
}

// Round 16
// 1961.583 us; speedup vs baseline: 1.0539x; 1.0079x over previous
//
#include <hip/hip_runtime.h>
#include <hip/hip_bf16.h>
#include <math.h>

// Problem constants
#define D_    1024
#define H_    16
#define HD_   64
#define NL_   6
#define DFF_  4096
#define B_    4
#define L_    1024
#define LC_   512

typedef short bf16x8 __attribute__((ext_vector_type(8)));
typedef float f32x4  __attribute__((ext_vector_type(4)));
typedef unsigned int uint32;

// ---------------------------------------------------------------- utilities
__device__ __forceinline__ float waveReduceSum(float v) {
#pragma unroll
  for (int off = 32; off > 0; off >>= 1) v += __shfl_xor(v, off);
  return v;
}
__device__ __forceinline__ ushort f2bf(float f) {
  union { __hip_bfloat16 h; ushort u; } c;
  c.h = __float2bfloat16(f);
  return c.u;
}
__device__ __forceinline__ float bf2f(ushort u) {
  union { uint32 i; float f; } c;
  c.i = ((uint32)u) << 16;
  return c.f;
}
__device__ __forceinline__ uint32 pk2(float a, float b) {
  return (uint32)f2bf(a) | ((uint32)f2bf(b) << 16);
}
// async global->LDS, 16B per lane. lds base must be wave-uniform (m104).
__device__ __forceinline__ void gload16(const ushort* g, ushort* l) {
  __builtin_amdgcn_global_load_lds(
      (const __attribute__((address_space(1))) uint32*)g,
      (__attribute__((address_space(3))) uint32*)l, 16, 0, 0);
}

// banded XCD swizzle: XCD chunk covers 4 tile-rows x (chunk/4) tile-cols.
// Requires gridDim.y % 4 == 0 and nwg % 8 == 0. Returns row,col tile indices.
__device__ __forceinline__ void xcd_banded(int& trow, int& tcol) {
  const int nwg = gridDim.x * gridDim.y;
  const int wg = blockIdx.y * gridDim.x + blockIdx.x;
  const int q = nwg >> 3;
  const int swz = (wg & 7) * q + (wg >> 3);
  const int bandw = gridDim.x * 4;
  const int band = swz / bandw;
  const int rem = swz % bandw;
  trow = band * 4 + (rem & 3);
  tcol = rem >> 2;
}

// ---------------------------------------------------------------- fp32 -> bf16 bulk convert
__global__ __launch_bounds__(256) void cvt_bf16_kernel(
    const float* __restrict__ in, ushort* __restrict__ out, int n4) {
  int i = blockIdx.x * 256 + threadIdx.x;
  int stride = gridDim.x * 256;
  for (; i < n4; i += stride) {
    float4 v = ((const float4*)in)[i];
    ushort4 o = {f2bf(v.x), f2bf(v.y), f2bf(v.z), f2bf(v.w)};
    ((ushort4*)out)[i] = o;
  }
}

// packed [NL][2048][1024]: rows 0-1023 = ck layer, 1024-2047 = cv layer
__global__ __launch_bounds__(256) void cvt_pack_kv_kernel(
    const float* __restrict__ ck, const float* __restrict__ cv,
    ushort* __restrict__ out, int n4) {
  int i = blockIdx.x * 256 + threadIdx.x;
  int stride = gridDim.x * 256;
  for (; i < n4; i += stride) {
    int row = i >> 8;               // 256 float4 per 1024-wide row
    int cb = i & 255;
    int layer = row >> 11;
    int sel = (row >> 10) & 1;
    int r = row & 1023;
    const float* src = (sel ? cv : ck) +
                       (((size_t)layer << 10) + r) * 1024 + cb * 4;
    float4 v = *(const float4*)src;
    ushort4 o = {f2bf(v.x), f2bf(v.y), f2bf(v.z), f2bf(v.w)};
    ((ushort4*)out)[i] = o;
  }
}

// ---------------------------------------------------------------- RoPE table
__global__ void rope_table_kernel(float* __restrict__ tab) {
  int t = blockIdx.x * 256 + threadIdx.x;   // [0, L_*32)
  if (t >= L_ * 32) return;
  int l = t >> 5, j = t & 31;
  float inv = powf(10000.f, -(float)j * (1.f / 32.f));
  float ang = (float)l * inv;
  tab[l * 64 + j] = cosf(ang);
  tab[l * 64 + 32 + j] = sinf(ang);
}

// ---------------------------------------------------------------- AdaLN gb, all layers in one launch
__global__ __launch_bounds__(256) void adaln_gb_all_kernel(
    const float* __restrict__ emb,
    const float* __restrict__ n1w, const float* __restrict__ n2w,
    const float* __restrict__ n3w,
    const float* __restrict__ n1b, const float* __restrict__ n2b,
    const float* __restrict__ n3b,
    float* __restrict__ gb) {
  int wid = blockIdx.x * 4 + (threadIdx.x >> 6);   // [0, 18*2048)
  int lane = threadIdx.x & 63;
  int n = wid & 2047;
  int g = wid >> 11;                 // 0..17
  int layer = g / 3, j = g - layer * 3;
  const float* wbase = (j == 0 ? n1w : (j == 1 ? n2w : n3w));
  const float* bbase = (j == 0 ? n1b : (j == 1 ? n2b : n3b));
  const float* wr = wbase + ((size_t)layer * 2048 + n) * 1024;
  float s0 = 0.f, s1 = 0.f, s2 = 0.f, s3 = 0.f;
#pragma unroll
  for (int k4 = 0; k4 < 4; ++k4) {
    int idx = k4 * 64 + lane;
    float4 w4 = ((const float4*)wr)[idx];
    float4 e0 = ((const float4*)emb)[idx];
    float4 e1 = ((const float4*)(emb + 1024))[idx];
    float4 e2 = ((const float4*)(emb + 2048))[idx];
    float4 e3 = ((const float4*)(emb + 3072))[idx];
    s0 += w4.x * e0.x + w4.y * e0.y + w4.z * e0.z + w4.w * e0.w;
    s1 += w4.x * e1.x + w4.y * e1.y + w4.z * e1.z + w4.w * e1.w;
    s2 += w4.x * e2.x + w4.y * e2.y + w4.z * e2.z + w4.w * e2.w;
    s3 += w4.x * e3.x + w4.y * e3.y + w4.z * e3.z + w4.w * e3.w;
  }
  s0 = waveReduceSum(s0);
  s1 = waveReduceSum(s1);
  s2 = waveReduceSum(s2);
  s3 = waveReduceSum(s3);
  if (lane == 0) {
    float bb = bbase[(size_t)layer * 2048 + n];
    gb[((size_t)g * 4 + 0) * 2048 + n] = s0 + bb;
    gb[((size_t)g * 4 + 1) * 2048 + n] = s1 + bb;
    gb[((size_t)g * 4 + 2) * 2048 + n] = s2 + bb;
    gb[((size_t)g * 4 + 3) * 2048 + n] = s3 + bb;
  }
}

// ---------------------------------------------------------------- AdaLN apply (bf16 out)
// wave-per-row: 64 lanes x 4 float4 = 1024 floats; shuffle-only reduction,
// no LDS, no barriers; 4 independent waves per block (grid = ROWS/4).
__global__ __launch_bounds__(256) void adaln_apply_kernel(
    const float* __restrict__ x, const float* __restrict__ gb,
    ushort* __restrict__ xn) {
  const int w = threadIdx.x >> 6, lane = threadIdx.x & 63;
  const int r = blockIdx.x * 4 + w;
  const int b = r >> 10;
  const float* xr = x + (size_t)r * D_;
  float4 v[4];
  float s = 0.f, q = 0.f;
#pragma unroll
  for (int i = 0; i < 4; ++i) {
    v[i] = ((const float4*)xr)[i * 64 + lane];
    s += v[i].x + v[i].y + v[i].z + v[i].w;
    q += v[i].x * v[i].x + v[i].y * v[i].y + v[i].z * v[i].z + v[i].w * v[i].w;
  }
  s = waveReduceSum(s);
  q = waveReduceSum(q);
  const float mean = s * (1.f / D_);
  const float rstd = rsqrtf(q * (1.f / D_) - mean * mean + 1e-5f);
  const float* gp = gb + (size_t)b * 2048;
  ushort* xo = xn + (size_t)r * D_;
#pragma unroll
  for (int i = 0; i < 4; ++i) {
    float4 g  = ((const float4*)gp)[i * 64 + lane];
    float4 be = ((const float4*)(gp + D_))[i * 64 + lane];
    ushort4 o;
    o.x = f2bf((v[i].x - mean) * rstd * (1.f + g.x) + be.x);
    o.y = f2bf((v[i].y - mean) * rstd * (1.f + g.y) + be.y);
    o.z = f2bf((v[i].z - mean) * rstd * (1.f + g.z) + be.z);
    o.w = f2bf((v[i].w - mean) * rstd * (1.f + g.w) + be.w);
    ((ushort4*)xo)[i * 64 + lane] = o;
  }
}

// ---------------------------------------------------------------- bf16 MFMA GEMM (128x128)
// depth-2 pipelined (3 LDS buffers + counted vmcnt), banded XCD swizzle,
// source-chunk LDS swizzle, padded vector epilogue, optional fused RoPE.
template <int FLAGS, bool OUTBF, int ROPE>
__global__ __launch_bounds__(256) void gemm_mfma_kernel(
    const ushort* __restrict__ A, int lda,
    const ushort* __restrict__ W, int ldw,
    const float* __restrict__ bias,
    const float* __restrict__ res, int ldres,
    void* __restrict__ Cout, int ldc, int K,
    const float* __restrict__ tab, int rlim, int lmask) {
  __shared__ __align__(16) ushort lds[24576];   // 48KB: A bufs @0, W bufs @12288
  const int tid = threadIdx.x;
  const int lane = tid & 63, wv = tid >> 6;
  const int wrow = (wv >> 1) * 64, wcol = (wv & 1) * 64;
  const int fr = lane & 15;
  const int kbs = (((lane >> 4) ^ (fr & 3)) & 3) * 8;

  int trow, tcol;
  xcd_banded(trow, tcol);
  const int row0 = trow * 128;
  const int col0 = tcol * 128;

  const int c0 = wv * 2, c1 = wv * 2 + 1;
  const int sr = lane >> 2;
  const int sc = (((lane & 3) ^ (sr & 3)) & 3) * 8;
  const ushort* Ap0 = A + (size_t)(row0 + c0 * 16 + sr) * lda + sc;
  const ushort* Ap1 = A + (size_t)(row0 + c1 * 16 + sr) * lda + sc;
  const ushort* Wp0 = W + (size_t)(col0 + c0 * 16 + sr) * ldw + sc;
  const ushort* Wp1 = W + (size_t)(col0 + c1 * 16 + sr) * ldw + sc;

  f32x4 acc[4][4];
#pragma unroll
  for (int m = 0; m < 4; ++m)
#pragma unroll
    for (int n = 0; n < 4; ++n) acc[m][n] = (f32x4)0.f;

#define ASB(B) (lds + (B) * 4096)
#define WSB(B) (lds + 12288 + (B) * 4096)
#define STAGE(B, T)                                   \
  do {                                                \
    const int koff_ = (T) * 32;                       \
    gload16(Ap0 + koff_, ASB(B) + c0 * 512);          \
    gload16(Ap1 + koff_, ASB(B) + c1 * 512);          \
    gload16(Wp0 + koff_, WSB(B) + c0 * 512);          \
    gload16(Wp1 + koff_, WSB(B) + c1 * 512);          \
  } while (0)
#define WAITV8() asm volatile("s_waitcnt vmcnt(8)" ::: "memory")
#define WAITV4() asm volatile("s_waitcnt vmcnt(4)" ::: "memory")
#define WAITV0() asm volatile("s_waitcnt vmcnt(0)" ::: "memory")
#define BAR()    __builtin_amdgcn_s_barrier()
#define COMPUTE(B)                                                          \
  do {                                                                      \
    bf16x8 af[4], bfr[4];                                                   \
    _Pragma("unroll")                                                       \
    for (int m = 0; m < 4; ++m)                                             \
      af[m] = *(const bf16x8*)(ASB(B) + (wrow + m * 16 + fr) * 32 + kbs);   \
    _Pragma("unroll")                                                       \
    for (int n = 0; n < 4; ++n)                                             \
      bfr[n] = *(const bf16x8*)(WSB(B) + (wcol + n * 16 + fr) * 32 + kbs);  \
    _Pragma("unroll")                                                       \
    for (int m = 0; m < 4; ++m)                                             \
      _Pragma("unroll")                                                     \
      for (int n = 0; n < 4; ++n)                                           \
        acc[m][n] = __builtin_amdgcn_mfma_f32_16x16x32_bf16(af[m], bfr[n],  \
                                                            acc[m][n], 0, 0, 0); \
  } while (0)

  const int NT = K >> 5;
  STAGE(0, 0);
  STAGE(1, 1);
  for (int t = 0; t < NT; t += 3) {
    {
      const bool sA = (t + 2) < NT;
      if (sA) STAGE(2, t + 2);
      if ((t + 1) < NT) { if (sA) WAITV8(); else WAITV4(); } else WAITV0();
      BAR(); COMPUTE(0); BAR();
    }
    if ((t + 1) < NT) {
      const bool sB = (t + 3) < NT;
      if (sB) STAGE(0, t + 3);
      if ((t + 2) < NT) { if (sB) WAITV8(); else WAITV4(); } else WAITV0();
      BAR(); COMPUTE(1); BAR();
    }
    if ((t + 2) < NT) {
      const bool sC = (t + 4) < NT;
      if (sC) STAGE(1, t + 4);
      if ((t + 3) < NT) { if (sC) WAITV8(); else WAITV4(); } else WAITV0();
      BAR(); COMPUTE(2); BAR();
    }
  }
#undef STAGE
#undef WAITV8
#undef WAITV4
#undef WAITV0
#undef COMPUTE

  float bn[4];
  if (FLAGS & 1) {
#pragma unroll
    for (int n = 0; n < 4; ++n) bn[n] = bias[col0 + wcol + n * 16 + fr];
  }
#define EPI(v, n)                                                     \
  do {                                                                \
    if (FLAGS & 1) (v) += bn[n];                                      \
    if (FLAGS & 2) (v) = 0.5f * (v) * (1.f + erff((v) * 0.70710678118f)); \
  } while (0)

  if (OUTBF) {
    ushort* Ct = lds;                       // [128][136] bf16 (padded)
    ushort* Cg = (ushort*)Cout;
#pragma unroll
    for (int m = 0; m < 4; ++m) {
      int lr0 = wrow + m * 16 + (lane >> 4) * 4;
#pragma unroll
      for (int n = 0; n < 4; ++n) {
        int lc = wcol + n * 16 + fr;
#pragma unroll
        for (int r = 0; r < 4; ++r) {
          float v = acc[m][n][r];
          EPI(v, n);
          Ct[(lr0 + r) * 136 + lc] = f2bf(v);
        }
      }
    }
    __syncthreads();
#pragma unroll
    for (int it = 0; it < 8; ++it) {
      int lr = (tid >> 4) + it * 16;
      int lc = (tid & 15) * 8;
      union { int4 v; ushort us[8]; } vv;
      vv.v = *(const int4*)&Ct[lr * 136 + lc];
      if (ROPE && (col0 + lc) < rlim) {
        union { int4 v; ushort us[8]; } pv;
        pv.v = *(const int4*)&Ct[lr * 136 + (lc ^ 32)];
        int l = (row0 + lr) & lmask;
        int j = lc & 31;
        const float* cb = &tab[l * 64 + j];
        bool lowhalf = (lc & 63) < 32;
#pragma unroll
        for (int e = 0; e < 8; ++e) {
          float cc = cb[e], ss = cb[32 + e];
          float xv = bf2f(vv.us[e]), xp = bf2f(pv.us[e]);
          float o = lowhalf ? (xv * cc - xp * ss) : (xp * ss + xv * cc);
          vv.us[e] = f2bf(o);
        }
      }
      *(int4*)&Cg[(size_t)(row0 + lr) * ldc + col0 + lc] = vv.v;
    }
  } else {
    float* Cf = (float*)lds;                // [64][132] f32 (padded) per half
    float* Cg = (float*)Cout;
#pragma unroll
    for (int half = 0; half < 2; ++half) {
      if ((wv >> 1) == half) {
#pragma unroll
        for (int m = 0; m < 4; ++m) {
          int lr0 = m * 16 + (lane >> 4) * 4;
#pragma unroll
          for (int n = 0; n < 4; ++n) {
            int lc = wcol + n * 16 + fr;
#pragma unroll
            for (int r = 0; r < 4; ++r) {
              float v = acc[m][n][r];
              EPI(v, n);
              Cf[(lr0 + r) * 132 + lc] = v;
            }
          }
        }
      }
      __syncthreads();
#pragma unroll
      for (int it = 0; it < 8; ++it) {
        int lr = (tid >> 5) + it * 8;
        int lc = (tid & 31) * 4;
        int grow = row0 + half * 64 + lr;
        float4 v = *(const float4*)&Cf[lr * 132 + lc];
        if (FLAGS & 4) {
          float4 rv = *(const float4*)&res[(size_t)grow * ldres + col0 + lc];
          v.x += rv.x; v.y += rv.y; v.z += rv.z; v.w += rv.w;
        }
        *(float4*)&Cg[(size_t)grow * ldc + col0 + lc] = v;
      }
      __syncthreads();
    }
  }
#undef EPI
#undef ASB
#undef WSB
#undef BAR
}

// ---------------------------------------------------------------- merged cq + (ck|cv) GEMM
// z=0: big = xnb @ cqW^T (M=4096, ldc=1024, lmask=1023, virtual grid 8x32)
// z=1: kvb = ctxb @ kvW^T (M=2048, ldc=2048, lmask=511, virtual grid 16x16)
// Both: K=1024, lda=1024, bf16-out, RoPE cols<1024. Same proven pipeline.
__global__ __launch_bounds__(256) void gemm_cqkv_kernel(
    const ushort* __restrict__ Aq, const ushort* __restrict__ Ac,
    const ushort* __restrict__ Wq, const ushort* __restrict__ Wkv,
    ushort* __restrict__ Cq, ushort* __restrict__ Ckv,
    const float* __restrict__ tab) {
  __shared__ __align__(16) ushort lds[24576];
  const int tid = threadIdx.x;
  const int lane = tid & 63, wv = tid >> 6;
  const int wrow = (wv >> 1) * 64, wcol = (wv & 1) * 64;
  const int fr = lane & 15;
  const int kbs = (((lane >> 4) ^ (fr & 3)) & 3) * 8;
  const int K = 1024, lda = 1024;

  const int z = blockIdx.z;
  const ushort* A = z ? Ac : Aq;
  const ushort* W = z ? Wkv : Wq;
  ushort* Cg = z ? Ckv : Cq;
  const int ldc = z ? 2048 : 1024;
  const int lmask = z ? 511 : 1023;
  const int vgx = z ? 16 : 8;

  // banded swizzle on the virtual grid (256 blocks per z-slice)
  const int flat = blockIdx.y * gridDim.x + blockIdx.x;   // 0..255
  const int swz = (flat & 7) * 32 + (flat >> 3);
  const int bandw = vgx * 4;
  const int band = swz / bandw;
  const int rem = swz % bandw;
  const int row0 = (band * 4 + (rem & 3)) * 128;
  const int col0 = (rem >> 2) * 128;

  const int c0 = wv * 2, c1 = wv * 2 + 1;
  const int sr = lane >> 2;
  const int sc = (((lane & 3) ^ (sr & 3)) & 3) * 8;
  const ushort* Ap0 = A + (size_t)(row0 + c0 * 16 + sr) * lda + sc;
  const ushort* Ap1 = A + (size_t)(row0 + c1 * 16 + sr) * lda + sc;
  const ushort* Wp0 = W + (size_t)(col0 + c0 * 16 + sr) * lda + sc;
  const ushort* Wp1 = W + (size_t)(col0 + c1 * 16 + sr) * lda + sc;

  f32x4 acc[4][4];
#pragma unroll
  for (int m = 0; m < 4; ++m)
#pragma unroll
    for (int n = 0; n < 4; ++n) acc[m][n] = (f32x4)0.f;

#define ASB(B) (lds + (B) * 4096)
#define WSB(B) (lds + 12288 + (B) * 4096)
#define STAGE(B, T)                                   \
  do {                                                \
    const int koff_ = (T) * 32;                       \
    gload16(Ap0 + koff_, ASB(B) + c0 * 512);          \
    gload16(Ap1 + koff_, ASB(B) + c1 * 512);          \
    gload16(Wp0 + koff_, WSB(B) + c0 * 512);          \
    gload16(Wp1 + koff_, WSB(B) + c1 * 512);          \
  } while (0)
#define WAITV8() asm volatile("s_waitcnt vmcnt(8)" ::: "memory")
#define WAITV4() asm volatile("s_waitcnt vmcnt(4)" ::: "memory")
#define WAITV0() asm volatile("s_waitcnt vmcnt(0)" ::: "memory")
#define BAR()    __builtin_amdgcn_s_barrier()
#define COMPUTE(B)                                                          \
  do {                                                                      \
    bf16x8 af[4], bfr[4];                                                   \
    _Pragma("unroll")                                                       \
    for (int m = 0; m < 4; ++m)                                             \
      af[m] = *(const bf16x8*)(ASB(B) + (wrow + m * 16 + fr) * 32 + kbs);   \
    _Pragma("unroll")                                                       \
    for (int n = 0; n < 4; ++n)                                             \
      bfr[n] = *(const bf16x8*)(WSB(B) + (wcol + n * 16 + fr) * 32 + kbs);  \
    _Pragma("unroll")                                                       \
    for (int m = 0; m < 4; ++m)                                             \
      _Pragma("unroll")                                                     \
      for (int n = 0; n < 4; ++n)                                           \
        acc[m][n] = __builtin_amdgcn_mfma_f32_16x16x32_bf16(af[m], bfr[n],  \
                                                            acc[m][n], 0, 0, 0); \
  } while (0)

  const int NT = K >> 5;   // 32
  STAGE(0, 0);
  STAGE(1, 1);
  for (int t = 0; t < NT; t += 3) {
    {
      const bool sA = (t + 2) < NT;
      if (sA) STAGE(2, t + 2);
      if ((t + 1) < NT) { if (sA) WAITV8(); else WAITV4(); } else WAITV0();
      BAR(); COMPUTE(0); BAR();
    }
    if ((t + 1) < NT) {
      const bool sB = (t + 3) < NT;
      if (sB) STAGE(0, t + 3);
      if ((t + 2) < NT) { if (sB) WAITV8(); else WAITV4(); } else WAITV0();
      BAR(); COMPUTE(1); BAR();
    }
    if ((t + 2) < NT) {
      const bool sC = (t + 4) < NT;
      if (sC) STAGE(1, t + 4);
      if ((t + 3) < NT) { if (sC) WAITV8(); else WAITV4(); } else WAITV0();
      BAR(); COMPUTE(2); BAR();
    }
  }
#undef STAGE
#undef WAITV8
#undef WAITV4
#undef WAITV0
#undef COMPUTE

  // bf16 epilogue with fused RoPE (cols < 1024)
  ushort* Ct = lds;                       // [128][136]
#pragma unroll
  for (int m = 0; m < 4; ++m) {
    int lr0 = wrow + m * 16 + (lane >> 4) * 4;
#pragma unroll
    for (int n = 0; n < 4; ++n) {
      int lc = wcol + n * 16 + fr;
#pragma unroll
      for (int r = 0; r < 4; ++r)
        Ct[(lr0 + r) * 136 + lc] = f2bf(acc[m][n][r]);
    }
  }
  __syncthreads();
#pragma unroll
  for (int it = 0; it < 8; ++it) {
    int lr = (tid >> 4) + it * 16;
    int lc = (tid & 15) * 8;
    union { int4 v; ushort us[8]; } vv;
    vv.v = *(const int4*)&Ct[lr * 136 + lc];
    if ((col0 + lc) < 1024) {
      union { int4 v; ushort us[8]; } pv;
      pv.v = *(const int4*)&Ct[lr * 136 + (lc ^ 32)];
      int l = (row0 + lr) & lmask;
      int j = lc & 31;
      const float* cb = &tab[l * 64 + j];
      bool lowhalf = (lc & 63) < 32;
#pragma unroll
      for (int e = 0; e < 8; ++e) {
        float cc = cb[e], ss = cb[32 + e];
        float xv = bf2f(vv.us[e]), xp = bf2f(pv.us[e]);
        float o = lowhalf ? (xv * cc - xp * ss) : (xp * ss + xv * cc);
        vv.us[e] = f2bf(o);
      }
    }
    *(int4*)&Cg[(size_t)(row0 + lr) * ldc + col0 + lc] = vv.v;
  }
#undef ASB
#undef WSB
#undef BAR
}

// ---------------------------------------------------------------- 256x256 8-wave GEMM
// BK=64, double-buffered 128KB LDS, one barrier + one late vmcnt(0) per K-tile;
// banded XCD swizzle; chunk-XOR LDS swizzle; setprio around MFMA. bf16 out.
// Epilogue: linear [256][256] LDS tile -> vector stores.
// FLAGS: 1=+bias, 2=gelu. Requires K%64==0, M,N%256==0, gridDim.y%4==0.
template <int FLAGS, int ROPE>
__global__ __launch_bounds__(512, 2) void gemm256_kernel(
    const ushort* __restrict__ A, int lda,
    const ushort* __restrict__ W, int ldw,
    const float* __restrict__ bias,
    ushort* __restrict__ Cout, int ldc, int K,
    const float* __restrict__ tab, int rlim, int lmask) {
  __shared__ __align__(16) ushort lds[65536];   // 128 KB
  const int tid = threadIdx.x;
  const int lane = tid & 63, wid = tid >> 6;
  const int wm = wid >> 2, wn = wid & 3;        // 2 x 4 wave grid
  const int fr = lane & 15, hi = lane >> 4;

  int trow, tcol;
  xcd_banded(trow, tcol);
  const int row0 = trow * 256;
  const int col0 = tcol * 256;

  const int srow = lane >> 3;
  const int scol = ((lane & 7) ^ srow) * 8;
  const ushort* Asrc[4];
  const ushort* Wsrc[4];
#pragma unroll
  for (int j = 0; j < 4; ++j) {
    int r = wid * 32 + j * 8 + srow;
    Asrc[j] = A + (size_t)(row0 + r) * lda + scol;
    Wsrc[j] = W + (size_t)(col0 + r) * ldw + scol;
  }
#define AB256(b) (lds + (b) * 16384)
#define WB256(b) (lds + 32768 + (b) * 16384)
#define STG256(b, T)                                      \
  do {                                                    \
    const int kk_ = (T) * 64;                             \
    _Pragma("unroll")                                     \
    for (int j = 0; j < 4; ++j) {                         \
      int ch_ = wid * 4 + j;                              \
      gload16(Asrc[j] + kk_, AB256(b) + ch_ * 512);       \
      gload16(Wsrc[j] + kk_, WB256(b) + ch_ * 512);       \
    }                                                     \
  } while (0)

  f32x4 acc[8][4];
#pragma unroll
  for (int m = 0; m < 8; ++m)
#pragma unroll
    for (int n = 0; n < 4; ++n) acc[m][n] = (f32x4)0.f;

  const int NT = K >> 6;
  STG256(0, 0);
  asm volatile("s_waitcnt vmcnt(0)" ::: "memory");
  __builtin_amdgcn_s_barrier();
  for (int t = 0; t < NT; ++t) {
    const int cur = t & 1;
    if (t + 1 < NT) STG256(cur ^ 1, t + 1);   // issue BEFORE compute
    const ushort* ab = AB256(cur);
    const ushort* wb = WB256(cur);
    __builtin_amdgcn_s_setprio(1);
#pragma unroll
    for (int s = 0; s < 2; ++s) {
      bf16x8 wf[4];
#pragma unroll
      for (int n = 0; n < 4; ++n) {
        int row = wn * 64 + n * 16 + fr;
        wf[n] = *(const bf16x8*)(wb + row * 64 + (((s * 4 + hi) ^ (fr & 7)) * 8));
      }
#pragma unroll
      for (int m = 0; m < 8; ++m) {
        int row = wm * 128 + m * 16 + fr;
        bf16x8 af = *(const bf16x8*)(ab + row * 64 + (((s * 4 + hi) ^ (fr & 7)) * 8));
#pragma unroll
        for (int n = 0; n < 4; ++n)
          acc[m][n] = __builtin_amdgcn_mfma_f32_16x16x32_bf16(af, wf[n],
                                                              acc[m][n], 0, 0, 0);
      }
    }
    __builtin_amdgcn_s_setprio(0);
    asm volatile("s_waitcnt vmcnt(0)" ::: "memory");
    __builtin_amdgcn_s_barrier();
  }
#undef STG256

  float bn[4];
  if (FLAGS & 1) {
#pragma unroll
    for (int n = 0; n < 4; ++n) bn[n] = bias[col0 + wn * 64 + n * 16 + fr];
  }
  ushort* Ct = lds;
#pragma unroll
  for (int m = 0; m < 8; ++m) {
    int lr0 = wm * 128 + m * 16 + hi * 4;
#pragma unroll
    for (int n = 0; n < 4; ++n) {
      int lc = wn * 64 + n * 16 + fr;
#pragma unroll
      for (int r = 0; r < 4; ++r) {
        float v = acc[m][n][r];
        if (FLAGS & 1) v += bn[n];
        if (FLAGS & 2) v = 0.5f * v * (1.f + erff(v * 0.70710678118f));
        Ct[(lr0 + r) * 256 + lc] = f2bf(v);
      }
    }
  }
  __syncthreads();
#pragma unroll
  for (int it = 0; it < 16; ++it) {
    int idx = tid + it * 512;
    int lr = idx >> 5;
    int lc = (idx & 31) * 8;
    union { int4 v; ushort us[8]; } vv;
    vv.v = *(const int4*)&Ct[lr * 256 + lc];
    if (ROPE && (col0 + lc) < rlim) {
      union { int4 v; ushort us[8]; } pv;
      pv.v = *(const int4*)&Ct[lr * 256 + (lc ^ 32)];
      int l = (row0 + lr) & lmask;
      int j = lc & 31;
      const float* cb = &tab[l * 64 + j];
      bool lowhalf = (lc & 63) < 32;
#pragma unroll
      for (int e = 0; e < 8; ++e) {
        float cc = cb[e], ss = cb[32 + e];
        float xv = bf2f(vv.us[e]), xp = bf2f(pv.us[e]);
        float o = lowhalf ? (xv * cc - xp * ss) : (xp * ss + xv * cc);
        vv.us[e] = f2bf(o);
      }
    }
    *(int4*)&Cout[(size_t)(row0 + lr) * ldc + col0 + lc] = vv.v;
  }
#undef AB256
#undef WB256
}

// ---------------------------------------------------------------- MFMA flash attention
// 128 q-rows/block, 8 waves: waves 0-3 stage K, waves 4-7 stage V (transposed).
// Swapped QK^T, register-exchange P, K/V dbuf + async-stage, T13 defer-max.
#define SWZ(row, col) (((row) << 6) + ((col) ^ (((row) & 7) << 3)))
__global__ __launch_bounds__(512) void attn_mfma_kernel(
    const ushort* __restrict__ Q, int ldq,
    const ushort* __restrict__ K, int ldk,
    const ushort* __restrict__ V, int ldv,
    ushort* __restrict__ O, int ldo,
    int Lq, int Lk, float scale) {
  __shared__ __align__(16) ushort Ks[2][64 * 64];
  __shared__ __align__(16) ushort Vt[2][64 * 64];
  __shared__ __align__(16) ushort Os[128 * 64];
  const int tid = threadIdx.x;
  const int lane = tid & 63, w = tid >> 6;       // w in 0..7
  const int fr = lane & 15, hi = lane >> 4, kb = hi * 8;
  const int b = blockIdx.z, h = blockIdx.y, q0 = blockIdx.x * 128;
  const int kw = w & 3;
  const bool isK = (w < 4);

  bf16x8 aq[2];
  {
    const ushort* qp = Q + (size_t)(b * Lq + q0 + w * 16 + fr) * ldq + h * 64 + kb;
    union { bf16x8 v; ushort us[8]; } t0, t1;
    t0.v = *(const bf16x8*)qp;
    t1.v = *(const bf16x8*)(qp + 32);
#pragma unroll
    for (int e = 0; e < 8; ++e) {
      t0.us[e] = f2bf(bf2f(t0.us[e]) * scale);
      t1.us[e] = f2bf(bf2f(t1.us[e]) * scale);
    }
    aq[0] = t0.v;
    aq[1] = t1.v;
  }

  const int ldkv = isK ? ldk : ldv;
  const ushort* kvbase = (isK ? K : V) + (size_t)(b * Lk + lane) * ldkv
                         + h * 64 + kw * 16;
  const size_t kvstep = (size_t)64 * ldkv;
  int4 r0, r1;
#define LOADKV(T)                                      \
  do {                                                 \
    const ushort* p_ = kvbase + (size_t)(T) * kvstep;  \
    r0 = ((const int4*)p_)[0];                         \
    r1 = ((const int4*)p_)[1];                         \
  } while (0)
#define WRITEKV(P)                                                        \
  do {                                                                    \
    if (isK) {                                                            \
      *(int4*)&Ks[P][SWZ(lane, kw * 16)]     = r0;                        \
      *(int4*)&Ks[P][SWZ(lane, kw * 16 + 8)] = r1;                        \
    } else {                                                              \
      union { int4 v; ushort us[8]; } u0_, u1_;                           \
      u0_.v = r0; u1_.v = r1;                                             \
      _Pragma("unroll")                                                   \
      for (int e = 0; e < 8; ++e) Vt[P][SWZ(kw * 16 + e, lane)] = u0_.us[e]; \
      _Pragma("unroll")                                                   \
      for (int e = 0; e < 8; ++e) Vt[P][SWZ(kw * 16 + 8 + e, lane)] = u1_.us[e]; \
    }                                                                     \
  } while (0)

  f32x4 oacc[4];
#pragma unroll
  for (int n = 0; n < 4; ++n) oacc[n] = (f32x4)0.f;
  float mq = -1e30f, lq = 0.f;
  const int ntiles = Lk >> 6;
  const bool lowhalf = (lane < 32);
  const bool sendSelf = (hi == 1 || hi == 2);

  LOADKV(0);
  WRITEKV(0);
  int p = 0;
  for (int t = 0; t < ntiles; ++t) {
    if (t + 1 < ntiles) LOADKV(t + 1);
    __syncthreads();

    f32x4 sacc[4];
#pragma unroll
    for (int n = 0; n < 4; ++n) sacc[n] = (f32x4)0.f;
    __builtin_amdgcn_s_setprio(1);
#pragma unroll
    for (int s = 0; s < 2; ++s) {
#pragma unroll
      for (int n = 0; n < 4; ++n) {
        bf16x8 ak = *(const bf16x8*)&Ks[p][SWZ(n * 16 + fr, s * 32 + kb)];
        sacc[n] = __builtin_amdgcn_mfma_f32_16x16x32_bf16(ak, aq[s], sacc[n], 0, 0, 0);
      }
    }
    __builtin_amdgcn_s_setprio(0);

    float sm = sacc[0][0];
#pragma unroll
    for (int n = 0; n < 4; ++n)
#pragma unroll
      for (int r = 0; r < 4; ++r) sm = fmaxf(sm, sacc[n][r]);
    sm = fmaxf(sm, __shfl_xor(sm, 16));
    sm = fmaxf(sm, __shfl_xor(sm, 32));
    // T13 defer-max: if every row's max growth <= 8, keep old running max.
    const bool defer = __all(sm - mq <= 8.f);
    if (!defer) {
      float mnew = fmaxf(mq, sm);
      float corrq = __expf(mq - mnew);
      mq = mnew;
      lq *= corrq;
      float c0 = __shfl(corrq, hi * 4 + 0);
      float c1 = __shfl(corrq, hi * 4 + 1);
      float c2 = __shfl(corrq, hi * 4 + 2);
      float c3 = __shfl(corrq, hi * 4 + 3);
#pragma unroll
      for (int n = 0; n < 4; ++n) {
        oacc[n][0] *= c0; oacc[n][1] *= c1; oacc[n][2] *= c2; oacc[n][3] *= c3;
      }
    }
    float pe[4][4];
    float psum = 0.f;
#pragma unroll
    for (int n = 0; n < 4; ++n)
#pragma unroll
      for (int r = 0; r < 4; ++r) {
        pe[n][r] = __expf(sacc[n][r] - mq);
        psum += pe[n][r];
      }
    psum += __shfl_xor(psum, 16);
    psum += __shfl_xor(psum, 32);
    lq += psum;

    uint32 u00 = pk2(pe[0][0], pe[0][1]), u01 = pk2(pe[0][2], pe[0][3]);
    uint32 u10 = pk2(pe[1][0], pe[1][1]), u11 = pk2(pe[1][2], pe[1][3]);
    uint32 u20 = pk2(pe[2][0], pe[2][1]), u21 = pk2(pe[2][2], pe[2][3]);
    uint32 u30 = pk2(pe[3][0], pe[3][1]), u31 = pk2(pe[3][2], pe[3][3]);
    uint32 selfw0 = lowhalf ? u00 : u10;
    uint32 selfw1 = lowhalf ? u01 : u11;
    uint32 selfw2 = lowhalf ? u20 : u30;
    uint32 selfw3 = lowhalf ? u21 : u31;
    uint32 send10 = lowhalf ? u10 : u00;
    uint32 send11 = lowhalf ? u11 : u01;
    uint32 send12 = lowhalf ? u30 : u20;
    uint32 send13 = lowhalf ? u31 : u21;
    uint32 farw0 = __shfl_xor((int)send10, 32);
    uint32 farw1 = __shfl_xor((int)send11, 32);
    uint32 farw2 = __shfl_xor((int)send12, 32);
    uint32 farw3 = __shfl_xor((int)send13, 32);
    uint32 s20 = sendSelf ? selfw0 : farw0;
    uint32 s21 = sendSelf ? selfw1 : farw1;
    uint32 s22 = sendSelf ? selfw2 : farw2;
    uint32 s23 = sendSelf ? selfw3 : farw3;
    uint32 rcv0 = __shfl_xor((int)s20, 16);
    uint32 rcv1 = __shfl_xor((int)s21, 16);
    uint32 rcv2 = __shfl_xor((int)s22, 16);
    uint32 rcv3 = __shfl_xor((int)s23, 16);
    union { uint32 wd[4]; bf16x8 v; } pa0, pa1;
    if (hi == 0) {
      pa0.wd[0] = selfw0; pa0.wd[1] = selfw1; pa0.wd[2] = rcv0; pa0.wd[3] = rcv1;
      pa1.wd[0] = selfw2; pa1.wd[1] = selfw3; pa1.wd[2] = rcv2; pa1.wd[3] = rcv3;
    } else if (hi == 1) {
      pa0.wd[0] = rcv0; pa0.wd[1] = rcv1; pa0.wd[2] = farw0; pa0.wd[3] = farw1;
      pa1.wd[0] = rcv2; pa1.wd[1] = rcv3; pa1.wd[2] = farw2; pa1.wd[3] = farw3;
    } else if (hi == 2) {
      pa0.wd[0] = farw0; pa0.wd[1] = farw1; pa0.wd[2] = rcv0; pa0.wd[3] = rcv1;
      pa1.wd[0] = farw2; pa1.wd[1] = farw3; pa1.wd[2] = rcv2; pa1.wd[3] = rcv3;
    } else {
      pa0.wd[0] = rcv0; pa0.wd[1] = rcv1; pa0.wd[2] = selfw0; pa0.wd[3] = selfw1;
      pa1.wd[0] = rcv2; pa1.wd[1] = rcv3; pa1.wd[2] = selfw2; pa1.wd[3] = selfw3;
    }

    __builtin_amdgcn_s_setprio(1);
#pragma unroll
    for (int n = 0; n < 4; ++n) {
      bf16x8 bv0 = *(const bf16x8*)&Vt[p][SWZ(n * 16 + fr, 0 * 32 + kb)];
      oacc[n] = __builtin_amdgcn_mfma_f32_16x16x32_bf16(pa0.v, bv0, oacc[n], 0, 0, 0);
      bf16x8 bv1 = *(const bf16x8*)&Vt[p][SWZ(n * 16 + fr, 1 * 32 + kb)];
      oacc[n] = __builtin_amdgcn_mfma_f32_16x16x32_bf16(pa1.v, bv1, oacc[n], 0, 0, 0);
    }
    __builtin_amdgcn_s_setprio(0);

    __syncthreads();
    if (t + 1 < ntiles) WRITEKV(p ^ 1);
    p ^= 1;
  }
#undef LOADKV
#undef WRITEKV

  float linv[4];
#pragma unroll
  for (int r = 0; r < 4; ++r) linv[r] = 1.f / __shfl(lq, hi * 4 + r);
#pragma unroll
  for (int r = 0; r < 4; ++r) {
    int rl = w * 16 + hi * 4 + r;
#pragma unroll
    for (int n = 0; n < 4; ++n)
      Os[SWZ(rl, n * 16 + fr)] = f2bf(oacc[n][r] * linv[r]);
  }
  __syncthreads();
  {
    int row = tid >> 2, cbk = (tid & 3) * 16;
    ushort* op = O + (size_t)(b * Lq + q0 + row) * ldo + h * 64 + cbk;
    int4 o0 = *(const int4*)&Os[SWZ(row, cbk)];
    int4 o1 = *(const int4*)&Os[SWZ(row, cbk + 8)];
    ((int4*)op)[0] = o0;
    ((int4*)op)[1] = o1;
  }
}

// ---------------------------------------------------------------- launch
extern "C" void kernel_launch(void* const* d_in, const int* in_sizes, int n_in,
                              void* d_out, int out_size, void* d_ws, size_t ws_size,
                              hipStream_t stream) {
  const float* x_in = (const float*)d_in[0];
  const float* emb  = (const float*)d_in[1];
  const float* ctx  = (const float*)d_in[2];
  const float* n1w = (const float*)d_in[5];
  const float* n1b = (const float*)d_in[6];
  const float* n2w = (const float*)d_in[7];
  const float* n2b = (const float*)d_in[8];
  const float* n3w = (const float*)d_in[9];
  const float* n3b = (const float*)d_in[10];
  const float* qkvw = (const float*)d_in[11];
  const float* sow  = (const float*)d_in[12];
  const float* cqw  = (const float*)d_in[13];
  const float* ckw  = (const float*)d_in[14];
  const float* cvw  = (const float*)d_in[15];
  const float* cow  = (const float*)d_in[16];
  const float* f1w  = (const float*)d_in[17];
  const float* f1b  = (const float*)d_in[18];
  const float* f2w  = (const float*)d_in[19];
  const float* f2b  = (const float*)d_in[20];

  float* xcur = (float*)d_out;

  // workspace layout
  ushort* xnb  = (ushort*)d_ws;                        // 4096x1024 bf16
  ushort* big  = xnb + (size_t)4096 * 1024;            // 4096x4096 bf16 (qkv/q/h)
  ushort* obb  = big + (size_t)4096 * 4096;            // 4096x1024 bf16 (attn out)
  ushort* kvb  = obb + (size_t)4096 * 1024;            // 2048x2048 bf16 (K|V packed)
  ushort* ctxb = kvb + (size_t)2048 * 2048;            // 2048x1024 bf16 (persistent)
  float*  gball= (float*)(ctxb + (size_t)2048 * 1024); // 18*4*2048 f32
  float*  tab  = gball + 18 * 4 * 2048;                // 65536 f32
  ushort* scrW = (ushort*)(tab + 65536);               // 4096x1024 bf16 scratch
  const size_t SZ_QKV = (size_t)NL_ * 3072 * 1024;
  const size_t SZ_SQ  = (size_t)NL_ * 1024 * 1024;
  const size_t SZ_F   = (size_t)NL_ * 4096 * 1024;
  const size_t M1 = (size_t)1024 * 1024;
  ushort* wqkv = scrW + (size_t)4096 * 1024;
  ushort* wso  = wqkv + SZ_QKV;
  ushort* wcq  = wso + SZ_SQ;
  ushort* wkv  = wcq + SZ_SQ;          // [NL][2048][1024] packed ck|cv
  ushort* wco  = wkv + 2 * SZ_SQ;
  ushort* wf1  = wco + SZ_SQ;
  ushort* wf2  = wf1 + SZ_F;
  const size_t need_full = (size_t)((char*)(wf2 + SZ_F) - (char*)d_ws);
  const bool wbfull = (ws_size >= need_full);

  hipMemcpyAsync(xcur, x_in, (size_t)B_ * L_ * D_ * sizeof(float),
                 hipMemcpyDeviceToDevice, stream);
  rope_table_kernel<<<128, 256, 0, stream>>>(tab);
  adaln_gb_all_kernel<<<9216, 256, 0, stream>>>(emb, n1w, n2w, n3w,
                                                n1b, n2b, n3b, gball);
  cvt_bf16_kernel<<<1024, 256, 0, stream>>>(ctx, ctxb,
                                            (int)((size_t)2048 * 1024 / 4));

  if (wbfull) {
    cvt_bf16_kernel<<<2048, 256, 0, stream>>>(qkvw, wqkv, (int)(SZ_QKV / 4));
    cvt_bf16_kernel<<<2048, 256, 0, stream>>>(sow,  wso,  (int)(SZ_SQ / 4));
    cvt_bf16_kernel<<<2048, 256, 0, stream>>>(cqw,  wcq,  (int)(SZ_SQ / 4));
    cvt_pack_kv_kernel<<<2048, 256, 0, stream>>>(ckw, cvw, wkv,
                                                 (int)(2 * SZ_SQ / 4));
    cvt_bf16_kernel<<<2048, 256, 0, stream>>>(cow,  wco,  (int)(SZ_SQ / 4));
    cvt_bf16_kernel<<<2048, 256, 0, stream>>>(f1w,  wf1,  (int)(SZ_F / 4));
    cvt_bf16_kernel<<<2048, 256, 0, stream>>>(f2w,  wf2,  (int)(SZ_F / 4));
  }

  auto prepW = [&](const float* src, ushort* full, size_t layerOff,
                   size_t nelem) -> const ushort* {
    if (wbfull) return full + layerOff;
    cvt_bf16_kernel<<<1024, 256, 0, stream>>>(src + layerOff, scrW,
                                              (int)(nelem / 4));
    return scrW;
  };

  const int ROWS = B_ * L_;
  const dim3 blk(256);
  const dim3 blk512(512);

  for (int i = 0; i < NL_; ++i) {
    const float* f1bi = f1b + (size_t)i * DFF_;
    const float* f2bi = f2b + (size_t)i * D_;

    // ---- self-attention block ----
    adaln_apply_kernel<<<ROWS / 4, blk, 0, stream>>>(
        xcur, gball + (size_t)(i * 3 + 0) * 4 * 2048, xnb);
    gemm256_kernel<0, 1><<<dim3(12, 16), blk512, 0, stream>>>(       // rope q,k
        xnb, D_, prepW(qkvw, wqkv, (size_t)i * 3072 * 1024, (size_t)3072 * 1024),
        D_, nullptr, big, 3072, D_, tab, 2048, 1023);
    attn_mfma_kernel<<<dim3(L_ / 128, H_, B_), blk512, 0, stream>>>(
        big, 3072, big + 1024, 3072, big + 2048, 3072, obb, D_, L_, L_, 0.125f);
    gemm_mfma_kernel<4, false, 0><<<dim3(8, 32), blk, 0, stream>>>(
        obb, D_, prepW(sow, wso, (size_t)i * M1, M1),
        D_, nullptr, xcur, D_, xcur, D_, D_, tab, 0, 0);

    // ---- cross-attention block ----
    adaln_apply_kernel<<<ROWS / 4, blk, 0, stream>>>(
        xcur, gball + (size_t)(i * 3 + 1) * 4 * 2048, xnb);
    // merged cq + (ck|cv) projections (rope on q and k halves)
    {
      const ushort *wcqi, *wkvi;
      if (wbfull) {
        wcqi = wcq + (size_t)i * M1;
        wkvi = wkv + (size_t)i * 2 * M1;
      } else {
        cvt_bf16_kernel<<<512, 256, 0, stream>>>(cqw + (size_t)i * M1, scrW,
                                                 (int)(M1 / 4));
        cvt_bf16_kernel<<<512, 256, 0, stream>>>(ckw + (size_t)i * M1,
                                                 scrW + M1, (int)(M1 / 4));
        cvt_bf16_kernel<<<512, 256, 0, stream>>>(cvw + (size_t)i * M1,
                                                 scrW + 2 * M1, (int)(M1 / 4));
        wcqi = scrW;
        wkvi = scrW + M1;
      }
      gemm_cqkv_kernel<<<dim3(16, 16, 2), blk, 0, stream>>>(
          xnb, ctxb, wcqi, wkvi, big, kvb, tab);
    }
    attn_mfma_kernel<<<dim3(L_ / 128, H_, B_), blk512, 0, stream>>>(
        big, 1024, kvb, 2048, kvb + 1024, 2048, obb, D_, L_, LC_, 0.125f);
    gemm_mfma_kernel<4, false, 0><<<dim3(8, 32), blk, 0, stream>>>(
        obb, D_, prepW(cow, wco, (size_t)i * M1, M1),
        D_, nullptr, xcur, D_, xcur, D_, D_, tab, 0, 0);

    // ---- FFN block ----
    adaln_apply_kernel<<<ROWS / 4, blk, 0, stream>>>(
        xcur, gball + (size_t)(i * 3 + 2) * 4 * 2048, xnb);
    gemm256_kernel<3, 0><<<dim3(16, 16), blk512, 0, stream>>>(       // bias+gelu
        xnb, D_, prepW(f1w, wf1, (size_t)i * 4096 * 1024, (size_t)4096 * 1024),
        D_, f1bi, big, DFF_, D_, tab, 0, 0);
    gemm_mfma_kernel<5, false, 0><<<dim3(8, 32), blk, 0, stream>>>(
        big, DFF_, prepW(f2w, wf2, (size_t)i * 4096 * 1024, (size_t)4096 * 1024),
        DFF_, f2bi, xcur, D_, xcur, D_, DFF_, tab, 0, 0);
  }
}

// Round 17
// 1951.795 us; speedup vs baseline: 1.0592x; 1.0050x over previous
//
#include <hip/hip_runtime.h>
#include <hip/hip_bf16.h>
#include <math.h>

// Problem constants
#define D_    1024
#define H_    16
#define HD_   64
#define NL_   6
#define DFF_  4096
#define B_    4
#define L_    1024
#define LC_   512

typedef short bf16x8 __attribute__((ext_vector_type(8)));
typedef float f32x4  __attribute__((ext_vector_type(4)));
typedef unsigned int uint32;

// ---------------------------------------------------------------- utilities
__device__ __forceinline__ float waveReduceSum(float v) {
#pragma unroll
  for (int off = 32; off > 0; off >>= 1) v += __shfl_xor(v, off);
  return v;
}
__device__ __forceinline__ ushort f2bf(float f) {
  union { __hip_bfloat16 h; ushort u; } c;
  c.h = __float2bfloat16(f);
  return c.u;
}
__device__ __forceinline__ float bf2f(ushort u) {
  union { uint32 i; float f; } c;
  c.i = ((uint32)u) << 16;
  return c.f;
}
__device__ __forceinline__ uint32 pk2(float a, float b) {
  return (uint32)f2bf(a) | ((uint32)f2bf(b) << 16);
}
// async global->LDS, 16B per lane. lds base must be wave-uniform (m104).
__device__ __forceinline__ void gload16(const ushort* g, ushort* l) {
  __builtin_amdgcn_global_load_lds(
      (const __attribute__((address_space(1))) uint32*)g,
      (__attribute__((address_space(3))) uint32*)l, 16, 0, 0);
}

// banded XCD swizzle: XCD chunk covers 4 tile-rows x (chunk/4) tile-cols.
// Requires gridDim.y % 4 == 0 and nwg % 8 == 0. Returns row,col tile indices.
__device__ __forceinline__ void xcd_banded(int& trow, int& tcol) {
  const int nwg = gridDim.x * gridDim.y;
  const int wg = blockIdx.y * gridDim.x + blockIdx.x;
  const int q = nwg >> 3;
  const int swz = (wg & 7) * q + (wg >> 3);
  const int bandw = gridDim.x * 4;
  const int band = swz / bandw;
  const int rem = swz % bandw;
  trow = band * 4 + (rem & 3);
  tcol = rem >> 2;
}

// ---------------------------------------------------------------- fp32 -> bf16 bulk convert
__global__ __launch_bounds__(256) void cvt_bf16_kernel(
    const float* __restrict__ in, ushort* __restrict__ out, int n4) {
  int i = blockIdx.x * 256 + threadIdx.x;
  int stride = gridDim.x * 256;
  for (; i < n4; i += stride) {
    float4 v = ((const float4*)in)[i];
    ushort4 o = {f2bf(v.x), f2bf(v.y), f2bf(v.z), f2bf(v.w)};
    ((ushort4*)out)[i] = o;
  }
}

// all six plain weight arrays in ONE launch (segment sizes in float4 units):
// qkv 4718592 | so 1572864 | cq 1572864 | co 1572864 | f1 6291456 | f2 6291456
__global__ __launch_bounds__(256) void cvt_weights_kernel(
    const float* __restrict__ qkv, const float* __restrict__ so,
    const float* __restrict__ cq,  const float* __restrict__ co,
    const float* __restrict__ f1,  const float* __restrict__ f2,
    ushort* __restrict__ dqkv, ushort* __restrict__ dso,
    ushort* __restrict__ dcq,  ushort* __restrict__ dco,
    ushort* __restrict__ df1,  ushort* __restrict__ df2) {
  const int stride = gridDim.x * 256;
  for (int i = blockIdx.x * 256 + threadIdx.x; i < 22020096; i += stride) {
    int j = i;
    const float* s;
    ushort* d;
    if (j < 4718592) { s = qkv; d = dqkv; }
    else if ((j -= 4718592) < 1572864) { s = so; d = dso; }
    else if ((j -= 1572864) < 1572864) { s = cq; d = dcq; }
    else if ((j -= 1572864) < 1572864) { s = co; d = dco; }
    else if ((j -= 1572864) < 6291456) { s = f1; d = df1; }
    else { j -= 6291456; s = f2; d = df2; }
    float4 v = ((const float4*)s)[j];
    ushort4 o = {f2bf(v.x), f2bf(v.y), f2bf(v.z), f2bf(v.w)};
    ((ushort4*)d)[j] = o;
  }
}

// packed [NL][2048][1024]: rows 0-1023 = ck layer, 1024-2047 = cv layer
__global__ __launch_bounds__(256) void cvt_pack_kv_kernel(
    const float* __restrict__ ck, const float* __restrict__ cv,
    ushort* __restrict__ out, int n4) {
  int i = blockIdx.x * 256 + threadIdx.x;
  int stride = gridDim.x * 256;
  for (; i < n4; i += stride) {
    int row = i >> 8;               // 256 float4 per 1024-wide row
    int cb = i & 255;
    int layer = row >> 11;
    int sel = (row >> 10) & 1;
    int r = row & 1023;
    const float* src = (sel ? cv : ck) +
                       (((size_t)layer << 10) + r) * 1024 + cb * 4;
    float4 v = *(const float4*)src;
    ushort4 o = {f2bf(v.x), f2bf(v.y), f2bf(v.z), f2bf(v.w)};
    ((ushort4*)out)[i] = o;
  }
}

// ---------------------------------------------------------------- RoPE table
__global__ void rope_table_kernel(float* __restrict__ tab) {
  int t = blockIdx.x * 256 + threadIdx.x;   // [0, L_*32)
  if (t >= L_ * 32) return;
  int l = t >> 5, j = t & 31;
  float inv = powf(10000.f, -(float)j * (1.f / 32.f));
  float ang = (float)l * inv;
  tab[l * 64 + j] = cosf(ang);
  tab[l * 64 + 32 + j] = sinf(ang);
}

// ---------------------------------------------------------------- AdaLN gb, all layers in one launch
__global__ __launch_bounds__(256) void adaln_gb_all_kernel(
    const float* __restrict__ emb,
    const float* __restrict__ n1w, const float* __restrict__ n2w,
    const float* __restrict__ n3w,
    const float* __restrict__ n1b, const float* __restrict__ n2b,
    const float* __restrict__ n3b,
    float* __restrict__ gb) {
  int wid = blockIdx.x * 4 + (threadIdx.x >> 6);   // [0, 18*2048)
  int lane = threadIdx.x & 63;
  int n = wid & 2047;
  int g = wid >> 11;                 // 0..17
  int layer = g / 3, j = g - layer * 3;
  const float* wbase = (j == 0 ? n1w : (j == 1 ? n2w : n3w));
  const float* bbase = (j == 0 ? n1b : (j == 1 ? n2b : n3b));
  const float* wr = wbase + ((size_t)layer * 2048 + n) * 1024;
  float s0 = 0.f, s1 = 0.f, s2 = 0.f, s3 = 0.f;
#pragma unroll
  for (int k4 = 0; k4 < 4; ++k4) {
    int idx = k4 * 64 + lane;
    float4 w4 = ((const float4*)wr)[idx];
    float4 e0 = ((const float4*)emb)[idx];
    float4 e1 = ((const float4*)(emb + 1024))[idx];
    float4 e2 = ((const float4*)(emb + 2048))[idx];
    float4 e3 = ((const float4*)(emb + 3072))[idx];
    s0 += w4.x * e0.x + w4.y * e0.y + w4.z * e0.z + w4.w * e0.w;
    s1 += w4.x * e1.x + w4.y * e1.y + w4.z * e1.z + w4.w * e1.w;
    s2 += w4.x * e2.x + w4.y * e2.y + w4.z * e2.z + w4.w * e2.w;
    s3 += w4.x * e3.x + w4.y * e3.y + w4.z * e3.z + w4.w * e3.w;
  }
  s0 = waveReduceSum(s0);
  s1 = waveReduceSum(s1);
  s2 = waveReduceSum(s2);
  s3 = waveReduceSum(s3);
  if (lane == 0) {
    float bb = bbase[(size_t)layer * 2048 + n];
    gb[((size_t)g * 4 + 0) * 2048 + n] = s0 + bb;
    gb[((size_t)g * 4 + 1) * 2048 + n] = s1 + bb;
    gb[((size_t)g * 4 + 2) * 2048 + n] = s2 + bb;
    gb[((size_t)g * 4 + 3) * 2048 + n] = s3 + bb;
  }
}

// ---------------------------------------------------------------- AdaLN apply (bf16 out)
// wave-per-row: 64 lanes x 4 float4 = 1024 floats; shuffle-only reduction,
// no LDS, no barriers; 4 independent waves per block (grid = ROWS/4).
__global__ __launch_bounds__(256) void adaln_apply_kernel(
    const float* __restrict__ x, const float* __restrict__ gb,
    ushort* __restrict__ xn) {
  const int w = threadIdx.x >> 6, lane = threadIdx.x & 63;
  const int r = blockIdx.x * 4 + w;
  const int b = r >> 10;
  const float* xr = x + (size_t)r * D_;
  float4 v[4];
  float s = 0.f, q = 0.f;
#pragma unroll
  for (int i = 0; i < 4; ++i) {
    v[i] = ((const float4*)xr)[i * 64 + lane];
    s += v[i].x + v[i].y + v[i].z + v[i].w;
    q += v[i].x * v[i].x + v[i].y * v[i].y + v[i].z * v[i].z + v[i].w * v[i].w;
  }
  s = waveReduceSum(s);
  q = waveReduceSum(q);
  const float mean = s * (1.f / D_);
  const float rstd = rsqrtf(q * (1.f / D_) - mean * mean + 1e-5f);
  const float* gp = gb + (size_t)b * 2048;
  ushort* xo = xn + (size_t)r * D_;
#pragma unroll
  for (int i = 0; i < 4; ++i) {
    float4 g  = ((const float4*)gp)[i * 64 + lane];
    float4 be = ((const float4*)(gp + D_))[i * 64 + lane];
    ushort4 o;
    o.x = f2bf((v[i].x - mean) * rstd * (1.f + g.x) + be.x);
    o.y = f2bf((v[i].y - mean) * rstd * (1.f + g.y) + be.y);
    o.z = f2bf((v[i].z - mean) * rstd * (1.f + g.z) + be.z);
    o.w = f2bf((v[i].w - mean) * rstd * (1.f + g.w) + be.w);
    ((ushort4*)xo)[i * 64 + lane] = o;
  }
}

// ---------------------------------------------------------------- bf16 MFMA GEMM (128x128)
// depth-2 pipelined (3 LDS buffers + counted vmcnt), banded XCD swizzle,
// source-chunk LDS swizzle, padded vector epilogue, optional fused RoPE.
template <int FLAGS, bool OUTBF, int ROPE>
__global__ __launch_bounds__(256) void gemm_mfma_kernel(
    const ushort* __restrict__ A, int lda,
    const ushort* __restrict__ W, int ldw,
    const float* __restrict__ bias,
    const float* __restrict__ res, int ldres,
    void* __restrict__ Cout, int ldc, int K,
    const float* __restrict__ tab, int rlim, int lmask) {
  __shared__ __align__(16) ushort lds[24576];   // 48KB: A bufs @0, W bufs @12288
  const int tid = threadIdx.x;
  const int lane = tid & 63, wv = tid >> 6;
  const int wrow = (wv >> 1) * 64, wcol = (wv & 1) * 64;
  const int fr = lane & 15;
  const int kbs = (((lane >> 4) ^ (fr & 3)) & 3) * 8;

  int trow, tcol;
  xcd_banded(trow, tcol);
  const int row0 = trow * 128;
  const int col0 = tcol * 128;

  const int c0 = wv * 2, c1 = wv * 2 + 1;
  const int sr = lane >> 2;
  const int sc = (((lane & 3) ^ (sr & 3)) & 3) * 8;
  const ushort* Ap0 = A + (size_t)(row0 + c0 * 16 + sr) * lda + sc;
  const ushort* Ap1 = A + (size_t)(row0 + c1 * 16 + sr) * lda + sc;
  const ushort* Wp0 = W + (size_t)(col0 + c0 * 16 + sr) * ldw + sc;
  const ushort* Wp1 = W + (size_t)(col0 + c1 * 16 + sr) * ldw + sc;

  f32x4 acc[4][4];
#pragma unroll
  for (int m = 0; m < 4; ++m)
#pragma unroll
    for (int n = 0; n < 4; ++n) acc[m][n] = (f32x4)0.f;

#define ASB(B) (lds + (B) * 4096)
#define WSB(B) (lds + 12288 + (B) * 4096)
#define STAGE(B, T)                                   \
  do {                                                \
    const int koff_ = (T) * 32;                       \
    gload16(Ap0 + koff_, ASB(B) + c0 * 512);          \
    gload16(Ap1 + koff_, ASB(B) + c1 * 512);          \
    gload16(Wp0 + koff_, WSB(B) + c0 * 512);          \
    gload16(Wp1 + koff_, WSB(B) + c1 * 512);          \
  } while (0)
#define WAITV8() asm volatile("s_waitcnt vmcnt(8)" ::: "memory")
#define WAITV4() asm volatile("s_waitcnt vmcnt(4)" ::: "memory")
#define WAITV0() asm volatile("s_waitcnt vmcnt(0)" ::: "memory")
#define BAR()    __builtin_amdgcn_s_barrier()
#define COMPUTE(B)                                                          \
  do {                                                                      \
    bf16x8 af[4], bfr[4];                                                   \
    _Pragma("unroll")                                                       \
    for (int m = 0; m < 4; ++m)                                             \
      af[m] = *(const bf16x8*)(ASB(B) + (wrow + m * 16 + fr) * 32 + kbs);   \
    _Pragma("unroll")                                                       \
    for (int n = 0; n < 4; ++n)                                             \
      bfr[n] = *(const bf16x8*)(WSB(B) + (wcol + n * 16 + fr) * 32 + kbs);  \
    _Pragma("unroll")                                                       \
    for (int m = 0; m < 4; ++m)                                             \
      _Pragma("unroll")                                                     \
      for (int n = 0; n < 4; ++n)                                           \
        acc[m][n] = __builtin_amdgcn_mfma_f32_16x16x32_bf16(af[m], bfr[n],  \
                                                            acc[m][n], 0, 0, 0); \
  } while (0)

  const int NT = K >> 5;
  STAGE(0, 0);
  STAGE(1, 1);
  for (int t = 0; t < NT; t += 3) {
    {
      const bool sA = (t + 2) < NT;
      if (sA) STAGE(2, t + 2);
      if ((t + 1) < NT) { if (sA) WAITV8(); else WAITV4(); } else WAITV0();
      BAR(); COMPUTE(0); BAR();
    }
    if ((t + 1) < NT) {
      const bool sB = (t + 3) < NT;
      if (sB) STAGE(0, t + 3);
      if ((t + 2) < NT) { if (sB) WAITV8(); else WAITV4(); } else WAITV0();
      BAR(); COMPUTE(1); BAR();
    }
    if ((t + 2) < NT) {
      const bool sC = (t + 4) < NT;
      if (sC) STAGE(1, t + 4);
      if ((t + 3) < NT) { if (sC) WAITV8(); else WAITV4(); } else WAITV0();
      BAR(); COMPUTE(2); BAR();
    }
  }
#undef STAGE
#undef WAITV8
#undef WAITV4
#undef WAITV0
#undef COMPUTE

  float bn[4];
  if (FLAGS & 1) {
#pragma unroll
    for (int n = 0; n < 4; ++n) bn[n] = bias[col0 + wcol + n * 16 + fr];
  }
#define EPI(v, n)                                                     \
  do {                                                                \
    if (FLAGS & 1) (v) += bn[n];                                      \
    if (FLAGS & 2) (v) = 0.5f * (v) * (1.f + erff((v) * 0.70710678118f)); \
  } while (0)

  if (OUTBF) {
    ushort* Ct = lds;                       // [128][136] bf16 (padded)
    ushort* Cg = (ushort*)Cout;
#pragma unroll
    for (int m = 0; m < 4; ++m) {
      int lr0 = wrow + m * 16 + (lane >> 4) * 4;
#pragma unroll
      for (int n = 0; n < 4; ++n) {
        int lc = wcol + n * 16 + fr;
#pragma unroll
        for (int r = 0; r < 4; ++r) {
          float v = acc[m][n][r];
          EPI(v, n);
          Ct[(lr0 + r) * 136 + lc] = f2bf(v);
        }
      }
    }
    __syncthreads();
#pragma unroll
    for (int it = 0; it < 8; ++it) {
      int lr = (tid >> 4) + it * 16;
      int lc = (tid & 15) * 8;
      union { int4 v; ushort us[8]; } vv;
      vv.v = *(const int4*)&Ct[lr * 136 + lc];
      if (ROPE && (col0 + lc) < rlim) {
        union { int4 v; ushort us[8]; } pv;
        pv.v = *(const int4*)&Ct[lr * 136 + (lc ^ 32)];
        int l = (row0 + lr) & lmask;
        int j = lc & 31;
        const float* cb = &tab[l * 64 + j];
        bool lowhalf = (lc & 63) < 32;
#pragma unroll
        for (int e = 0; e < 8; ++e) {
          float cc = cb[e], ss = cb[32 + e];
          float xv = bf2f(vv.us[e]), xp = bf2f(pv.us[e]);
          float o = lowhalf ? (xv * cc - xp * ss) : (xp * ss + xv * cc);
          vv.us[e] = f2bf(o);
        }
      }
      *(int4*)&Cg[(size_t)(row0 + lr) * ldc + col0 + lc] = vv.v;
    }
  } else {
    float* Cf = (float*)lds;                // [64][132] f32 (padded) per half
    float* Cg = (float*)Cout;
#pragma unroll
    for (int half = 0; half < 2; ++half) {
      if ((wv >> 1) == half) {
#pragma unroll
        for (int m = 0; m < 4; ++m) {
          int lr0 = m * 16 + (lane >> 4) * 4;
#pragma unroll
          for (int n = 0; n < 4; ++n) {
            int lc = wcol + n * 16 + fr;
#pragma unroll
            for (int r = 0; r < 4; ++r) {
              float v = acc[m][n][r];
              EPI(v, n);
              Cf[(lr0 + r) * 132 + lc] = v;
            }
          }
        }
      }
      __syncthreads();
#pragma unroll
      for (int it = 0; it < 8; ++it) {
        int lr = (tid >> 5) + it * 8;
        int lc = (tid & 31) * 4;
        int grow = row0 + half * 64 + lr;
        float4 v = *(const float4*)&Cf[lr * 132 + lc];
        if (FLAGS & 4) {
          float4 rv = *(const float4*)&res[(size_t)grow * ldres + col0 + lc];
          v.x += rv.x; v.y += rv.y; v.z += rv.z; v.w += rv.w;
        }
        *(float4*)&Cg[(size_t)grow * ldc + col0 + lc] = v;
      }
      __syncthreads();
    }
  }
#undef EPI
#undef ASB
#undef WSB
#undef BAR
}

// ---------------------------------------------------------------- merged cq + (ck|cv) GEMM
// z=0: big = xnb @ cqW^T (M=4096, ldc=1024, lmask=1023, virtual grid 8x32)
// z=1: kvb = ctxb @ kvW^T (M=2048, ldc=2048, lmask=511, virtual grid 16x16)
// Both: K=1024, lda=1024, bf16-out, RoPE cols<1024. Same proven pipeline.
__global__ __launch_bounds__(256) void gemm_cqkv_kernel(
    const ushort* __restrict__ Aq, const ushort* __restrict__ Ac,
    const ushort* __restrict__ Wq, const ushort* __restrict__ Wkv,
    ushort* __restrict__ Cq, ushort* __restrict__ Ckv,
    const float* __restrict__ tab) {
  __shared__ __align__(16) ushort lds[24576];
  const int tid = threadIdx.x;
  const int lane = tid & 63, wv = tid >> 6;
  const int wrow = (wv >> 1) * 64, wcol = (wv & 1) * 64;
  const int fr = lane & 15;
  const int kbs = (((lane >> 4) ^ (fr & 3)) & 3) * 8;
  const int K = 1024, lda = 1024;

  const int z = blockIdx.z;
  const ushort* A = z ? Ac : Aq;
  const ushort* W = z ? Wkv : Wq;
  ushort* Cg = z ? Ckv : Cq;
  const int ldc = z ? 2048 : 1024;
  const int lmask = z ? 511 : 1023;
  const int vgx = z ? 16 : 8;

  // banded swizzle on the virtual grid (256 blocks per z-slice)
  const int flat = blockIdx.y * gridDim.x + blockIdx.x;   // 0..255
  const int swz = (flat & 7) * 32 + (flat >> 3);
  const int bandw = vgx * 4;
  const int band = swz / bandw;
  const int rem = swz % bandw;
  const int row0 = (band * 4 + (rem & 3)) * 128;
  const int col0 = (rem >> 2) * 128;

  const int c0 = wv * 2, c1 = wv * 2 + 1;
  const int sr = lane >> 2;
  const int sc = (((lane & 3) ^ (sr & 3)) & 3) * 8;
  const ushort* Ap0 = A + (size_t)(row0 + c0 * 16 + sr) * lda + sc;
  const ushort* Ap1 = A + (size_t)(row0 + c1 * 16 + sr) * lda + sc;
  const ushort* Wp0 = W + (size_t)(col0 + c0 * 16 + sr) * lda + sc;
  const ushort* Wp1 = W + (size_t)(col0 + c1 * 16 + sr) * lda + sc;

  f32x4 acc[4][4];
#pragma unroll
  for (int m = 0; m < 4; ++m)
#pragma unroll
    for (int n = 0; n < 4; ++n) acc[m][n] = (f32x4)0.f;

#define ASB(B) (lds + (B) * 4096)
#define WSB(B) (lds + 12288 + (B) * 4096)
#define STAGE(B, T)                                   \
  do {                                                \
    const int koff_ = (T) * 32;                       \
    gload16(Ap0 + koff_, ASB(B) + c0 * 512);          \
    gload16(Ap1 + koff_, ASB(B) + c1 * 512);          \
    gload16(Wp0 + koff_, WSB(B) + c0 * 512);          \
    gload16(Wp1 + koff_, WSB(B) + c1 * 512);          \
  } while (0)
#define WAITV8() asm volatile("s_waitcnt vmcnt(8)" ::: "memory")
#define WAITV4() asm volatile("s_waitcnt vmcnt(4)" ::: "memory")
#define WAITV0() asm volatile("s_waitcnt vmcnt(0)" ::: "memory")
#define BAR()    __builtin_amdgcn_s_barrier()
#define COMPUTE(B)                                                          \
  do {                                                                      \
    bf16x8 af[4], bfr[4];                                                   \
    _Pragma("unroll")                                                       \
    for (int m = 0; m < 4; ++m)                                             \
      af[m] = *(const bf16x8*)(ASB(B) + (wrow + m * 16 + fr) * 32 + kbs);   \
    _Pragma("unroll")                                                       \
    for (int n = 0; n < 4; ++n)                                             \
      bfr[n] = *(const bf16x8*)(WSB(B) + (wcol + n * 16 + fr) * 32 + kbs);  \
    _Pragma("unroll")                                                       \
    for (int m = 0; m < 4; ++m)                                             \
      _Pragma("unroll")                                                     \
      for (int n = 0; n < 4; ++n)                                           \
        acc[m][n] = __builtin_amdgcn_mfma_f32_16x16x32_bf16(af[m], bfr[n],  \
                                                            acc[m][n], 0, 0, 0); \
  } while (0)

  const int NT = K >> 5;   // 32
  STAGE(0, 0);
  STAGE(1, 1);
  for (int t = 0; t < NT; t += 3) {
    {
      const bool sA = (t + 2) < NT;
      if (sA) STAGE(2, t + 2);
      if ((t + 1) < NT) { if (sA) WAITV8(); else WAITV4(); } else WAITV0();
      BAR(); COMPUTE(0); BAR();
    }
    if ((t + 1) < NT) {
      const bool sB = (t + 3) < NT;
      if (sB) STAGE(0, t + 3);
      if ((t + 2) < NT) { if (sB) WAITV8(); else WAITV4(); } else WAITV0();
      BAR(); COMPUTE(1); BAR();
    }
    if ((t + 2) < NT) {
      const bool sC = (t + 4) < NT;
      if (sC) STAGE(1, t + 4);
      if ((t + 3) < NT) { if (sC) WAITV8(); else WAITV4(); } else WAITV0();
      BAR(); COMPUTE(2); BAR();
    }
  }
#undef STAGE
#undef WAITV8
#undef WAITV4
#undef WAITV0
#undef COMPUTE

  // bf16 epilogue with fused RoPE (cols < 1024)
  ushort* Ct = lds;                       // [128][136]
#pragma unroll
  for (int m = 0; m < 4; ++m) {
    int lr0 = wrow + m * 16 + (lane >> 4) * 4;
#pragma unroll
    for (int n = 0; n < 4; ++n) {
      int lc = wcol + n * 16 + fr;
#pragma unroll
      for (int r = 0; r < 4; ++r)
        Ct[(lr0 + r) * 136 + lc] = f2bf(acc[m][n][r]);
    }
  }
  __syncthreads();
#pragma unroll
  for (int it = 0; it < 8; ++it) {
    int lr = (tid >> 4) + it * 16;
    int lc = (tid & 15) * 8;
    union { int4 v; ushort us[8]; } vv;
    vv.v = *(const int4*)&Ct[lr * 136 + lc];
    if ((col0 + lc) < 1024) {
      union { int4 v; ushort us[8]; } pv;
      pv.v = *(const int4*)&Ct[lr * 136 + (lc ^ 32)];
      int l = (row0 + lr) & lmask;
      int j = lc & 31;
      const float* cb = &tab[l * 64 + j];
      bool lowhalf = (lc & 63) < 32;
#pragma unroll
      for (int e = 0; e < 8; ++e) {
        float cc = cb[e], ss = cb[32 + e];
        float xv = bf2f(vv.us[e]), xp = bf2f(pv.us[e]);
        float o = lowhalf ? (xv * cc - xp * ss) : (xp * ss + xv * cc);
        vv.us[e] = f2bf(o);
      }
    }
    *(int4*)&Cg[(size_t)(row0 + lr) * ldc + col0 + lc] = vv.v;
  }
#undef ASB
#undef WSB
#undef BAR
}

// ---------------------------------------------------------------- 256x256 8-wave GEMM
// BK=64, double-buffered 128KB LDS, one barrier + one late vmcnt(0) per K-tile;
// banded XCD swizzle; chunk-XOR LDS swizzle; setprio around MFMA. bf16 out.
// Epilogue: linear [256][256] LDS tile -> vector stores.
// FLAGS: 1=+bias, 2=gelu. Requires K%64==0, M,N%256==0, gridDim.y%4==0.
template <int FLAGS, int ROPE>
__global__ __launch_bounds__(512, 2) void gemm256_kernel(
    const ushort* __restrict__ A, int lda,
    const ushort* __restrict__ W, int ldw,
    const float* __restrict__ bias,
    ushort* __restrict__ Cout, int ldc, int K,
    const float* __restrict__ tab, int rlim, int lmask) {
  __shared__ __align__(16) ushort lds[65536];   // 128 KB
  const int tid = threadIdx.x;
  const int lane = tid & 63, wid = tid >> 6;
  const int wm = wid >> 2, wn = wid & 3;        // 2 x 4 wave grid
  const int fr = lane & 15, hi = lane >> 4;

  int trow, tcol;
  xcd_banded(trow, tcol);
  const int row0 = trow * 256;
  const int col0 = tcol * 256;

  const int srow = lane >> 3;
  const int scol = ((lane & 7) ^ srow) * 8;
  const ushort* Asrc[4];
  const ushort* Wsrc[4];
#pragma unroll
  for (int j = 0; j < 4; ++j) {
    int r = wid * 32 + j * 8 + srow;
    Asrc[j] = A + (size_t)(row0 + r) * lda + scol;
    Wsrc[j] = W + (size_t)(col0 + r) * ldw + scol;
  }
#define AB256(b) (lds + (b) * 16384)
#define WB256(b) (lds + 32768 + (b) * 16384)
#define STG256(b, T)                                      \
  do {                                                    \
    const int kk_ = (T) * 64;                             \
    _Pragma("unroll")                                     \
    for (int j = 0; j < 4; ++j) {                         \
      int ch_ = wid * 4 + j;                              \
      gload16(Asrc[j] + kk_, AB256(b) + ch_ * 512);       \
      gload16(Wsrc[j] + kk_, WB256(b) + ch_ * 512);       \
    }                                                     \
  } while (0)

  f32x4 acc[8][4];
#pragma unroll
  for (int m = 0; m < 8; ++m)
#pragma unroll
    for (int n = 0; n < 4; ++n) acc[m][n] = (f32x4)0.f;

  const int NT = K >> 6;
  STG256(0, 0);
  asm volatile("s_waitcnt vmcnt(0)" ::: "memory");
  __builtin_amdgcn_s_barrier();
  for (int t = 0; t < NT; ++t) {
    const int cur = t & 1;
    if (t + 1 < NT) STG256(cur ^ 1, t + 1);   // issue BEFORE compute
    const ushort* ab = AB256(cur);
    const ushort* wb = WB256(cur);
    __builtin_amdgcn_s_setprio(1);
#pragma unroll
    for (int s = 0; s < 2; ++s) {
      bf16x8 wf[4];
#pragma unroll
      for (int n = 0; n < 4; ++n) {
        int row = wn * 64 + n * 16 + fr;
        wf[n] = *(const bf16x8*)(wb + row * 64 + (((s * 4 + hi) ^ (fr & 7)) * 8));
      }
#pragma unroll
      for (int m = 0; m < 8; ++m) {
        int row = wm * 128 + m * 16 + fr;
        bf16x8 af = *(const bf16x8*)(ab + row * 64 + (((s * 4 + hi) ^ (fr & 7)) * 8));
#pragma unroll
        for (int n = 0; n < 4; ++n)
          acc[m][n] = __builtin_amdgcn_mfma_f32_16x16x32_bf16(af, wf[n],
                                                              acc[m][n], 0, 0, 0);
      }
    }
    __builtin_amdgcn_s_setprio(0);
    asm volatile("s_waitcnt vmcnt(0)" ::: "memory");
    __builtin_amdgcn_s_barrier();
  }
#undef STG256

  float bn[4];
  if (FLAGS & 1) {
#pragma unroll
    for (int n = 0; n < 4; ++n) bn[n] = bias[col0 + wn * 64 + n * 16 + fr];
  }
  ushort* Ct = lds;
#pragma unroll
  for (int m = 0; m < 8; ++m) {
    int lr0 = wm * 128 + m * 16 + hi * 4;
#pragma unroll
    for (int n = 0; n < 4; ++n) {
      int lc = wn * 64 + n * 16 + fr;
#pragma unroll
      for (int r = 0; r < 4; ++r) {
        float v = acc[m][n][r];
        if (FLAGS & 1) v += bn[n];
        if (FLAGS & 2) v = 0.5f * v * (1.f + erff(v * 0.70710678118f));
        Ct[(lr0 + r) * 256 + lc] = f2bf(v);
      }
    }
  }
  __syncthreads();
#pragma unroll
  for (int it = 0; it < 16; ++it) {
    int idx = tid + it * 512;
    int lr = idx >> 5;
    int lc = (idx & 31) * 8;
    union { int4 v; ushort us[8]; } vv;
    vv.v = *(const int4*)&Ct[lr * 256 + lc];
    if (ROPE && (col0 + lc) < rlim) {
      union { int4 v; ushort us[8]; } pv;
      pv.v = *(const int4*)&Ct[lr * 256 + (lc ^ 32)];
      int l = (row0 + lr) & lmask;
      int j = lc & 31;
      const float* cb = &tab[l * 64 + j];
      bool lowhalf = (lc & 63) < 32;
#pragma unroll
      for (int e = 0; e < 8; ++e) {
        float cc = cb[e], ss = cb[32 + e];
        float xv = bf2f(vv.us[e]), xp = bf2f(pv.us[e]);
        float o = lowhalf ? (xv * cc - xp * ss) : (xp * ss + xv * cc);
        vv.us[e] = f2bf(o);
      }
    }
    *(int4*)&Cout[(size_t)(row0 + lr) * ldc + col0 + lc] = vv.v;
  }
#undef AB256
#undef WB256
}

// ---------------------------------------------------------------- MFMA flash attention
// 128 q-rows/block, 8 waves: waves 0-3 stage K, waves 4-7 stage V (transposed).
// Swapped QK^T, register-exchange P, K/V dbuf + async-stage, T13 defer-max.
#define SWZ(row, col) (((row) << 6) + ((col) ^ (((row) & 7) << 3)))
__global__ __launch_bounds__(512) void attn_mfma_kernel(
    const ushort* __restrict__ Q, int ldq,
    const ushort* __restrict__ K, int ldk,
    const ushort* __restrict__ V, int ldv,
    ushort* __restrict__ O, int ldo,
    int Lq, int Lk, float scale) {
  __shared__ __align__(16) ushort Ks[2][64 * 64];
  __shared__ __align__(16) ushort Vt[2][64 * 64];
  __shared__ __align__(16) ushort Os[128 * 64];
  const int tid = threadIdx.x;
  const int lane = tid & 63, w = tid >> 6;       // w in 0..7
  const int fr = lane & 15, hi = lane >> 4, kb = hi * 8;
  const int b = blockIdx.z, h = blockIdx.y, q0 = blockIdx.x * 128;
  const int kw = w & 3;
  const bool isK = (w < 4);

  bf16x8 aq[2];
  {
    const ushort* qp = Q + (size_t)(b * Lq + q0 + w * 16 + fr) * ldq + h * 64 + kb;
    union { bf16x8 v; ushort us[8]; } t0, t1;
    t0.v = *(const bf16x8*)qp;
    t1.v = *(const bf16x8*)(qp + 32);
#pragma unroll
    for (int e = 0; e < 8; ++e) {
      t0.us[e] = f2bf(bf2f(t0.us[e]) * scale);
      t1.us[e] = f2bf(bf2f(t1.us[e]) * scale);
    }
    aq[0] = t0.v;
    aq[1] = t1.v;
  }

  const int ldkv = isK ? ldk : ldv;
  const ushort* kvbase = (isK ? K : V) + (size_t)(b * Lk + lane) * ldkv
                         + h * 64 + kw * 16;
  const size_t kvstep = (size_t)64 * ldkv;
  int4 r0, r1;
#define LOADKV(T)                                      \
  do {                                                 \
    const ushort* p_ = kvbase + (size_t)(T) * kvstep;  \
    r0 = ((const int4*)p_)[0];                         \
    r1 = ((const int4*)p_)[1];                         \
  } while (0)
#define WRITEKV(P)                                                        \
  do {                                                                    \
    if (isK) {                                                            \
      *(int4*)&Ks[P][SWZ(lane, kw * 16)]     = r0;                        \
      *(int4*)&Ks[P][SWZ(lane, kw * 16 + 8)] = r1;                        \
    } else {                                                              \
      union { int4 v; ushort us[8]; } u0_, u1_;                           \
      u0_.v = r0; u1_.v = r1;                                             \
      _Pragma("unroll")                                                   \
      for (int e = 0; e < 8; ++e) Vt[P][SWZ(kw * 16 + e, lane)] = u0_.us[e]; \
      _Pragma("unroll")                                                   \
      for (int e = 0; e < 8; ++e) Vt[P][SWZ(kw * 16 + 8 + e, lane)] = u1_.us[e]; \
    }                                                                     \
  } while (0)

  f32x4 oacc[4];
#pragma unroll
  for (int n = 0; n < 4; ++n) oacc[n] = (f32x4)0.f;
  float mq = -1e30f, lq = 0.f;
  const int ntiles = Lk >> 6;
  const bool lowhalf = (lane < 32);
  const bool sendSelf = (hi == 1 || hi == 2);

  LOADKV(0);
  WRITEKV(0);
  int p = 0;
  for (int t = 0; t < ntiles; ++t) {
    if (t + 1 < ntiles) LOADKV(t + 1);
    __syncthreads();

    f32x4 sacc[4];
#pragma unroll
    for (int n = 0; n < 4; ++n) sacc[n] = (f32x4)0.f;
    __builtin_amdgcn_s_setprio(1);
#pragma unroll
    for (int s = 0; s < 2; ++s) {
#pragma unroll
      for (int n = 0; n < 4; ++n) {
        bf16x8 ak = *(const bf16x8*)&Ks[p][SWZ(n * 16 + fr, s * 32 + kb)];
        sacc[n] = __builtin_amdgcn_mfma_f32_16x16x32_bf16(ak, aq[s], sacc[n], 0, 0, 0);
      }
    }
    __builtin_amdgcn_s_setprio(0);

    float sm = sacc[0][0];
#pragma unroll
    for (int n = 0; n < 4; ++n)
#pragma unroll
      for (int r = 0; r < 4; ++r) sm = fmaxf(sm, sacc[n][r]);
    sm = fmaxf(sm, __shfl_xor(sm, 16));
    sm = fmaxf(sm, __shfl_xor(sm, 32));
    // T13 defer-max: if every row's max growth <= 8, keep old running max.
    const bool defer = __all(sm - mq <= 8.f);
    if (!defer) {
      float mnew = fmaxf(mq, sm);
      float corrq = __expf(mq - mnew);
      mq = mnew;
      lq *= corrq;
      float c0 = __shfl(corrq, hi * 4 + 0);
      float c1 = __shfl(corrq, hi * 4 + 1);
      float c2 = __shfl(corrq, hi * 4 + 2);
      float c3 = __shfl(corrq, hi * 4 + 3);
#pragma unroll
      for (int n = 0; n < 4; ++n) {
        oacc[n][0] *= c0; oacc[n][1] *= c1; oacc[n][2] *= c2; oacc[n][3] *= c3;
      }
    }
    float pe[4][4];
    float psum = 0.f;
#pragma unroll
    for (int n = 0; n < 4; ++n)
#pragma unroll
      for (int r = 0; r < 4; ++r) {
        pe[n][r] = __expf(sacc[n][r] - mq);
        psum += pe[n][r];
      }
    psum += __shfl_xor(psum, 16);
    psum += __shfl_xor(psum, 32);
    lq += psum;

    uint32 u00 = pk2(pe[0][0], pe[0][1]), u01 = pk2(pe[0][2], pe[0][3]);
    uint32 u10 = pk2(pe[1][0], pe[1][1]), u11 = pk2(pe[1][2], pe[1][3]);
    uint32 u20 = pk2(pe[2][0], pe[2][1]), u21 = pk2(pe[2][2], pe[2][3]);
    uint32 u30 = pk2(pe[3][0], pe[3][1]), u31 = pk2(pe[3][2], pe[3][3]);
    uint32 selfw0 = lowhalf ? u00 : u10;
    uint32 selfw1 = lowhalf ? u01 : u11;
    uint32 selfw2 = lowhalf ? u20 : u30;
    uint32 selfw3 = lowhalf ? u21 : u31;
    uint32 send10 = lowhalf ? u10 : u00;
    uint32 send11 = lowhalf ? u11 : u01;
    uint32 send12 = lowhalf ? u30 : u20;
    uint32 send13 = lowhalf ? u31 : u21;
    uint32 farw0 = __shfl_xor((int)send10, 32);
    uint32 farw1 = __shfl_xor((int)send11, 32);
    uint32 farw2 = __shfl_xor((int)send12, 32);
    uint32 farw3 = __shfl_xor((int)send13, 32);
    uint32 s20 = sendSelf ? selfw0 : farw0;
    uint32 s21 = sendSelf ? selfw1 : farw1;
    uint32 s22 = sendSelf ? selfw2 : farw2;
    uint32 s23 = sendSelf ? selfw3 : farw3;
    uint32 rcv0 = __shfl_xor((int)s20, 16);
    uint32 rcv1 = __shfl_xor((int)s21, 16);
    uint32 rcv2 = __shfl_xor((int)s22, 16);
    uint32 rcv3 = __shfl_xor((int)s23, 16);
    union { uint32 wd[4]; bf16x8 v; } pa0, pa1;
    if (hi == 0) {
      pa0.wd[0] = selfw0; pa0.wd[1] = selfw1; pa0.wd[2] = rcv0; pa0.wd[3] = rcv1;
      pa1.wd[0] = selfw2; pa1.wd[1] = selfw3; pa1.wd[2] = rcv2; pa1.wd[3] = rcv3;
    } else if (hi == 1) {
      pa0.wd[0] = rcv0; pa0.wd[1] = rcv1; pa0.wd[2] = farw0; pa0.wd[3] = farw1;
      pa1.wd[0] = rcv2; pa1.wd[1] = rcv3; pa1.wd[2] = farw2; pa1.wd[3] = farw3;
    } else if (hi == 2) {
      pa0.wd[0] = farw0; pa0.wd[1] = farw1; pa0.wd[2] = rcv0; pa0.wd[3] = rcv1;
      pa1.wd[0] = farw2; pa1.wd[1] = farw3; pa1.wd[2] = rcv2; pa1.wd[3] = rcv3;
    } else {
      pa0.wd[0] = rcv0; pa0.wd[1] = rcv1; pa0.wd[2] = selfw0; pa0.wd[3] = selfw1;
      pa1.wd[0] = rcv2; pa1.wd[1] = rcv3; pa1.wd[2] = selfw2; pa1.wd[3] = selfw3;
    }

    __builtin_amdgcn_s_setprio(1);
#pragma unroll
    for (int n = 0; n < 4; ++n) {
      bf16x8 bv0 = *(const bf16x8*)&Vt[p][SWZ(n * 16 + fr, 0 * 32 + kb)];
      oacc[n] = __builtin_amdgcn_mfma_f32_16x16x32_bf16(pa0.v, bv0, oacc[n], 0, 0, 0);
      bf16x8 bv1 = *(const bf16x8*)&Vt[p][SWZ(n * 16 + fr, 1 * 32 + kb)];
      oacc[n] = __builtin_amdgcn_mfma_f32_16x16x32_bf16(pa1.v, bv1, oacc[n], 0, 0, 0);
    }
    __builtin_amdgcn_s_setprio(0);

    __syncthreads();
    if (t + 1 < ntiles) WRITEKV(p ^ 1);
    p ^= 1;
  }
#undef LOADKV
#undef WRITEKV

  float linv[4];
#pragma unroll
  for (int r = 0; r < 4; ++r) linv[r] = 1.f / __shfl(lq, hi * 4 + r);
#pragma unroll
  for (int r = 0; r < 4; ++r) {
    int rl = w * 16 + hi * 4 + r;
#pragma unroll
    for (int n = 0; n < 4; ++n)
      Os[SWZ(rl, n * 16 + fr)] = f2bf(oacc[n][r] * linv[r]);
  }
  __syncthreads();
  {
    int row = tid >> 2, cbk = (tid & 3) * 16;
    ushort* op = O + (size_t)(b * Lq + q0 + row) * ldo + h * 64 + cbk;
    int4 o0 = *(const int4*)&Os[SWZ(row, cbk)];
    int4 o1 = *(const int4*)&Os[SWZ(row, cbk + 8)];
    ((int4*)op)[0] = o0;
    ((int4*)op)[1] = o1;
  }
}

// ---------------------------------------------------------------- launch
extern "C" void kernel_launch(void* const* d_in, const int* in_sizes, int n_in,
                              void* d_out, int out_size, void* d_ws, size_t ws_size,
                              hipStream_t stream) {
  const float* x_in = (const float*)d_in[0];
  const float* emb  = (const float*)d_in[1];
  const float* ctx  = (const float*)d_in[2];
  const float* n1w = (const float*)d_in[5];
  const float* n1b = (const float*)d_in[6];
  const float* n2w = (const float*)d_in[7];
  const float* n2b = (const float*)d_in[8];
  const float* n3w = (const float*)d_in[9];
  const float* n3b = (const float*)d_in[10];
  const float* qkvw = (const float*)d_in[11];
  const float* sow  = (const float*)d_in[12];
  const float* cqw  = (const float*)d_in[13];
  const float* ckw  = (const float*)d_in[14];
  const float* cvw  = (const float*)d_in[15];
  const float* cow  = (const float*)d_in[16];
  const float* f1w  = (const float*)d_in[17];
  const float* f1b  = (const float*)d_in[18];
  const float* f2w  = (const float*)d_in[19];
  const float* f2b  = (const float*)d_in[20];

  float* xcur = (float*)d_out;

  // workspace layout
  ushort* xnb  = (ushort*)d_ws;                        // 4096x1024 bf16
  ushort* big  = xnb + (size_t)4096 * 1024;            // 4096x4096 bf16 (qkv/q/h)
  ushort* obb  = big + (size_t)4096 * 4096;            // 4096x1024 bf16 (attn out)
  ushort* kvb  = obb + (size_t)4096 * 1024;            // 2048x2048 bf16 (K|V packed)
  ushort* ctxb = kvb + (size_t)2048 * 2048;            // 2048x1024 bf16 (persistent)
  float*  gball= (float*)(ctxb + (size_t)2048 * 1024); // 18*4*2048 f32
  float*  tab  = gball + 18 * 4 * 2048;                // 65536 f32
  ushort* scrW = (ushort*)(tab + 65536);               // 4096x1024 bf16 scratch
  const size_t SZ_QKV = (size_t)NL_ * 3072 * 1024;
  const size_t SZ_SQ  = (size_t)NL_ * 1024 * 1024;
  const size_t SZ_F   = (size_t)NL_ * 4096 * 1024;
  const size_t M1 = (size_t)1024 * 1024;
  ushort* wqkv = scrW + (size_t)4096 * 1024;
  ushort* wso  = wqkv + SZ_QKV;
  ushort* wcq  = wso + SZ_SQ;
  ushort* wkv  = wcq + SZ_SQ;          // [NL][2048][1024] packed ck|cv
  ushort* wco  = wkv + 2 * SZ_SQ;
  ushort* wf1  = wco + SZ_SQ;
  ushort* wf2  = wf1 + SZ_F;
  const size_t need_full = (size_t)((char*)(wf2 + SZ_F) - (char*)d_ws);
  const bool wbfull = (ws_size >= need_full);

  hipMemcpyAsync(xcur, x_in, (size_t)B_ * L_ * D_ * sizeof(float),
                 hipMemcpyDeviceToDevice, stream);
  rope_table_kernel<<<128, 256, 0, stream>>>(tab);
  adaln_gb_all_kernel<<<9216, 256, 0, stream>>>(emb, n1w, n2w, n3w,
                                                n1b, n2b, n3b, gball);
  cvt_bf16_kernel<<<1024, 256, 0, stream>>>(ctx, ctxb,
                                            (int)((size_t)2048 * 1024 / 4));

  if (wbfull) {
    cvt_weights_kernel<<<2048, 256, 0, stream>>>(
        qkvw, sow, cqw, cow, f1w, f2w, wqkv, wso, wcq, wco, wf1, wf2);
    cvt_pack_kv_kernel<<<2048, 256, 0, stream>>>(ckw, cvw, wkv,
                                                 (int)(2 * SZ_SQ / 4));
  }

  auto prepW = [&](const float* src, ushort* full, size_t layerOff,
                   size_t nelem) -> const ushort* {
    if (wbfull) return full + layerOff;
    cvt_bf16_kernel<<<1024, 256, 0, stream>>>(src + layerOff, scrW,
                                              (int)(nelem / 4));
    return scrW;
  };

  const int ROWS = B_ * L_;
  const dim3 blk(256);
  const dim3 blk512(512);

  for (int i = 0; i < NL_; ++i) {
    const float* f1bi = f1b + (size_t)i * DFF_;
    const float* f2bi = f2b + (size_t)i * D_;

    // ---- self-attention block ----
    adaln_apply_kernel<<<ROWS / 4, blk, 0, stream>>>(
        xcur, gball + (size_t)(i * 3 + 0) * 4 * 2048, xnb);
    gemm256_kernel<0, 1><<<dim3(12, 16), blk512, 0, stream>>>(       // rope q,k
        xnb, D_, prepW(qkvw, wqkv, (size_t)i * 3072 * 1024, (size_t)3072 * 1024),
        D_, nullptr, big, 3072, D_, tab, 2048, 1023);
    attn_mfma_kernel<<<dim3(L_ / 128, H_, B_), blk512, 0, stream>>>(
        big, 3072, big + 1024, 3072, big + 2048, 3072, obb, D_, L_, L_, 0.125f);
    gemm_mfma_kernel<4, false, 0><<<dim3(8, 32), blk, 0, stream>>>(
        obb, D_, prepW(sow, wso, (size_t)i * M1, M1),
        D_, nullptr, xcur, D_, xcur, D_, D_, tab, 0, 0);

    // ---- cross-attention block ----
    adaln_apply_kernel<<<ROWS / 4, blk, 0, stream>>>(
        xcur, gball + (size_t)(i * 3 + 1) * 4 * 2048, xnb);
    // merged cq + (ck|cv) projections (rope on q and k halves)
    {
      const ushort *wcqi, *wkvi;
      if (wbfull) {
        wcqi = wcq + (size_t)i * M1;
        wkvi = wkv + (size_t)i * 2 * M1;
      } else {
        cvt_bf16_kernel<<<512, 256, 0, stream>>>(cqw + (size_t)i * M1, scrW,
                                                 (int)(M1 / 4));
        cvt_bf16_kernel<<<512, 256, 0, stream>>>(ckw + (size_t)i * M1,
                                                 scrW + M1, (int)(M1 / 4));
        cvt_bf16_kernel<<<512, 256, 0, stream>>>(cvw + (size_t)i * M1,
                                                 scrW + 2 * M1, (int)(M1 / 4));
        wcqi = scrW;
        wkvi = scrW + M1;
      }
      gemm_cqkv_kernel<<<dim3(16, 16, 2), blk, 0, stream>>>(
          xnb, ctxb, wcqi, wkvi, big, kvb, tab);
    }
    attn_mfma_kernel<<<dim3(L_ / 128, H_, B_), blk512, 0, stream>>>(
        big, 1024, kvb, 2048, kvb + 1024, 2048, obb, D_, L_, LC_, 0.125f);
    gemm_mfma_kernel<4, false, 0><<<dim3(8, 32), blk, 0, stream>>>(
        obb, D_, prepW(cow, wco, (size_t)i * M1, M1),
        D_, nullptr, xcur, D_, xcur, D_, D_, tab, 0, 0);

    // ---- FFN block ----
    adaln_apply_kernel<<<ROWS / 4, blk, 0, stream>>>(
        xcur, gball + (size_t)(i * 3 + 2) * 4 * 2048, xnb);
    gemm256_kernel<3, 0><<<dim3(16, 16), blk512, 0, stream>>>(       // bias+gelu
        xnb, D_, prepW(f1w, wf1, (size_t)i * 4096 * 1024, (size_t)4096 * 1024),
        D_, f1bi, big, DFF_, D_, tab, 0, 0);
    gemm_mfma_kernel<5, false, 0><<<dim3(8, 32), blk, 0, stream>>>(
        big, DFF_, prepW(f2w, wf2, (size_t)i * 4096 * 1024, (size_t)4096 * 1024),
        DFF_, f2bi, xcur, D_, xcur, D_, DFF_, tab, 0, 0);
  }
}